// Round 1
// baseline (5795.443 us; speedup 1.0000x reference)
//
#include <hip/hip_runtime.h>
#include <math.h>

#define Bb 4
#define Nn 2048
#define Kk 32
#define Hh 128
#define NIi 256
#define NH_ 4
#define Dd 32
#define DFFh 512

#define NEGF -3.402823466e38f

__device__ __forceinline__ float gelu_f(float x) {
    return 0.5f * x * (1.0f + erff(x * 0.7071067811865476f));
}

// Sum v across the block (256 threads). All threads must call. Returns total to all.
__device__ __forceinline__ float blocksum(float v, float* red) {
    int t = threadIdx.x;
    #pragma unroll
    for (int m = 32; m; m >>= 1) v += __shfl_xor(v, m, 64);
    __syncthreads();
    if ((t & 63) == 0) red[t >> 6] = v;
    __syncthreads();
    return red[0] + red[1] + red[2] + red[3];
}

// ---------------- K1: neighbor attention + gelu + residual + LN(n1) -> hv1 ----
__global__ __launch_bounds__(256) void k_node_attn(
    const float* __restrict__ hV, const float* __restrict__ hEV,
    const float* __restrict__ maskA,
    const float* __restrict__ WQ, const float* __restrict__ WK,
    const float* __restrict__ WV, const float* __restrict__ WO,
    const float* __restrict__ n1g, const float* __restrict__ n1b,
    float* __restrict__ hv1)
{
    __shared__ float EV[Kk][NIi];      // 32 KB
    __shared__ float Kt[Kk][Hh + 1];
    __shared__ float Vt[Kk][Hh + 1];
    __shared__ float Qs[Hh];
    __shared__ float hvr[Hh];
    __shared__ float att[NH_][Kk];
    __shared__ float outr[Hh];
    __shared__ float red[4];

    const int bn = blockIdx.x;
    const int t = threadIdx.x;
    const float* evp = hEV + (size_t)bn * (Kk * NIi);
    for (int i = t; i < Kk * NIi; i += 256) EV[i >> 8][i & 255] = evp[i];
    if (t < Hh) hvr[t] = hV[(size_t)bn * Hh + t];
    __syncthreads();

    // Q = hv_row @ WQ
    if (t < Hh) {
        float a = 0.f;
        for (int i = 0; i < Hh; ++i) a += hvr[i] * WQ[i * Hh + t];
        Qs[t] = a;
    }
    // K = EV @ WK, V = EV @ WV  (register-accumulated: weight loaded once, used 16x)
    {
        const int c = t & 127, half = t >> 7;
        float aK[16], aV[16];
        #pragma unroll
        for (int k = 0; k < 16; ++k) { aK[k] = 0.f; aV[k] = 0.f; }
        for (int i = 0; i < NIi; ++i) {
            float wk = WK[i * Hh + c], wv = WV[i * Hh + c];
            #pragma unroll
            for (int k = 0; k < 16; ++k) {
                float e = EV[half * 16 + k][i];
                aK[k] += e * wk; aV[k] += e * wv;
            }
        }
        #pragma unroll
        for (int k = 0; k < 16; ++k) {
            Kt[half * 16 + k][c] = aK[k];
            Vt[half * 16 + k][c] = aV[k];
        }
    }
    __syncthreads();

    // logits[nh][k] = Q[nh]·K[k][nh] / sqrt(32)
    if (t < NH_ * Kk) {
        int nh = t >> 5, k = t & 31;
        float a = 0.f;
        for (int d = 0; d < Dd; ++d) a += Qs[nh * Dd + d] * Kt[k][nh * Dd + d];
        att[nh][k] = a * 0.17677669529663687f;
    }
    __syncthreads();
    // masked softmax over k, then post-multiply by mask
    if (t < NH_) {
        const float* m = maskA + (size_t)bn * Kk;
        float l[Kk];
        float mx = NEGF;
        #pragma unroll
        for (int k = 0; k < Kk; ++k) {
            l[k] = (m[k] > 0.f) ? att[t][k] : NEGF;
            mx = fmaxf(mx, l[k]);
        }
        float s = 0.f;
        #pragma unroll
        for (int k = 0; k < Kk; ++k) { l[k] = expf(l[k] - mx); s += l[k]; }
        float inv = 1.f / s;
        #pragma unroll
        for (int k = 0; k < Kk; ++k) att[t][k] = m[k] * l[k] * inv;
    }
    __syncthreads();
    // out[nh*32+d] = sum_k att[nh][k] * V[k][nh*32+d]
    if (t < Hh) {
        int nh = t >> 5, d = t & 31;
        float a = 0.f;
        #pragma unroll
        for (int k = 0; k < Kk; ++k) a += att[nh][k] * Vt[k][nh * Dd + d];
        outr[t] = a;
    }
    __syncthreads();
    // dh = gelu(out @ WO); x = h_V + dh; LN(n1)
    float x = 0.f;
    if (t < Hh) {
        float a = 0.f;
        for (int h = 0; h < Hh; ++h) a += outr[h] * WO[h * Hh + t];
        x = hvr[t] + gelu_f(a);
    }
    float mu = blocksum((t < Hh) ? x : 0.f, red) * (1.f / Hh);
    float dx = (t < Hh) ? (x - mu) : 0.f;
    float var = blocksum(dx * dx, red) * (1.f / Hh);
    if (t < Hh)
        hv1[(size_t)bn * Hh + t] = n1g[t] * dx / sqrtf(var + 1e-5f) + n1b[t];
}

// ---------------- K2: FFN1 + gelu + residual + LN(n1) + mask -> outV ----------
__global__ __launch_bounds__(256) void k_node_ffn(
    const float* __restrict__ hv1, const float* __restrict__ maskV,
    const float* __restrict__ Win, const float* __restrict__ bin,
    const float* __restrict__ Wout, const float* __restrict__ bout,
    const float* __restrict__ n1g, const float* __restrict__ n1b,
    float* __restrict__ outV)
{
    __shared__ float xr[Hh];
    __shared__ float hid[DFFh];
    __shared__ float red[4];
    const int bn = blockIdx.x, t = threadIdx.x;
    if (t < Hh) xr[t] = hv1[(size_t)bn * Hh + t];
    __syncthreads();
    {
        float a0 = 0.f, a1 = 0.f;
        for (int i = 0; i < Hh; ++i) {
            float xi = xr[i];
            a0 += xi * Win[i * DFFh + t];
            a1 += xi * Win[i * DFFh + t + 256];
        }
        hid[t] = gelu_f(a0 + bin[t]);
        hid[t + 256] = gelu_f(a1 + bin[t + 256]);
    }
    __syncthreads();
    float x = 0.f;
    if (t < Hh) {
        float a = bout[t];
        for (int i = 0; i < DFFh; ++i) a += hid[i] * Wout[i * Hh + t];
        x = xr[t] + gelu_f(a);
    }
    float mu = blocksum((t < Hh) ? x : 0.f, red) * (1.f / Hh);
    float dx = (t < Hh) ? (x - mu) : 0.f;
    float var = blocksum(dx * dx, red) * (1.f / Hh);
    if (t < Hh) {
        float v = n1g[t] * dx / sqrtf(var + 1e-5f) + n1b[t];
        outV[(size_t)bn * Hh + t] = maskV[bn] * v;
    }
}

// ---------------- K3: xop = LN(hv2, op_g, op_beta) @ W1 + b1 ------------------
__global__ __launch_bounds__(256) void k_xop(
    const float* __restrict__ hv2, const float* __restrict__ W1,
    const float* __restrict__ b1, const float* __restrict__ opg,
    const float* __restrict__ opb, float* __restrict__ xop)
{
    __shared__ float y[Hh];
    __shared__ float red[4];
    const int bn = blockIdx.x, t = threadIdx.x;
    float x = (t < Hh) ? hv2[(size_t)bn * Hh + t] : 0.f;
    float mu = blocksum((t < Hh) ? x : 0.f, red) * (1.f / Hh);
    float dx = (t < Hh) ? (x - mu) : 0.f;
    float var = blocksum(dx * dx, red) * (1.f / Hh);
    if (t < Hh) y[t] = opg[t] * dx / sqrtf(var + 1e-5f) + opb[t];
    __syncthreads();
    if (t < Hh) {
        float a = b1[t];
        for (int i = 0; i < Hh; ++i) a += y[i] * W1[i * Hh + t];
        xop[(size_t)bn * Hh + t] = a;
    }
}

// ---------------- K4: h_E1 = h_E + (x ⊙ x[nbr]) @ W2 + b2 -> outE -------------
__global__ __launch_bounds__(256) void k_outer(
    const float* __restrict__ xop, const float* __restrict__ hE,
    const int* __restrict__ Eidx, const float* __restrict__ W2,
    const float* __restrict__ b2, float* __restrict__ outE)
{
    __shared__ float W2s[Hh][Hh];   // 64 KB
    __shared__ float xc[Hh];
    __shared__ float ou[2][Hh];
    const int bn = blockIdx.x, t = threadIdx.x;
    const int b = bn >> 11;          // N = 2048
    for (int i = t; i < Hh * Hh; i += 256) W2s[i >> 7][i & 127] = W2[i];
    if (t < Hh) xc[t] = xop[(size_t)bn * Hh + t];
    __syncthreads();
    const int c = t & 127, half = t >> 7;
    for (int kk = 0; kk < Kk; kk += 2) {
        int k = kk + half;
        int idx = Eidx[(size_t)bn * Kk + k];
        ou[half][c] = xc[c] * xop[((size_t)b * Nn + idx) * Hh + c];
        __syncthreads();
        float a = b2[c];
        for (int h = 0; h < Hh; ++h) a += ou[half][h] * W2s[h][c];
        size_t o = ((size_t)bn * Kk + k) * Hh + c;
        outE[o] = hE[o] + a;
        __syncthreads();
    }
}

// ---------------- K5: edge self-attention + gelu + residual + LN(n3), in place
__global__ __launch_bounds__(256) void k_edge_attn(
    const float* __restrict__ maskA,
    const float* __restrict__ WKg, const float* __restrict__ WVg,
    const float* __restrict__ WOg,
    const float* __restrict__ n3g, const float* __restrict__ n3b,
    float* __restrict__ outE)
{
    __shared__ float T[Kk][Hh + 1];
    __shared__ float Qe[Kk][Hh + 1];
    __shared__ float Ke[Kk][Hh + 1];
    __shared__ float Ve[Kk][Hh + 1];
    __shared__ float Le[NH_][Kk][Kk + 1];
    __shared__ float Pe[NH_][Kk][Kk + 1];
    __shared__ float ms[Kk];
    __shared__ float mu_[Kk], isd_[Kk];

    const int bn = blockIdx.x, t = threadIdx.x;
    float* ep = outE + (size_t)bn * (Kk * Hh);
    for (int i = t; i < Kk * Hh; i += 256) T[i >> 7][i & 127] = ep[i];
    if (t < Kk) ms[t] = maskA[(size_t)bn * Kk + t];
    __syncthreads();

    // Q = T@WO (faithful to original), K = T@WK, V = T@WV
    {
        const int c = t & 127, half = t >> 7;
        float aQ[16], aK[16], aV[16];
        #pragma unroll
        for (int k = 0; k < 16; ++k) { aQ[k] = 0.f; aK[k] = 0.f; aV[k] = 0.f; }
        for (int i = 0; i < Hh; ++i) {
            float wq = WOg[i * Hh + c], wk = WKg[i * Hh + c], wv = WVg[i * Hh + c];
            #pragma unroll
            for (int k = 0; k < 16; ++k) {
                float e = T[half * 16 + k][i];
                aQ[k] += e * wq; aK[k] += e * wk; aV[k] += e * wv;
            }
        }
        #pragma unroll
        for (int k = 0; k < 16; ++k) {
            Qe[half * 16 + k][c] = aQ[k];
            Ke[half * 16 + k][c] = aK[k];
            Ve[half * 16 + k][c] = aV[k];
        }
    }
    __syncthreads();

    // raw einsum logits Le[h][q][k], with .view remap [K,H] -> [NH,K,d]
    for (int o = t; o < NH_ * Kk * Kk; o += 256) {
        int h = o >> 10, q = (o >> 5) & 31, k = o & 31;
        const float* qrow = &Qe[(h << 3) | (q >> 2)][(q & 3) << 5];
        const float* krow = &Ke[(h << 3) | (k >> 2)][(k & 3) << 5];
        float a = 0.f;
        #pragma unroll
        for (int d = 0; d < Dd; ++d) a += qrow[d] * krow[d];
        Le[h][q][k] = a;
    }
    __syncthreads();

    // reshaped+swapped logits, masked softmax over c (no post-mask here)
    if (t < NH_ * Kk) {
        int a = t >> 5, q2 = t & 31;
        float mq = ms[q2];
        float l[Kk];
        float mx = NEGF;
        #pragma unroll
        for (int c = 0; c < Kk; ++c) {
            float lg = Le[c >> 3][((c & 7) << 2) | (q2 >> 3)][((q2 & 7) << 2) | a]
                       * 0.17677669529663687f;
            l[c] = (mq * ms[c] > 0.f) ? lg : NEGF;
            mx = fmaxf(mx, l[c]);
        }
        float s = 0.f;
        #pragma unroll
        for (int c = 0; c < Kk; ++c) { l[c] = expf(l[c] - mx); s += l[c]; }
        float inv = 1.f / s;
        #pragma unroll
        for (int c = 0; c < Kk; ++c) Pe[a][q2][c] = l[c] * inv;
    }
    __syncthreads();

    // PV with V remap; write O2[q2][a*32+dd] into Ke (free now)
    for (int o = t; o < NH_ * Kk * Dd; o += 256) {
        int a = o >> 10, q2 = (o >> 5) & 31, dd = o & 31;
        float acc = 0.f;
        #pragma unroll
        for (int c = 0; c < Kk; ++c)
            acc += Pe[a][q2][c] * Ve[(a << 3) | (c >> 2)][((c & 3) << 5) | dd];
        Ke[q2][(a << 5) | dd] = acc;
    }
    __syncthreads();

    // dh = gelu(O2 @ WO); x2 = T + dh -> Qe
    {
        const int c = t & 127, half = t >> 7;
        float acc[16];
        #pragma unroll
        for (int k = 0; k < 16; ++k) acc[k] = 0.f;
        for (int i = 0; i < Hh; ++i) {
            float w = WOg[i * Hh + c];
            #pragma unroll
            for (int k = 0; k < 16; ++k) acc[k] += Ke[half * 16 + k][i] * w;
        }
        #pragma unroll
        for (int k = 0; k < 16; ++k) {
            int r = half * 16 + k;
            Qe[r][c] = T[r][c] + gelu_f(acc[k]);
        }
    }
    __syncthreads();
    // LN(n3) per row
    if (t < Kk) {
        float s = 0.f;
        for (int i = 0; i < Hh; ++i) s += Qe[t][i];
        float mu = s * (1.f / Hh);
        float v = 0.f;
        for (int i = 0; i < Hh; ++i) { float d = Qe[t][i] - mu; v += d * d; }
        mu_[t] = mu; isd_[t] = 1.f / sqrtf(v * (1.f / Hh) + 1e-5f);
    }
    __syncthreads();
    for (int o = t; o < Kk * Hh; o += 256) {
        int r = o >> 7, c2 = o & 127;
        ep[o] = n3g[c2] * (Qe[r][c2] - mu_[r]) * isd_[r] + n3b[c2];
    }
}

// ---------------- K6: edge FFN + gelu + residual + LN(n4), in place -----------
__global__ __launch_bounds__(256) void k_edge_ffn(
    const float* __restrict__ Win, const float* __restrict__ bin,
    const float* __restrict__ Wout, const float* __restrict__ bout,
    const float* __restrict__ n4g, const float* __restrict__ n4b,
    float* __restrict__ outE)
{
    __shared__ float X[Kk][Hh + 1];
    __shared__ float Hd[Kk][DFFh + 1];   // ~66 KB
    __shared__ float mu_[Kk], isd_[Kk];
    const int bn = blockIdx.x, t = threadIdx.x;
    float* ep = outE + (size_t)bn * (Kk * Hh);
    for (int i = t; i < Kk * Hh; i += 256) X[i >> 7][i & 127] = ep[i];
    __syncthreads();
    // stage 1: hidden = gelu(X @ Win + bin); thread owns cols t and t+256
    {
        float a0[Kk], a1[Kk];
        #pragma unroll
        for (int k = 0; k < Kk; ++k) { a0[k] = 0.f; a1[k] = 0.f; }
        for (int i = 0; i < Hh; ++i) {
            float w0 = Win[i * DFFh + t], w1 = Win[i * DFFh + t + 256];
            #pragma unroll
            for (int k = 0; k < Kk; ++k) {
                float e = X[k][i];
                a0[k] += e * w0; a1[k] += e * w1;
            }
        }
        float bi0 = bin[t], bi1 = bin[t + 256];
        #pragma unroll
        for (int k = 0; k < Kk; ++k) {
            Hd[k][t] = gelu_f(a0[k] + bi0);
            Hd[k][t + 256] = gelu_f(a1[k] + bi1);
        }
    }
    __syncthreads();
    // stage 2: out = gelu(hidden @ Wout + bout) + residual
    {
        const int c = t & 127, half = t >> 7;
        float acc[16];
        #pragma unroll
        for (int k = 0; k < 16; ++k) acc[k] = 0.f;
        for (int i = 0; i < DFFh; ++i) {
            float w = Wout[i * Hh + c];
            #pragma unroll
            for (int k = 0; k < 16; ++k) acc[k] += Hd[half * 16 + k][i] * w;
        }
        float bo = bout[c];
        #pragma unroll
        for (int k = 0; k < 16; ++k) {
            int r = half * 16 + k;
            X[r][c] = X[r][c] + gelu_f(acc[k] + bo);
        }
    }
    __syncthreads();
    if (t < Kk) {
        float s = 0.f;
        for (int i = 0; i < Hh; ++i) s += X[t][i];
        float mu = s * (1.f / Hh);
        float v = 0.f;
        for (int i = 0; i < Hh; ++i) { float d = X[t][i] - mu; v += d * d; }
        mu_[t] = mu; isd_[t] = 1.f / sqrtf(v * (1.f / Hh) + 1e-5f);
    }
    __syncthreads();
    for (int o = t; o < Kk * Hh; o += 256) {
        int r = o >> 7, c2 = o & 127;
        ep[o] = n4g[c2] * (X[r][c2] - mu_[r]) * isd_[r] + n4b[c2];
    }
}

extern "C" void kernel_launch(void* const* d_in, const int* in_sizes, int n_in,
                              void* d_out, int out_size, void* d_ws, size_t ws_size,
                              hipStream_t stream) {
    const float* hV     = (const float*)d_in[0];
    const float* hE     = (const float*)d_in[1];
    const float* hEV    = (const float*)d_in[2];
    const float* maskV  = (const float*)d_in[3];
    const float* maskA  = (const float*)d_in[4];
    const float* naWQ   = (const float*)d_in[5];
    const float* naWK   = (const float*)d_in[6];
    const float* naWV   = (const float*)d_in[7];
    const float* naWO   = (const float*)d_in[8];
    const float* eaWK   = (const float*)d_in[9];
    const float* eaWV   = (const float*)d_in[10];
    const float* eaWO   = (const float*)d_in[11];
    const float* d1Win  = (const float*)d_in[12];
    const float* d1bin  = (const float*)d_in[13];
    const float* d1Wout = (const float*)d_in[14];
    const float* d1bout = (const float*)d_in[15];
    const float* d2Win  = (const float*)d_in[16];
    const float* d2bin  = (const float*)d_in[17];
    const float* d2Wout = (const float*)d_in[18];
    const float* d2bout = (const float*)d_in[19];
    const float* opW1   = (const float*)d_in[20];
    const float* opb1   = (const float*)d_in[21];
    const float* opW2   = (const float*)d_in[22];
    const float* opb2   = (const float*)d_in[23];
    const float* opg    = (const float*)d_in[24];
    const float* opbeta = (const float*)d_in[25];
    const float* n1g    = (const float*)d_in[26];
    const float* n1b    = (const float*)d_in[27];
    const float* n3g    = (const float*)d_in[28];
    const float* n3b    = (const float*)d_in[29];
    const float* n4g    = (const float*)d_in[30];
    const float* n4b    = (const float*)d_in[31];
    const int*   Eidx   = (const int*)d_in[32];

    float* outV = (float*)d_out;
    float* outE = outV + (size_t)Bb * Nn * Hh;
    float* scratch = (float*)d_ws;   // 4 MB, reused: hv1 then xop

    dim3 grid(Bb * Nn), blk(256);
    k_node_attn<<<grid, blk, 0, stream>>>(hV, hEV, maskA, naWQ, naWK, naWV, naWO,
                                          n1g, n1b, scratch);
    k_node_ffn<<<grid, blk, 0, stream>>>(scratch, maskV, d1Win, d1bin, d1Wout,
                                         d1bout, n1g, n1b, outV);
    k_xop<<<grid, blk, 0, stream>>>(outV, opW1, opb1, opg, opbeta, scratch);
    k_outer<<<grid, blk, 0, stream>>>(scratch, hE, Eidx, opW2, opb2, outE);
    k_edge_attn<<<grid, blk, 0, stream>>>(maskA, eaWK, eaWV, eaWO, n3g, n3b, outE);
    k_edge_ffn<<<grid, blk, 0, stream>>>(d2Win, d2bin, d2Wout, d2bout, n4g, n4b, outE);
}

// Round 2
// 1377.177 us; speedup vs baseline: 4.2082x; 4.2082x over previous
//
#include <hip/hip_runtime.h>
#include <math.h>

#define Bb 4
#define Nn 2048
#define Kk 32
#define Hh 128
#define NIi 256
#define NH_ 4
#define Dd 32
#define DFFh 512

#define NEGF -3.402823466e38f

typedef unsigned short u16;
typedef __attribute__((ext_vector_type(8))) short bf16x8;
typedef __attribute__((ext_vector_type(4))) float f32x4;

// bf16 weight buffer offsets (in elements), base = d_ws + 2MB
#define OFF_NAWKT   0        // [128][256]
#define OFF_NAWVT   32768    // [128][256]
#define OFF_EAWKT   65536    // [128][128]
#define OFF_EAWVT   81920    // [128][128]
#define OFF_EAWOT   98304    // [128][128]
#define OFF_D2WINT  114688   // [512][128]
#define OFF_D2WOUTT 180224   // [128][512]
#define OFF_OPW2T   245760   // [128][128]
#define WB_TOTAL    262144

__device__ __forceinline__ float gelu_f(float x) {
    return 0.5f * x * (1.0f + erff(x * 0.7071067811865476f));
}

__device__ __forceinline__ u16 f2bf(float f) {
    union { float f; unsigned int u; } v; v.f = f;
    unsigned int r = v.u + 0x7FFFu + ((v.u >> 16) & 1u);   // RNE
    return (u16)(r >> 16);
}

__device__ __forceinline__ float bf2f(u16 u) {
    union { unsigned int u; float f; } v; v.u = ((unsigned int)u) << 16;
    return v.f;
}

__device__ __forceinline__ float blocksum(float v, float* red) {
    int t = threadIdx.x;
    #pragma unroll
    for (int m = 32; m; m >>= 1) v += __shfl_xor(v, m, 64);
    __syncthreads();
    if ((t & 63) == 0) red[t >> 6] = v;
    __syncthreads();
    return red[0] + red[1] + red[2] + red[3];
}

// ---------------- K0: convert + transpose weights to bf16 in ws ---------------
__global__ __launch_bounds__(256) void k_prep(
    const float* __restrict__ naWK, const float* __restrict__ naWV,
    const float* __restrict__ eaWK, const float* __restrict__ eaWV,
    const float* __restrict__ eaWO, const float* __restrict__ d2Win,
    const float* __restrict__ d2Wout, const float* __restrict__ opW2,
    u16* __restrict__ wb)
{
    int i = blockIdx.x * 256 + threadIdx.x;
    const float* src; int R, C, off;
    if (i < 32768)       { src = naWK;   R = 256; C = 128; off = OFF_NAWKT; }
    else if (i < 65536)  { src = naWV;   R = 256; C = 128; off = OFF_NAWVT; }
    else if (i < 81920)  { src = eaWK;   R = 128; C = 128; off = OFF_EAWKT; }
    else if (i < 98304)  { src = eaWV;   R = 128; C = 128; off = OFF_EAWVT; }
    else if (i < 114688) { src = eaWO;   R = 128; C = 128; off = OFF_EAWOT; }
    else if (i < 180224) { src = d2Win;  R = 128; C = 512; off = OFF_D2WINT; }
    else if (i < 245760) { src = d2Wout; R = 512; C = 128; off = OFF_D2WOUTT; }
    else                 { src = opW2;   R = 128; C = 128; off = OFF_OPW2T; }
    int j = i - off;
    int c = j / R, r = j - c * R;       // dest W^T[C][R]: row c, col r
    wb[i] = f2bf(src[r * C + c]);
}

// ---------------- K1: neighbor attention + gelu + residual + LN(n1) -> hv1 ----
__global__ __launch_bounds__(256) void k_node_attn(
    const float* __restrict__ hV, const float* __restrict__ hEV,
    const float* __restrict__ maskA,
    const float* __restrict__ WQ, const u16* __restrict__ wb,
    const float* __restrict__ WO,
    const float* __restrict__ n1g, const float* __restrict__ n1b,
    float* __restrict__ hv1)
{
    __shared__ __align__(16) short EVb[32 * 264];   // bf16 EV, stride 264
    __shared__ __align__(16) float Kt[32][129];
    __shared__ __align__(16) float Vt[32][129];
    __shared__ float Qs[128], hvr[128], att[NH_][Kk], outr[128], red[4];

    const int bn = blockIdx.x, t = threadIdx.x;
    const int w = t >> 6, l = t & 63, l15 = l & 15, lq = l >> 4;
    const float* evp = hEV + (size_t)bn * (Kk * NIi);
    for (int i = t; i < Kk * NIi; i += 256)
        EVb[(i >> 8) * 264 + (i & 255)] = (short)f2bf(evp[i]);
    if (t < Hh) hvr[t] = hV[(size_t)bn * Hh + t];
    __syncthreads();

    // K = EV @ WK, V = EV @ WV via MFMA (B = W^T bf16)
    #pragma unroll
    for (int i = 0; i < 8; ++i) {
        int id = w + 4 * i;              // 0..31
        int mat = id >> 4, rem = id & 15;
        int m0 = (rem >> 3) << 4, n0 = (rem & 7) << 4;
        const u16* Bp = wb + (mat ? OFF_NAWVT : OFF_NAWKT);
        f32x4 acc = {0.f, 0.f, 0.f, 0.f};
        #pragma unroll
        for (int kt = 0; kt < 8; ++kt) {
            bf16x8 a = *(const bf16x8*)&EVb[(m0 + l15) * 264 + kt * 32 + lq * 8];
            bf16x8 b = *(const bf16x8*)(Bp + (size_t)(n0 + l15) * 256 + kt * 32 + lq * 8);
            acc = __builtin_amdgcn_mfma_f32_16x16x32_bf16(a, b, acc, 0, 0, 0);
        }
        int col = n0 + l15;
        float* dst = mat ? &Vt[0][0] : &Kt[0][0];
        #pragma unroll
        for (int r = 0; r < 4; ++r)
            dst[(m0 + lq * 4 + r) * 129 + col] = acc[r];
    }
    // Q = hv_row @ WQ (fp32, tiny)
    if (t < Hh) {
        float a = 0.f;
        for (int i = 0; i < Hh; ++i) a += hvr[i] * WQ[i * Hh + t];
        Qs[t] = a;
    }
    __syncthreads();

    if (t < NH_ * Kk) {
        int nh = t >> 5, k = t & 31;
        float a = 0.f;
        #pragma unroll
        for (int d = 0; d < Dd; ++d) a += Qs[nh * Dd + d] * Kt[k][nh * Dd + d];
        att[nh][k] = a * 0.17677669529663687f;
    }
    __syncthreads();
    if (t < NH_) {
        const float* m = maskA + (size_t)bn * Kk;
        float lv[Kk];
        float mx = NEGF;
        #pragma unroll
        for (int k = 0; k < Kk; ++k) {
            lv[k] = (m[k] > 0.f) ? att[t][k] : NEGF;
            mx = fmaxf(mx, lv[k]);
        }
        float s = 0.f;
        #pragma unroll
        for (int k = 0; k < Kk; ++k) { lv[k] = expf(lv[k] - mx); s += lv[k]; }
        float inv = 1.f / s;
        #pragma unroll
        for (int k = 0; k < Kk; ++k) att[t][k] = m[k] * lv[k] * inv;
    }
    __syncthreads();
    if (t < Hh) {
        int nh = t >> 5, d = t & 31;
        float a = 0.f;
        #pragma unroll
        for (int k = 0; k < Kk; ++k) a += att[nh][k] * Vt[k][nh * Dd + d];
        outr[t] = a;
    }
    __syncthreads();
    float x = 0.f;
    if (t < Hh) {
        float a = 0.f;
        for (int h = 0; h < Hh; ++h) a += outr[h] * WO[h * Hh + t];
        x = hvr[t] + gelu_f(a);
    }
    float mu = blocksum((t < Hh) ? x : 0.f, red) * (1.f / Hh);
    float dx = (t < Hh) ? (x - mu) : 0.f;
    float var = blocksum(dx * dx, red) * (1.f / Hh);
    if (t < Hh)
        hv1[(size_t)bn * Hh + t] = n1g[t] * dx / sqrtf(var + 1e-5f) + n1b[t];
}

// ---------------- K2: FFN1 + gelu + residual + LN(n1) + mask, in-place on hv --
__global__ __launch_bounds__(256) void k_node_ffn(
    float* __restrict__ hv, const float* __restrict__ maskV,
    const float* __restrict__ Win, const float* __restrict__ bin,
    const float* __restrict__ Wout, const float* __restrict__ bout,
    const float* __restrict__ n1g, const float* __restrict__ n1b)
{
    __shared__ float xr[Hh];
    __shared__ float hid[DFFh];
    __shared__ float red[4];
    const int bn = blockIdx.x, t = threadIdx.x;
    if (t < Hh) xr[t] = hv[(size_t)bn * Hh + t];
    __syncthreads();
    {
        float a0 = 0.f, a1 = 0.f;
        for (int i = 0; i < Hh; ++i) {
            float xi = xr[i];
            a0 += xi * Win[i * DFFh + t];
            a1 += xi * Win[i * DFFh + t + 256];
        }
        hid[t] = gelu_f(a0 + bin[t]);
        hid[t + 256] = gelu_f(a1 + bin[t + 256]);
    }
    __syncthreads();
    float x = 0.f;
    if (t < Hh) {
        float a = bout[t];
        for (int i = 0; i < DFFh; ++i) a += hid[i] * Wout[i * Hh + t];
        x = xr[t] + gelu_f(a);
    }
    float mu = blocksum((t < Hh) ? x : 0.f, red) * (1.f / Hh);
    float dx = (t < Hh) ? (x - mu) : 0.f;
    float var = blocksum(dx * dx, red) * (1.f / Hh);
    if (t < Hh) {
        float v = n1g[t] * dx / sqrtf(var + 1e-5f) + n1b[t];
        hv[(size_t)bn * Hh + t] = maskV[bn] * v;
    }
}

// ---------------- K3: xop = LN(hv2, op_g, op_beta) @ W1 + b1 (bf16 out) -------
__global__ __launch_bounds__(256) void k_xop(
    const float* __restrict__ hv2, const float* __restrict__ W1,
    const float* __restrict__ b1, const float* __restrict__ opg,
    const float* __restrict__ opb, u16* __restrict__ xop)
{
    __shared__ float y[Hh];
    __shared__ float red[4];
    const int bn = blockIdx.x, t = threadIdx.x;
    float x = (t < Hh) ? hv2[(size_t)bn * Hh + t] : 0.f;
    float mu = blocksum((t < Hh) ? x : 0.f, red) * (1.f / Hh);
    float dx = (t < Hh) ? (x - mu) : 0.f;
    float var = blocksum(dx * dx, red) * (1.f / Hh);
    if (t < Hh) y[t] = opg[t] * dx / sqrtf(var + 1e-5f) + opb[t];
    __syncthreads();
    if (t < Hh) {
        float a = b1[t];
        for (int i = 0; i < Hh; ++i) a += y[i] * W1[i * Hh + t];
        xop[(size_t)bn * Hh + t] = f2bf(a);
    }
}

// ---------------- K4: h_E1 = h_E + (x ⊙ x[nbr]) @ W2 + b2 -> outE (MFMA) ------
__global__ __launch_bounds__(256) void k_outer(
    const u16* __restrict__ xop, const float* __restrict__ hE,
    const int* __restrict__ Eidx, const u16* __restrict__ wb,
    const float* __restrict__ b2, float* __restrict__ outE)
{
    __shared__ __align__(16) short A1[32 * 136];
    __shared__ float xcf[128];
    __shared__ int idxs[32];
    const int bn = blockIdx.x, t = threadIdx.x;
    const int b = bn >> 11;
    const int w = t >> 6, l = t & 63, l15 = l & 15, lq = l >> 4;
    if (t < 128) xcf[t] = bf2f(xop[(size_t)bn * 128 + t]);
    if (t < 32) idxs[t] = Eidx[(size_t)bn * 32 + t];
    __syncthreads();
    for (int i = t; i < 4096; i += 256) {
        int k = i >> 7, h = i & 127;
        float nb = bf2f(xop[((size_t)b * Nn + idxs[k]) * 128 + h]);
        A1[k * 136 + h] = (short)f2bf(xcf[h] * nb);
    }
    __syncthreads();
    const u16* Bp = wb + OFF_OPW2T;
    #pragma unroll
    for (int i = 0; i < 4; ++i) {
        int id = w + 4 * i, m0 = (id >> 3) << 4, n0 = (id & 7) << 4;
        f32x4 acc = {0.f, 0.f, 0.f, 0.f};
        #pragma unroll
        for (int kt = 0; kt < 4; ++kt) {
            bf16x8 a = *(const bf16x8*)&A1[(m0 + l15) * 136 + kt * 32 + lq * 8];
            bf16x8 bv = *(const bf16x8*)(Bp + (size_t)(n0 + l15) * 128 + kt * 32 + lq * 8);
            acc = __builtin_amdgcn_mfma_f32_16x16x32_bf16(a, bv, acc, 0, 0, 0);
        }
        int col = n0 + l15;
        float bb = b2[col];
        #pragma unroll
        for (int r = 0; r < 4; ++r) {
            int row = m0 + lq * 4 + r;
            size_t o = (size_t)bn * 4096 + row * 128 + col;
            outE[o] = hE[o] + acc[r] + bb;
        }
    }
}

// ---------------- K5: edge self-attention + gelu + residual + LN(n3), in place
__global__ __launch_bounds__(256) void k_edge_attn(
    const float* __restrict__ maskA, const u16* __restrict__ wb,
    const float* __restrict__ n3g, const float* __restrict__ n3b,
    float* __restrict__ outE)
{
    __shared__ __align__(16) float Xf[32][129];
    __shared__ __align__(16) short A1[32 * 136];     // X bf16; later O2
    __shared__ __align__(16) short QeP[5120];        // Qe [32][136]; later Pe [4][32][40]
    __shared__ __align__(16) short Ke[32 * 136];
    __shared__ __align__(16) short Vp[4 * 32 * 40];  // V''[a][dd][c]
    __shared__ __align__(16) float Le[NH_][Kk][Kk + 1];
    __shared__ float ms[32];
    __shared__ float mu_[32], isd_[32];

    const int bn = blockIdx.x, t = threadIdx.x;
    const int w = t >> 6, l = t & 63, l15 = l & 15, lq = l >> 4;
    float* ep = outE + (size_t)bn * 4096;

    for (int i = t; i < 4096; i += 256) {
        float v = ep[i];
        Xf[i >> 7][i & 127] = v;
        A1[(i >> 7) * 136 + (i & 127)] = (short)f2bf(v);
    }
    if (t < 32) ms[t] = maskA[(size_t)bn * 32 + t];
    __syncthreads();

    // Projections: Q = X@WO (faithful), K = X@WK, V = X@WV. 48 tiles.
    #pragma unroll
    for (int i = 0; i < 12; ++i) {
        int id = w + 4 * i;                 // 0..47
        int mat = id >> 4, rem = id & 15;
        int m0 = (rem >> 3) << 4, n0 = (rem & 7) << 4;
        const u16* Bp = wb + ((mat == 0) ? OFF_EAWOT : (mat == 1) ? OFF_EAWKT : OFF_EAWVT);
        f32x4 acc = {0.f, 0.f, 0.f, 0.f};
        #pragma unroll
        for (int kt = 0; kt < 4; ++kt) {
            bf16x8 a = *(const bf16x8*)&A1[(m0 + l15) * 136 + kt * 32 + lq * 8];
            bf16x8 bv = *(const bf16x8*)(Bp + (size_t)(n0 + l15) * 128 + kt * 32 + lq * 8);
            acc = __builtin_amdgcn_mfma_f32_16x16x32_bf16(a, bv, acc, 0, 0, 0);
        }
        int col = n0 + l15;
        #pragma unroll
        for (int r = 0; r < 4; ++r) {
            int row = m0 + lq * 4 + r;
            u16 hv = f2bf(acc[r]);
            if (mat == 0) QeP[row * 136 + col] = (short)hv;
            else if (mat == 1) Ke[row * 136 + col] = (short)hv;
            else Vp[((row >> 3) * 32 + (col & 31)) * 40 + (((row & 7) << 2) | (col >> 5))] = (short)hv;
        }
    }
    __syncthreads();

    // logits via MFMA over d=32: Le[h][q][k]
    #pragma unroll
    for (int i = 0; i < 4; ++i) {
        int id = w + 4 * i;                 // 0..15
        int h = id >> 2, rem = id & 3;
        int q0 = (rem >> 1) << 4, k0 = (rem & 1) << 4;
        int q = q0 + l15, k = k0 + l15;
        bf16x8 a = *(const bf16x8*)&QeP[(((h << 3) | (q >> 2)) * 136) + (((q & 3) << 5) + lq * 8)];
        bf16x8 bv = *(const bf16x8*)&Ke[(((h << 3) | (k >> 2)) * 136) + (((k & 3) << 5) + lq * 8)];
        f32x4 acc = {0.f, 0.f, 0.f, 0.f};
        acc = __builtin_amdgcn_mfma_f32_16x16x32_bf16(a, bv, acc, 0, 0, 0);
        #pragma unroll
        for (int r = 0; r < 4; ++r)
            Le[h][q0 + lq * 4 + r][k0 + l15] = acc[r];
    }
    __syncthreads();

    // masked softmax (reshape+swap semantics), write Pe bf16 into QeP region
    if (t < 128) {
        int a = t >> 5, q2 = t & 31;
        float mq = ms[q2];
        float lv[Kk];
        float mx = NEGF;
        #pragma unroll
        for (int c = 0; c < Kk; ++c) {
            float lg = Le[c >> 3][((c & 7) << 2) | (q2 >> 3)][((q2 & 7) << 2) | a]
                       * 0.17677669529663687f;
            lv[c] = (mq * ms[c] > 0.f) ? lg : NEGF;
            mx = fmaxf(mx, lv[c]);
        }
        float s = 0.f;
        #pragma unroll
        for (int c = 0; c < Kk; ++c) { lv[c] = expf(lv[c] - mx); s += lv[c]; }
        float inv = 1.f / s;
        #pragma unroll
        for (int c = 0; c < Kk; ++c)
            QeP[((a * 32 + q2) * 40) + c] = (short)f2bf(lv[c] * inv);
    }
    __syncthreads();

    // PV via MFMA over c=32: O2[q2][(a<<5)+dd] into A1 region
    #pragma unroll
    for (int i = 0; i < 4; ++i) {
        int id = w + 4 * i;
        int a = id >> 2, rem = id & 3;
        int q0 = (rem >> 1) << 4, d0 = (rem & 1) << 4;
        bf16x8 pa = *(const bf16x8*)&QeP[((a * 32 + q0 + l15) * 40) + lq * 8];
        bf16x8 vb = *(const bf16x8*)&Vp[((a * 32 + d0 + l15) * 40) + lq * 8];
        f32x4 acc = {0.f, 0.f, 0.f, 0.f};
        acc = __builtin_amdgcn_mfma_f32_16x16x32_bf16(pa, vb, acc, 0, 0, 0);
        #pragma unroll
        for (int r = 0; r < 4; ++r)
            A1[(q0 + lq * 4 + r) * 136 + (a << 5) + d0 + l15] = (short)f2bf(acc[r]);
    }
    __syncthreads();

    // final: dh = gelu(O2 @ WO); Xf += dh
    const u16* Bo = wb + OFF_EAWOT;
    #pragma unroll
    for (int i = 0; i < 4; ++i) {
        int id = w + 4 * i;
        int m0 = (id >> 3) << 4, n0 = (id & 7) << 4;
        f32x4 acc = {0.f, 0.f, 0.f, 0.f};
        #pragma unroll
        for (int kt = 0; kt < 4; ++kt) {
            bf16x8 a = *(const bf16x8*)&A1[(m0 + l15) * 136 + kt * 32 + lq * 8];
            bf16x8 bv = *(const bf16x8*)(Bo + (size_t)(n0 + l15) * 128 + kt * 32 + lq * 8);
            acc = __builtin_amdgcn_mfma_f32_16x16x32_bf16(a, bv, acc, 0, 0, 0);
        }
        int col = n0 + l15;
        #pragma unroll
        for (int r = 0; r < 4; ++r) {
            int row = m0 + lq * 4 + r;
            Xf[row][col] += gelu_f(acc[r]);
        }
    }
    __syncthreads();

    if (t < 32) {
        float s = 0.f;
        for (int i = 0; i < Hh; ++i) s += Xf[t][i];
        float mu = s * (1.f / Hh);
        float v = 0.f;
        for (int i = 0; i < Hh; ++i) { float d = Xf[t][i] - mu; v += d * d; }
        mu_[t] = mu; isd_[t] = 1.f / sqrtf(v * (1.f / Hh) + 1e-5f);
    }
    __syncthreads();
    for (int o = t; o < 4096; o += 256) {
        int r = o >> 7, c2 = o & 127;
        ep[o] = n3g[c2] * (Xf[r][c2] - mu_[r]) * isd_[r] + n3b[c2];
    }
}

// ---------------- K6: edge FFN + gelu + residual + LN(n4), in place (MFMA) ----
__global__ __launch_bounds__(256) void k_edge_ffn(
    const u16* __restrict__ wb, const float* __restrict__ bin,
    const float* __restrict__ bout,
    const float* __restrict__ n4g, const float* __restrict__ n4b,
    float* __restrict__ outE)
{
    __shared__ __align__(16) float Xf[32][129];
    __shared__ __align__(16) short A1[32 * 136];
    __shared__ __align__(16) short Hd[32 * 520];
    __shared__ float mu_[32], isd_[32];
    const int bn = blockIdx.x, t = threadIdx.x;
    const int w = t >> 6, l = t & 63, l15 = l & 15, lq = l >> 4;
    float* ep = outE + (size_t)bn * 4096;
    for (int i = t; i < 4096; i += 256) {
        float v = ep[i];
        Xf[i >> 7][i & 127] = v;
        A1[(i >> 7) * 136 + (i & 127)] = (short)f2bf(v);
    }
    __syncthreads();

    // stage 1: Hd = gelu(X @ Win + bin), N=512, K=128
    const u16* Bw = wb + OFF_D2WINT;
    bf16x8 aA[2][4];
    #pragma unroll
    for (int m = 0; m < 2; ++m)
        #pragma unroll
        for (int kt = 0; kt < 4; ++kt)
            aA[m][kt] = *(const bf16x8*)&A1[(m * 16 + l15) * 136 + kt * 32 + lq * 8];
    for (int nt = 0; nt < 8; ++nt) {
        int n0 = (w * 8 + nt) * 16;
        bf16x8 bB[4];
        #pragma unroll
        for (int kt = 0; kt < 4; ++kt)
            bB[kt] = *(const bf16x8*)(Bw + (size_t)(n0 + l15) * 128 + kt * 32 + lq * 8);
        int col = n0 + l15;
        float bi = bin[col];
        #pragma unroll
        for (int m = 0; m < 2; ++m) {
            f32x4 acc = {0.f, 0.f, 0.f, 0.f};
            #pragma unroll
            for (int kt = 0; kt < 4; ++kt)
                acc = __builtin_amdgcn_mfma_f32_16x16x32_bf16(aA[m][kt], bB[kt], acc, 0, 0, 0);
            #pragma unroll
            for (int r = 0; r < 4; ++r)
                Hd[(m * 16 + lq * 4 + r) * 520 + col] = (short)f2bf(gelu_f(acc[r] + bi));
        }
    }
    __syncthreads();

    // stage 2: X += gelu(Hd @ Wout + bout), N=128, K=512
    const u16* Bo = wb + OFF_D2WOUTT;
    #pragma unroll
    for (int ni = 0; ni < 2; ++ni) {
        int n0 = (w + ni * 4) * 16;
        int col = n0 + l15;
        float bo = bout[col];
        #pragma unroll
        for (int m = 0; m < 2; ++m) {
            f32x4 acc = {0.f, 0.f, 0.f, 0.f};
            #pragma unroll
            for (int kt = 0; kt < 16; ++kt) {
                bf16x8 a = *(const bf16x8*)&Hd[(m * 16 + l15) * 520 + kt * 32 + lq * 8];
                bf16x8 bv = *(const bf16x8*)(Bo + (size_t)col * 512 + kt * 32 + lq * 8);
                acc = __builtin_amdgcn_mfma_f32_16x16x32_bf16(a, bv, acc, 0, 0, 0);
            }
            #pragma unroll
            for (int r = 0; r < 4; ++r) {
                int row = m * 16 + lq * 4 + r;
                Xf[row][col] += gelu_f(acc[r] + bo);
            }
        }
    }
    __syncthreads();

    if (t < 32) {
        float s = 0.f;
        for (int i = 0; i < Hh; ++i) s += Xf[t][i];
        float mu = s * (1.f / Hh);
        float v = 0.f;
        for (int i = 0; i < Hh; ++i) { float d = Xf[t][i] - mu; v += d * d; }
        mu_[t] = mu; isd_[t] = 1.f / sqrtf(v * (1.f / Hh) + 1e-5f);
    }
    __syncthreads();
    for (int o = t; o < 4096; o += 256) {
        int r = o >> 7, c2 = o & 127;
        ep[o] = n4g[c2] * (Xf[r][c2] - mu_[r]) * isd_[r] + n4b[c2];
    }
}

extern "C" void kernel_launch(void* const* d_in, const int* in_sizes, int n_in,
                              void* d_out, int out_size, void* d_ws, size_t ws_size,
                              hipStream_t stream) {
    const float* hV     = (const float*)d_in[0];
    const float* hE     = (const float*)d_in[1];
    const float* hEV    = (const float*)d_in[2];
    const float* maskV  = (const float*)d_in[3];
    const float* maskA  = (const float*)d_in[4];
    const float* naWQ   = (const float*)d_in[5];
    const float* naWK   = (const float*)d_in[6];
    const float* naWV   = (const float*)d_in[7];
    const float* naWO   = (const float*)d_in[8];
    const float* eaWK   = (const float*)d_in[9];
    const float* eaWV   = (const float*)d_in[10];
    const float* eaWO   = (const float*)d_in[11];
    const float* d1Win  = (const float*)d_in[12];
    const float* d1bin  = (const float*)d_in[13];
    const float* d1Wout = (const float*)d_in[14];
    const float* d1bout = (const float*)d_in[15];
    const float* d2Win  = (const float*)d_in[16];
    const float* d2bin  = (const float*)d_in[17];
    const float* d2Wout = (const float*)d_in[18];
    const float* d2bout = (const float*)d_in[19];
    const float* opW1   = (const float*)d_in[20];
    const float* opb1   = (const float*)d_in[21];
    const float* opW2   = (const float*)d_in[22];
    const float* opb2   = (const float*)d_in[23];
    const float* opg    = (const float*)d_in[24];
    const float* opbeta = (const float*)d_in[25];
    const float* n1g    = (const float*)d_in[26];
    const float* n1b    = (const float*)d_in[27];
    const float* n3g    = (const float*)d_in[28];
    const float* n3b    = (const float*)d_in[29];
    const float* n4g    = (const float*)d_in[30];
    const float* n4b    = (const float*)d_in[31];
    const int*   Eidx   = (const int*)d_in[32];

    float* outV = (float*)d_out;
    float* outE = outV + (size_t)Bb * Nn * Hh;
    u16* xop = (u16*)d_ws;                       // [B*N*H] bf16  (2 MB)
    u16* wb  = (u16*)d_ws + (size_t)Bb * Nn * Hh; // bf16 weights (512 KB)

    dim3 blk(256);
    k_prep<<<dim3(WB_TOTAL / 256), blk, 0, stream>>>(naWK, naWV, eaWK, eaWV, eaWO,
                                                     d2Win, d2Wout, opW2, wb);
    dim3 grid(Bb * Nn);
    k_node_attn<<<grid, blk, 0, stream>>>(hV, hEV, maskA, naWQ, wb, naWO,
                                          n1g, n1b, outV);
    k_node_ffn<<<grid, blk, 0, stream>>>(outV, maskV, d1Win, d1bin, d1Wout,
                                         d1bout, n1g, n1b);
    k_xop<<<grid, blk, 0, stream>>>(outV, opW1, opb1, opg, opbeta, xop);
    k_outer<<<grid, blk, 0, stream>>>(xop, hE, Eidx, wb, opb2, outE);
    k_edge_attn<<<grid, blk, 0, stream>>>(maskA, wb, n3g, n3b, outE);
    k_edge_ffn<<<grid, blk, 0, stream>>>(wb, d2bin, d2bout, n4g, n4b, outE);
}

// Round 3
// 1066.991 us; speedup vs baseline: 5.4316x; 1.2907x over previous
//
#include <hip/hip_runtime.h>
#include <math.h>

#define Bb 4
#define Nn 2048
#define Kk 32
#define Hh 128
#define NIi 256
#define NH_ 4
#define Dd 32
#define DFFh 512

#define NEGF -3.402823466e38f

typedef unsigned short u16;
typedef __attribute__((ext_vector_type(8))) short bf16x8;
typedef __attribute__((ext_vector_type(4))) short s16x4;
typedef __attribute__((ext_vector_type(4))) float f32x4;

// bf16 weight buffer offsets (elements); base = d_ws + 2MB
#define OFF_NAWKT   0        // [128][256]
#define OFF_NAWVT   32768    // [128][256]
#define OFF_EAWKT   65536    // [128][128]
#define OFF_EAWVT   81920
#define OFF_EAWOT   98304
#define OFF_D2WINT  114688   // [512][128]
#define OFF_D2WOUTT 180224   // [128][512]
#define OFF_OPW2T   245760   // [128][128]
#define OFF_D1WINT  262144   // [512][128]
#define OFF_D1WOUTT 327680   // [128][512]
#define OFF_OPW1T   393216   // [128][128]
#define WB_TOTAL    409600

// Fast exact-gelu: A&S 7.1.26 erf (|eps|<=1.5e-7), branchless.
__device__ __forceinline__ float gelu_f(float x) {
    float z = x * 0.7071067811865476f;
    float a = fabsf(z);
    float d = fmaf(0.3275911f, a, 1.0f);
    float t = __fdividef(1.0f, d);
    float p = fmaf(fmaf(fmaf(fmaf(1.061405429f, t, -1.453152027f), t,
                             1.421413741f), t, -0.284496736f), t, 0.254829592f);
    float e = __expf(-a * a);
    float erfa = fmaf(-p * t, e, 1.0f);
    float er = copysignf(erfa, z);
    return 0.5f * x * (1.0f + er);
}

__device__ __forceinline__ u16 f2bf(float f) {
    union { float f; unsigned int u; } v; v.f = f;
    unsigned int r = v.u + 0x7FFFu + ((v.u >> 16) & 1u);   // RNE
    return (u16)(r >> 16);
}

__device__ __forceinline__ float bf2f(u16 u) {
    union { unsigned int u; float f; } v; v.u = ((unsigned int)u) << 16;
    return v.f;
}

__device__ __forceinline__ s16x4 packbf4(f32x4 v) {
    s16x4 r;
    r.x = (short)f2bf(v.x); r.y = (short)f2bf(v.y);
    r.z = (short)f2bf(v.z); r.w = (short)f2bf(v.w);
    return r;
}

__device__ __forceinline__ float blocksum(float v, float* red) {
    int t = threadIdx.x;
    #pragma unroll
    for (int m = 32; m; m >>= 1) v += __shfl_xor(v, m, 64);
    __syncthreads();
    if ((t & 63) == 0) red[t >> 6] = v;
    __syncthreads();
    return red[0] + red[1] + red[2] + red[3];
}

// ---------------- K0: convert + transpose weights to bf16 in ws ---------------
__global__ __launch_bounds__(256) void k_prep(
    const float* __restrict__ naWK, const float* __restrict__ naWV,
    const float* __restrict__ eaWK, const float* __restrict__ eaWV,
    const float* __restrict__ eaWO, const float* __restrict__ d2Win,
    const float* __restrict__ d2Wout, const float* __restrict__ opW2,
    const float* __restrict__ d1Win, const float* __restrict__ d1Wout,
    const float* __restrict__ opW1, u16* __restrict__ wb)
{
    int i = blockIdx.x * 256 + threadIdx.x;
    const float* src; int R, C, off;
    if (i < 32768)       { src = naWK;   R = 256; C = 128; off = OFF_NAWKT; }
    else if (i < 65536)  { src = naWV;   R = 256; C = 128; off = OFF_NAWVT; }
    else if (i < 81920)  { src = eaWK;   R = 128; C = 128; off = OFF_EAWKT; }
    else if (i < 98304)  { src = eaWV;   R = 128; C = 128; off = OFF_EAWVT; }
    else if (i < 114688) { src = eaWO;   R = 128; C = 128; off = OFF_EAWOT; }
    else if (i < 180224) { src = d2Win;  R = 128; C = 512; off = OFF_D2WINT; }
    else if (i < 245760) { src = d2Wout; R = 512; C = 128; off = OFF_D2WOUTT; }
    else if (i < 262144) { src = opW2;   R = 128; C = 128; off = OFF_OPW2T; }
    else if (i < 327680) { src = d1Win;  R = 128; C = 512; off = OFF_D1WINT; }
    else if (i < 393216) { src = d1Wout; R = 512; C = 128; off = OFF_D1WOUTT; }
    else                 { src = opW1;   R = 128; C = 128; off = OFF_OPW1T; }
    int j = i - off;
    int c = j / R, r = j - c * R;       // dest W^T[C][R]
    wb[i] = f2bf(src[r * C + c]);
}

// ---------------- K1: neighbor attention + gelu + residual + LN(n1) -> hv1 ----
__global__ __launch_bounds__(256) void k_node_attn(
    const float* __restrict__ hV, const float* __restrict__ hEV,
    const float* __restrict__ maskA,
    const float* __restrict__ WQ, const u16* __restrict__ wb,
    const float* __restrict__ WO,
    const float* __restrict__ n1g, const float* __restrict__ n1b,
    float* __restrict__ hv1)
{
    __shared__ __align__(16) short EVb[32 * 264];
    __shared__ __align__(16) float Kt[32][129];
    __shared__ __align__(16) float Vt[32][129];
    __shared__ float Qs[128], hvr[128], att[NH_][Kk], outr[128], red[4];

    const int bn = blockIdx.x, t = threadIdx.x;
    const int w = t >> 6, l = t & 63, l15 = l & 15, lq = l >> 4;
    const float* evp = hEV + (size_t)bn * (Kk * NIi);
    for (int i4 = t * 4; i4 < Kk * NIi; i4 += 1024) {
        f32x4 v = *(const f32x4*)&evp[i4];
        *(s16x4*)&EVb[(i4 >> 8) * 264 + (i4 & 255)] = packbf4(v);
    }
    if (t < Hh) hvr[t] = hV[(size_t)bn * Hh + t];
    __syncthreads();

    // K = EV @ WK, V = EV @ WV via MFMA
    #pragma unroll
    for (int i = 0; i < 8; ++i) {
        int id = w + 4 * i;
        int mat = id >> 4, rem = id & 15;
        int m0 = (rem >> 3) << 4, n0 = (rem & 7) << 4;
        const u16* Bp = wb + (mat ? OFF_NAWVT : OFF_NAWKT);
        f32x4 acc = {0.f, 0.f, 0.f, 0.f};
        #pragma unroll
        for (int kt = 0; kt < 8; ++kt) {
            bf16x8 a = *(const bf16x8*)&EVb[(m0 + l15) * 264 + kt * 32 + lq * 8];
            bf16x8 b = *(const bf16x8*)(Bp + (size_t)(n0 + l15) * 256 + kt * 32 + lq * 8);
            acc = __builtin_amdgcn_mfma_f32_16x16x32_bf16(a, b, acc, 0, 0, 0);
        }
        int col = n0 + l15;
        float* dst = mat ? &Vt[0][0] : &Kt[0][0];
        #pragma unroll
        for (int r = 0; r < 4; ++r)
            dst[(m0 + lq * 4 + r) * 129 + col] = acc[r];
    }
    if (t < Hh) {
        float a = 0.f;
        for (int i = 0; i < Hh; ++i) a += hvr[i] * WQ[i * Hh + t];
        Qs[t] = a;
    }
    __syncthreads();

    if (t < NH_ * Kk) {
        int nh = t >> 5, k = t & 31;
        float a = 0.f;
        #pragma unroll
        for (int d = 0; d < Dd; ++d) a += Qs[nh * Dd + d] * Kt[k][nh * Dd + d];
        att[nh][k] = a * 0.17677669529663687f;
    }
    __syncthreads();
    // wave-parallel masked softmax (32-lane groups per head)
    if (t < 128) {
        int nh = t >> 5, k = t & 31;
        float mk = maskA[(size_t)bn * Kk + k];
        float lg = (mk > 0.f) ? att[nh][k] : NEGF;
        float mx = lg;
        #pragma unroll
        for (int s = 16; s; s >>= 1) mx = fmaxf(mx, __shfl_xor(mx, s, 32));
        float e = __expf(lg - mx);
        float sum = e;
        #pragma unroll
        for (int s = 16; s; s >>= 1) sum += __shfl_xor(sum, s, 32);
        att[nh][k] = mk * e / sum;
    }
    __syncthreads();
    if (t < Hh) {
        int nh = t >> 5, d = t & 31;
        float a = 0.f;
        #pragma unroll
        for (int k = 0; k < Kk; ++k) a += att[nh][k] * Vt[k][nh * Dd + d];
        outr[t] = a;
    }
    __syncthreads();
    float x = 0.f;
    if (t < Hh) {
        float a = 0.f;
        for (int h = 0; h < Hh; ++h) a += outr[h] * WO[h * Hh + t];
        x = hvr[t] + gelu_f(a);
    }
    float mu = blocksum((t < Hh) ? x : 0.f, red) * (1.f / Hh);
    float dx = (t < Hh) ? (x - mu) : 0.f;
    float var = blocksum(dx * dx, red) * (1.f / Hh);
    if (t < Hh)
        hv1[(size_t)bn * Hh + t] = n1g[t] * dx / sqrtf(var + 1e-5f) + n1b[t];
}

// ---------------- K2: batched node FFN (M=32 tokens), MFMA, in-place on hv ----
__global__ __launch_bounds__(256, 3) void k_node_ffn(
    float* __restrict__ hv, const float* __restrict__ maskV,
    const u16* __restrict__ wb, const float* __restrict__ bin,
    const float* __restrict__ bout,
    const float* __restrict__ n1g, const float* __restrict__ n1b)
{
    __shared__ __align__(16) float Xf[32][132];
    __shared__ __align__(16) short A1[32 * 136];
    __shared__ __align__(16) short Hd[32 * 264];
    __shared__ float mu_[32], isd_[32];
    const int bn = blockIdx.x, t = threadIdx.x;
    const int w = t >> 6, l = t & 63, l15 = l & 15, lq = l >> 4;
    float* ep = hv + (size_t)bn * 4096;
    for (int i4 = t * 4; i4 < 4096; i4 += 1024) {
        f32x4 v = *(const f32x4*)&ep[i4];
        int r = i4 >> 7, c = i4 & 127;
        *(f32x4*)&Xf[r][c] = v;
        *(s16x4*)&A1[r * 136 + c] = packbf4(v);
    }
    __syncthreads();

    bf16x8 aA[2][4];
    #pragma unroll
    for (int m = 0; m < 2; ++m)
        #pragma unroll
        for (int kt = 0; kt < 4; ++kt)
            aA[m][kt] = *(const bf16x8*)&A1[(m * 16 + l15) * 136 + kt * 32 + lq * 8];

    const int col0 = w * 16 + l15, col1 = (w + 4) * 16 + l15;
    f32x4 acc2[2][2];
    #pragma unroll
    for (int i = 0; i < 2; ++i)
        #pragma unroll
        for (int m = 0; m < 2; ++m) acc2[i][m] = (f32x4){0.f, 0.f, 0.f, 0.f};

    for (int ch = 0; ch < 2; ++ch) {
        // stage 1: hidden cols [ch*256, ch*256+256)
        #pragma unroll
        for (int nt = 0; nt < 4; ++nt) {
            int lc0 = (w * 4 + nt) * 16;
            int g = ch * 256 + lc0 + l15;
            bf16x8 bB[4];
            #pragma unroll
            for (int kt = 0; kt < 4; ++kt)
                bB[kt] = *(const bf16x8*)(wb + OFF_D1WINT + (size_t)g * 128 + kt * 32 + lq * 8);
            float bi = bin[g];
            #pragma unroll
            for (int m = 0; m < 2; ++m) {
                f32x4 acc = {0.f, 0.f, 0.f, 0.f};
                #pragma unroll
                for (int kt = 0; kt < 4; ++kt)
                    acc = __builtin_amdgcn_mfma_f32_16x16x32_bf16(aA[m][kt], bB[kt], acc, 0, 0, 0);
                #pragma unroll
                for (int r = 0; r < 4; ++r)
                    Hd[(m * 16 + lq * 4 + r) * 264 + lc0 + l15] = (short)f2bf(gelu_f(acc[r] + bi));
            }
        }
        __syncthreads();
        // stage 2 partial over this chunk's k
        #pragma unroll
        for (int kt = 0; kt < 8; ++kt) {
            bf16x8 a0 = *(const bf16x8*)&Hd[l15 * 264 + kt * 32 + lq * 8];
            bf16x8 a1 = *(const bf16x8*)&Hd[(16 + l15) * 264 + kt * 32 + lq * 8];
            bf16x8 b0 = *(const bf16x8*)(wb + OFF_D1WOUTT + (size_t)col0 * 512 + ch * 256 + kt * 32 + lq * 8);
            bf16x8 b1 = *(const bf16x8*)(wb + OFF_D1WOUTT + (size_t)col1 * 512 + ch * 256 + kt * 32 + lq * 8);
            acc2[0][0] = __builtin_amdgcn_mfma_f32_16x16x32_bf16(a0, b0, acc2[0][0], 0, 0, 0);
            acc2[0][1] = __builtin_amdgcn_mfma_f32_16x16x32_bf16(a1, b0, acc2[0][1], 0, 0, 0);
            acc2[1][0] = __builtin_amdgcn_mfma_f32_16x16x32_bf16(a0, b1, acc2[1][0], 0, 0, 0);
            acc2[1][1] = __builtin_amdgcn_mfma_f32_16x16x32_bf16(a1, b1, acc2[1][1], 0, 0, 0);
        }
        __syncthreads();
    }
    #pragma unroll
    for (int ni = 0; ni < 2; ++ni) {
        int col = ni ? col1 : col0;
        float bo = bout[col];
        #pragma unroll
        for (int m = 0; m < 2; ++m)
            #pragma unroll
            for (int r = 0; r < 4; ++r) {
                int row = m * 16 + lq * 4 + r;
                Xf[row][col] += gelu_f(acc2[ni][m][r] + bo);
            }
    }
    __syncthreads();
    {
        int r = t >> 3, sub = t & 7;
        float s = 0.f, ss = 0.f;
        #pragma unroll
        for (int j = 0; j < 16; ++j) {
            float v = Xf[r][sub * 16 + j]; s += v; ss += v * v;
        }
        #pragma unroll
        for (int m = 1; m < 8; m <<= 1) { s += __shfl_xor(s, m, 8); ss += __shfl_xor(ss, m, 8); }
        if (sub == 0) {
            float mu = s * (1.f / 128.f);
            mu_[r] = mu;
            isd_[r] = 1.f / sqrtf(ss * (1.f / 128.f) - mu * mu + 1e-5f);
        }
    }
    __syncthreads();
    for (int i4 = t * 4; i4 < 4096; i4 += 1024) {
        int r = i4 >> 7, c = i4 & 127;
        float mv = maskV[bn * 32 + r];
        f32x4 xv = *(const f32x4*)&Xf[r][c];
        f32x4 o;
        #pragma unroll
        for (int j = 0; j < 4; ++j)
            o[j] = mv * (n1g[c + j] * (xv[j] - mu_[r]) * isd_[r] + n1b[c + j]);
        *(f32x4*)&ep[i4] = o;
    }
}

// ---------------- K3: batched xop = LN(hv2, op_g, op_beta) @ W1 + b1 (bf16) ---
__global__ __launch_bounds__(256) void k_xop(
    const float* __restrict__ hv2, const u16* __restrict__ wb,
    const float* __restrict__ b1, const float* __restrict__ opg,
    const float* __restrict__ opb, u16* __restrict__ xop)
{
    __shared__ __align__(16) float Xf[32][132];
    __shared__ __align__(16) short A1[32 * 136];
    __shared__ float mu_[32], isd_[32];
    const int bn = blockIdx.x, t = threadIdx.x;
    const int w = t >> 6, l = t & 63, l15 = l & 15, lq = l >> 4;
    const float* ep = hv2 + (size_t)bn * 4096;
    for (int i4 = t * 4; i4 < 4096; i4 += 1024) {
        f32x4 v = *(const f32x4*)&ep[i4];
        *(f32x4*)&Xf[i4 >> 7][i4 & 127] = v;
    }
    __syncthreads();
    {
        int r = t >> 3, sub = t & 7;
        float s = 0.f, ss = 0.f;
        #pragma unroll
        for (int j = 0; j < 16; ++j) {
            float v = Xf[r][sub * 16 + j]; s += v; ss += v * v;
        }
        #pragma unroll
        for (int m = 1; m < 8; m <<= 1) { s += __shfl_xor(s, m, 8); ss += __shfl_xor(ss, m, 8); }
        if (sub == 0) {
            float mu = s * (1.f / 128.f);
            mu_[r] = mu;
            isd_[r] = 1.f / sqrtf(ss * (1.f / 128.f) - mu * mu + 1e-5f);
        }
    }
    __syncthreads();
    for (int i4 = t * 4; i4 < 4096; i4 += 1024) {
        int r = i4 >> 7, c = i4 & 127;
        f32x4 xv = *(const f32x4*)&Xf[r][c];
        f32x4 y;
        #pragma unroll
        for (int j = 0; j < 4; ++j)
            y[j] = opg[c + j] * (xv[j] - mu_[r]) * isd_[r] + opb[c + j];
        *(s16x4*)&A1[r * 136 + c] = packbf4(y);
    }
    __syncthreads();
    #pragma unroll
    for (int i = 0; i < 4; ++i) {
        int id = w + 4 * i;
        int m0 = (id >> 3) << 4, n0 = (id & 7) << 4;
        f32x4 acc = {0.f, 0.f, 0.f, 0.f};
        #pragma unroll
        for (int kt = 0; kt < 4; ++kt) {
            bf16x8 a = *(const bf16x8*)&A1[(m0 + l15) * 136 + kt * 32 + lq * 8];
            bf16x8 bv = *(const bf16x8*)(wb + OFF_OPW1T + (size_t)(n0 + l15) * 128 + kt * 32 + lq * 8);
            acc = __builtin_amdgcn_mfma_f32_16x16x32_bf16(a, bv, acc, 0, 0, 0);
        }
        int col = n0 + l15;
        float bb = b1[col];
        #pragma unroll
        for (int r = 0; r < 4; ++r)
            xop[(size_t)(bn * 32 + m0 + lq * 4 + r) * 128 + col] = f2bf(acc[r] + bb);
    }
}

// ---------------- K4: h_E1 = h_E + (x ⊙ x[nbr]) @ W2 + b2 -> outE (MFMA) ------
__global__ __launch_bounds__(256) void k_outer(
    const u16* __restrict__ xop, const float* __restrict__ hE,
    const int* __restrict__ Eidx, const u16* __restrict__ wb,
    const float* __restrict__ b2, float* __restrict__ outE)
{
    __shared__ __align__(16) short A1[32 * 136];
    __shared__ float xcf[128];
    __shared__ int idxs[32];
    const int bn = blockIdx.x, t = threadIdx.x;
    const int b = bn >> 11;
    const int w = t >> 6, l = t & 63, l15 = l & 15, lq = l >> 4;
    if (t < 128) xcf[t] = bf2f(xop[(size_t)bn * 128 + t]);
    if (t < 32) idxs[t] = Eidx[(size_t)bn * 32 + t];
    __syncthreads();
    for (int i4 = t * 4; i4 < 4096; i4 += 1024) {
        int k = i4 >> 7, h = i4 & 127;
        s16x4 nb = *(const s16x4*)&xop[((size_t)b * Nn + idxs[k]) * 128 + h];
        f32x4 prod;
        prod.x = xcf[h] * bf2f(nb.x);
        prod.y = xcf[h + 1] * bf2f(nb.y);
        prod.z = xcf[h + 2] * bf2f(nb.z);
        prod.w = xcf[h + 3] * bf2f(nb.w);
        *(s16x4*)&A1[k * 136 + h] = packbf4(prod);
    }
    __syncthreads();
    const u16* Bp = wb + OFF_OPW2T;
    #pragma unroll
    for (int i = 0; i < 4; ++i) {
        int id = w + 4 * i, m0 = (id >> 3) << 4, n0 = (id & 7) << 4;
        f32x4 acc = {0.f, 0.f, 0.f, 0.f};
        #pragma unroll
        for (int kt = 0; kt < 4; ++kt) {
            bf16x8 a = *(const bf16x8*)&A1[(m0 + l15) * 136 + kt * 32 + lq * 8];
            bf16x8 bv = *(const bf16x8*)(Bp + (size_t)(n0 + l15) * 128 + kt * 32 + lq * 8);
            acc = __builtin_amdgcn_mfma_f32_16x16x32_bf16(a, bv, acc, 0, 0, 0);
        }
        int col = n0 + l15;
        float bb = b2[col];
        #pragma unroll
        for (int r = 0; r < 4; ++r) {
            int row = m0 + lq * 4 + r;
            size_t o = (size_t)bn * 4096 + row * 128 + col;
            outE[o] = hE[o] + acc[r] + bb;
        }
    }
}

// ---------------- K5: edge self-attention + gelu + residual + LN(n3), in place
__global__ __launch_bounds__(256) void k_edge_attn(
    const float* __restrict__ maskA, const u16* __restrict__ wb,
    const float* __restrict__ n3g, const float* __restrict__ n3b,
    float* __restrict__ outE)
{
    __shared__ __align__(16) float Xf[32][132];
    __shared__ __align__(16) short A1[32 * 136];     // X bf16; later O2
    __shared__ __align__(16) short QeP[5120];        // Qe [32][136-ish]; later Pe [4][32][40]
    __shared__ __align__(16) short Ke[32 * 136];
    __shared__ __align__(16) short Vp[4 * 32 * 40];  // V''[a][dd][c]
    __shared__ __align__(16) float Le[NH_][Kk][Kk + 1];
    __shared__ float ms[32];
    __shared__ float mu_[32], isd_[32];

    const int bn = blockIdx.x, t = threadIdx.x;
    const int w = t >> 6, l = t & 63, l15 = l & 15, lq = l >> 4;
    float* ep = outE + (size_t)bn * 4096;

    for (int i4 = t * 4; i4 < 4096; i4 += 1024) {
        f32x4 v = *(const f32x4*)&ep[i4];
        int r = i4 >> 7, c = i4 & 127;
        *(f32x4*)&Xf[r][c] = v;
        *(s16x4*)&A1[r * 136 + c] = packbf4(v);
    }
    if (t < 32) ms[t] = maskA[(size_t)bn * 32 + t];
    __syncthreads();

    // Projections: Q = X@WO (faithful), K = X@WK, V = X@WV
    #pragma unroll
    for (int i = 0; i < 12; ++i) {
        int id = w + 4 * i;
        int mat = id >> 4, rem = id & 15;
        int m0 = (rem >> 3) << 4, n0 = (rem & 7) << 4;
        const u16* Bp = wb + ((mat == 0) ? OFF_EAWOT : (mat == 1) ? OFF_EAWKT : OFF_EAWVT);
        f32x4 acc = {0.f, 0.f, 0.f, 0.f};
        #pragma unroll
        for (int kt = 0; kt < 4; ++kt) {
            bf16x8 a = *(const bf16x8*)&A1[(m0 + l15) * 136 + kt * 32 + lq * 8];
            bf16x8 bv = *(const bf16x8*)(Bp + (size_t)(n0 + l15) * 128 + kt * 32 + lq * 8);
            acc = __builtin_amdgcn_mfma_f32_16x16x32_bf16(a, bv, acc, 0, 0, 0);
        }
        int col = n0 + l15;
        #pragma unroll
        for (int r = 0; r < 4; ++r) {
            int row = m0 + lq * 4 + r;
            u16 hv = f2bf(acc[r]);
            if (mat == 0) QeP[row * 136 + col] = (short)hv;
            else if (mat == 1) Ke[row * 136 + col] = (short)hv;
            else Vp[((row >> 3) * 32 + (col & 31)) * 40 + (((row & 7) << 2) | (col >> 5))] = (short)hv;
        }
    }
    __syncthreads();

    // logits via MFMA over d=32: Le[h][q][k]
    #pragma unroll
    for (int i = 0; i < 4; ++i) {
        int id = w + 4 * i;
        int h = id >> 2, rem = id & 3;
        int q0 = (rem >> 1) << 4, k0 = (rem & 1) << 4;
        int q = q0 + l15, k = k0 + l15;
        bf16x8 a = *(const bf16x8*)&QeP[(((h << 3) | (q >> 2)) * 136) + (((q & 3) << 5) + lq * 8)];
        bf16x8 bv = *(const bf16x8*)&Ke[(((h << 3) | (k >> 2)) * 136) + (((k & 3) << 5) + lq * 8)];
        f32x4 acc = {0.f, 0.f, 0.f, 0.f};
        acc = __builtin_amdgcn_mfma_f32_16x16x32_bf16(a, bv, acc, 0, 0, 0);
        #pragma unroll
        for (int r = 0; r < 4; ++r)
            Le[h][q0 + lq * 4 + r][k0 + l15] = acc[r];
    }
    __syncthreads();

    // masked softmax (reshape+swap semantics), write Pe bf16 into QeP region
    if (t < 128) {
        int a = t >> 5, q2 = t & 31;
        float mq = ms[q2];
        float lv[Kk];
        float mx = NEGF;
        #pragma unroll
        for (int c = 0; c < Kk; ++c) {
            float lg = Le[c >> 3][((c & 7) << 2) | (q2 >> 3)][((q2 & 7) << 2) | a]
                       * 0.17677669529663687f;
            lv[c] = (mq * ms[c] > 0.f) ? lg : NEGF;
            mx = fmaxf(mx, lv[c]);
        }
        float s = 0.f;
        #pragma unroll
        for (int c = 0; c < Kk; ++c) { lv[c] = __expf(lv[c] - mx); s += lv[c]; }
        float inv = 1.f / s;
        #pragma unroll
        for (int c = 0; c < Kk; ++c)
            QeP[((a * 32 + q2) * 40) + c] = (short)f2bf(lv[c] * inv);
    }
    __syncthreads();

    // PV via MFMA over c=32: O2[q2][(a<<5)+dd] into A1 region
    #pragma unroll
    for (int i = 0; i < 4; ++i) {
        int id = w + 4 * i;
        int a = id >> 2, rem = id & 3;
        int q0 = (rem >> 1) << 4, d0 = (rem & 1) << 4;
        bf16x8 pa = *(const bf16x8*)&QeP[((a * 32 + q0 + l15) * 40) + lq * 8];
        bf16x8 vb = *(const bf16x8*)&Vp[((a * 32 + d0 + l15) * 40) + lq * 8];
        f32x4 acc = {0.f, 0.f, 0.f, 0.f};
        acc = __builtin_amdgcn_mfma_f32_16x16x32_bf16(pa, vb, acc, 0, 0, 0);
        #pragma unroll
        for (int r = 0; r < 4; ++r)
            A1[(q0 + lq * 4 + r) * 136 + (a << 5) + d0 + l15] = (short)f2bf(acc[r]);
    }
    __syncthreads();

    // final: dh = gelu(O2 @ WO); Xf += dh
    const u16* Bo = wb + OFF_EAWOT;
    #pragma unroll
    for (int i = 0; i < 4; ++i) {
        int id = w + 4 * i;
        int m0 = (id >> 3) << 4, n0 = (id & 7) << 4;
        f32x4 acc = {0.f, 0.f, 0.f, 0.f};
        #pragma unroll
        for (int kt = 0; kt < 4; ++kt) {
            bf16x8 a = *(const bf16x8*)&A1[(m0 + l15) * 136 + kt * 32 + lq * 8];
            bf16x8 bv = *(const bf16x8*)(Bo + (size_t)(n0 + l15) * 128 + kt * 32 + lq * 8);
            acc = __builtin_amdgcn_mfma_f32_16x16x32_bf16(a, bv, acc, 0, 0, 0);
        }
        int col = n0 + l15;
        #pragma unroll
        for (int r = 0; r < 4; ++r) {
            int row = m0 + lq * 4 + r;
            Xf[row][col] += gelu_f(acc[r]);
        }
    }
    __syncthreads();
    {
        int r = t >> 3, sub = t & 7;
        float s = 0.f, ss = 0.f;
        #pragma unroll
        for (int j = 0; j < 16; ++j) {
            float v = Xf[r][sub * 16 + j]; s += v; ss += v * v;
        }
        #pragma unroll
        for (int m = 1; m < 8; m <<= 1) { s += __shfl_xor(s, m, 8); ss += __shfl_xor(ss, m, 8); }
        if (sub == 0) {
            float mu = s * (1.f / 128.f);
            mu_[r] = mu;
            isd_[r] = 1.f / sqrtf(ss * (1.f / 128.f) - mu * mu + 1e-5f);
        }
    }
    __syncthreads();
    for (int i4 = t * 4; i4 < 4096; i4 += 1024) {
        int r = i4 >> 7, c = i4 & 127;
        f32x4 xv = *(const f32x4*)&Xf[r][c];
        f32x4 o;
        #pragma unroll
        for (int j = 0; j < 4; ++j)
            o[j] = n3g[c + j] * (xv[j] - mu_[r]) * isd_[r] + n3b[c + j];
        *(f32x4*)&ep[i4] = o;
    }
}

// ---------------- K6: edge FFN + gelu + residual + LN(n4), in place (MFMA) ----
__global__ __launch_bounds__(256, 3) void k_edge_ffn(
    const u16* __restrict__ wb, const float* __restrict__ bin,
    const float* __restrict__ bout,
    const float* __restrict__ n4g, const float* __restrict__ n4b,
    float* __restrict__ outE)
{
    __shared__ __align__(16) float Xf[32][132];
    __shared__ __align__(16) short A1[32 * 136];
    __shared__ __align__(16) short Hd[32 * 264];
    __shared__ float mu_[32], isd_[32];
    const int bn = blockIdx.x, t = threadIdx.x;
    const int w = t >> 6, l = t & 63, l15 = l & 15, lq = l >> 4;
    float* ep = outE + (size_t)bn * 4096;
    for (int i4 = t * 4; i4 < 4096; i4 += 1024) {
        f32x4 v = *(const f32x4*)&ep[i4];
        int r = i4 >> 7, c = i4 & 127;
        *(f32x4*)&Xf[r][c] = v;
        *(s16x4*)&A1[r * 136 + c] = packbf4(v);
    }
    __syncthreads();

    bf16x8 aA[2][4];
    #pragma unroll
    for (int m = 0; m < 2; ++m)
        #pragma unroll
        for (int kt = 0; kt < 4; ++kt)
            aA[m][kt] = *(const bf16x8*)&A1[(m * 16 + l15) * 136 + kt * 32 + lq * 8];

    const int col0 = w * 16 + l15, col1 = (w + 4) * 16 + l15;
    f32x4 acc2[2][2];
    #pragma unroll
    for (int i = 0; i < 2; ++i)
        #pragma unroll
        for (int m = 0; m < 2; ++m) acc2[i][m] = (f32x4){0.f, 0.f, 0.f, 0.f};

    for (int ch = 0; ch < 2; ++ch) {
        #pragma unroll
        for (int nt = 0; nt < 4; ++nt) {
            int lc0 = (w * 4 + nt) * 16;
            int g = ch * 256 + lc0 + l15;
            bf16x8 bB[4];
            #pragma unroll
            for (int kt = 0; kt < 4; ++kt)
                bB[kt] = *(const bf16x8*)(wb + OFF_D2WINT + (size_t)g * 128 + kt * 32 + lq * 8);
            float bi = bin[g];
            #pragma unroll
            for (int m = 0; m < 2; ++m) {
                f32x4 acc = {0.f, 0.f, 0.f, 0.f};
                #pragma unroll
                for (int kt = 0; kt < 4; ++kt)
                    acc = __builtin_amdgcn_mfma_f32_16x16x32_bf16(aA[m][kt], bB[kt], acc, 0, 0, 0);
                #pragma unroll
                for (int r = 0; r < 4; ++r)
                    Hd[(m * 16 + lq * 4 + r) * 264 + lc0 + l15] = (short)f2bf(gelu_f(acc[r] + bi));
            }
        }
        __syncthreads();
        #pragma unroll
        for (int kt = 0; kt < 8; ++kt) {
            bf16x8 a0 = *(const bf16x8*)&Hd[l15 * 264 + kt * 32 + lq * 8];
            bf16x8 a1 = *(const bf16x8*)&Hd[(16 + l15) * 264 + kt * 32 + lq * 8];
            bf16x8 b0 = *(const bf16x8*)(wb + OFF_D2WOUTT + (size_t)col0 * 512 + ch * 256 + kt * 32 + lq * 8);
            bf16x8 b1 = *(const bf16x8*)(wb + OFF_D2WOUTT + (size_t)col1 * 512 + ch * 256 + kt * 32 + lq * 8);
            acc2[0][0] = __builtin_amdgcn_mfma_f32_16x16x32_bf16(a0, b0, acc2[0][0], 0, 0, 0);
            acc2[0][1] = __builtin_amdgcn_mfma_f32_16x16x32_bf16(a1, b0, acc2[0][1], 0, 0, 0);
            acc2[1][0] = __builtin_amdgcn_mfma_f32_16x16x32_bf16(a0, b1, acc2[1][0], 0, 0, 0);
            acc2[1][1] = __builtin_amdgcn_mfma_f32_16x16x32_bf16(a1, b1, acc2[1][1], 0, 0, 0);
        }
        __syncthreads();
    }
    #pragma unroll
    for (int ni = 0; ni < 2; ++ni) {
        int col = ni ? col1 : col0;
        float bo = bout[col];
        #pragma unroll
        for (int m = 0; m < 2; ++m)
            #pragma unroll
            for (int r = 0; r < 4; ++r) {
                int row = m * 16 + lq * 4 + r;
                Xf[row][col] += gelu_f(acc2[ni][m][r] + bo);
            }
    }
    __syncthreads();
    {
        int r = t >> 3, sub = t & 7;
        float s = 0.f, ss = 0.f;
        #pragma unroll
        for (int j = 0; j < 16; ++j) {
            float v = Xf[r][sub * 16 + j]; s += v; ss += v * v;
        }
        #pragma unroll
        for (int m = 1; m < 8; m <<= 1) { s += __shfl_xor(s, m, 8); ss += __shfl_xor(ss, m, 8); }
        if (sub == 0) {
            float mu = s * (1.f / 128.f);
            mu_[r] = mu;
            isd_[r] = 1.f / sqrtf(ss * (1.f / 128.f) - mu * mu + 1e-5f);
        }
    }
    __syncthreads();
    for (int i4 = t * 4; i4 < 4096; i4 += 1024) {
        int r = i4 >> 7, c = i4 & 127;
        f32x4 xv = *(const f32x4*)&Xf[r][c];
        f32x4 o;
        #pragma unroll
        for (int j = 0; j < 4; ++j)
            o[j] = n4g[c + j] * (xv[j] - mu_[r]) * isd_[r] + n4b[c + j];
        *(f32x4*)&ep[i4] = o;
    }
}

extern "C" void kernel_launch(void* const* d_in, const int* in_sizes, int n_in,
                              void* d_out, int out_size, void* d_ws, size_t ws_size,
                              hipStream_t stream) {
    const float* hV     = (const float*)d_in[0];
    const float* hE     = (const float*)d_in[1];
    const float* hEV    = (const float*)d_in[2];
    const float* maskV  = (const float*)d_in[3];
    const float* maskA  = (const float*)d_in[4];
    const float* naWQ   = (const float*)d_in[5];
    const float* naWK   = (const float*)d_in[6];
    const float* naWV   = (const float*)d_in[7];
    const float* naWO   = (const float*)d_in[8];
    const float* eaWK   = (const float*)d_in[9];
    const float* eaWV   = (const float*)d_in[10];
    const float* eaWO   = (const float*)d_in[11];
    const float* d1Win  = (const float*)d_in[12];
    const float* d1bin  = (const float*)d_in[13];
    const float* d1Wout = (const float*)d_in[14];
    const float* d1bout = (const float*)d_in[15];
    const float* d2Win  = (const float*)d_in[16];
    const float* d2bin  = (const float*)d_in[17];
    const float* d2Wout = (const float*)d_in[18];
    const float* d2bout = (const float*)d_in[19];
    const float* opW1   = (const float*)d_in[20];
    const float* opb1   = (const float*)d_in[21];
    const float* opW2   = (const float*)d_in[22];
    const float* opb2   = (const float*)d_in[23];
    const float* opg    = (const float*)d_in[24];
    const float* opbeta = (const float*)d_in[25];
    const float* n1g    = (const float*)d_in[26];
    const float* n1b    = (const float*)d_in[27];
    const float* n3g    = (const float*)d_in[28];
    const float* n3b    = (const float*)d_in[29];
    const float* n4g    = (const float*)d_in[30];
    const float* n4b    = (const float*)d_in[31];
    const int*   Eidx   = (const int*)d_in[32];

    float* outV = (float*)d_out;
    float* outE = outV + (size_t)Bb * Nn * Hh;
    u16* xop = (u16*)d_ws;                        // [B*N*H] bf16 (2 MB)
    u16* wb  = (u16*)d_ws + (size_t)Bb * Nn * Hh; // bf16 weights (~820 KB)

    dim3 blk(256);
    k_prep<<<dim3(WB_TOTAL / 256), blk, 0, stream>>>(naWK, naWV, eaWK, eaWV, eaWO,
                                                     d2Win, d2Wout, opW2,
                                                     d1Win, d1Wout, opW1, wb);
    dim3 grid(Bb * Nn);
    k_node_attn<<<grid, blk, 0, stream>>>(hV, hEV, maskA, naWQ, wb, naWO,
                                          n1g, n1b, outV);
    k_node_ffn<<<dim3(Bb * Nn / 32), blk, 0, stream>>>(outV, maskV, wb, d1bin,
                                                       d1bout, n1g, n1b);
    k_xop<<<dim3(Bb * Nn / 32), blk, 0, stream>>>(outV, wb, opb1, opg, opbeta, xop);
    k_outer<<<grid, blk, 0, stream>>>(xop, hE, Eidx, wb, opb2, outE);
    k_edge_attn<<<grid, blk, 0, stream>>>(maskA, wb, n3g, n3b, outE);
    k_edge_ffn<<<grid, blk, 0, stream>>>(wb, d2bin, d2bout, n4g, n4b, outE);
}

// Round 4
// 991.373 us; speedup vs baseline: 5.8459x; 1.0763x over previous
//
#include <hip/hip_runtime.h>
#include <math.h>

#define Bb 4
#define Nn 2048
#define Kk 32
#define Hh 128
#define NIi 256
#define NH_ 4
#define Dd 32
#define DFFh 512

#define NEGF -3.402823466e38f

typedef unsigned short u16;
typedef __attribute__((ext_vector_type(8))) short bf16x8;
typedef __attribute__((ext_vector_type(4))) short s16x4;
typedef __attribute__((ext_vector_type(4))) float f32x4;

// bf16 weight buffer offsets (elements); base = d_ws + 2MB
#define OFF_NAWKT   0        // [128][256]
#define OFF_NAWVT   32768    // [128][256]
#define OFF_EAWKT   65536    // [128][128]
#define OFF_EAWVT   81920
#define OFF_EAWOT   98304
#define OFF_D2WINT  114688   // [512][128]
#define OFF_D2WOUTT 180224   // [128][512]
#define OFF_OPW2T   245760   // [128][128]
#define OFF_D1WINT  262144   // [512][128]
#define OFF_D1WOUTT 327680   // [128][512]
#define OFF_OPW1T   393216   // [128][128]
#define OFF_NAWQT   409600   // [128][128]
#define OFF_NAWOT   425984   // [128][128]
#define WB_TOTAL    442368

// Fast exact-gelu: A&S 7.1.26 erf (|eps|<=1.5e-7), branchless.
__device__ __forceinline__ float gelu_f(float x) {
    float z = x * 0.7071067811865476f;
    float a = fabsf(z);
    float d = fmaf(0.3275911f, a, 1.0f);
    float t = __fdividef(1.0f, d);
    float p = fmaf(fmaf(fmaf(fmaf(1.061405429f, t, -1.453152027f), t,
                             1.421413741f), t, -0.284496736f), t, 0.254829592f);
    float e = __expf(-a * a);
    float erfa = fmaf(-p * t, e, 1.0f);
    float er = copysignf(erfa, z);
    return 0.5f * x * (1.0f + er);
}

__device__ __forceinline__ u16 f2bf(float f) {
    union { float f; unsigned int u; } v; v.f = f;
    unsigned int r = v.u + 0x7FFFu + ((v.u >> 16) & 1u);   // RNE
    return (u16)(r >> 16);
}

__device__ __forceinline__ float bf2f(u16 u) {
    union { unsigned int u; float f; } v; v.u = ((unsigned int)u) << 16;
    return v.f;
}

__device__ __forceinline__ s16x4 packbf4(f32x4 v) {
    s16x4 r;
    r.x = (short)f2bf(v.x); r.y = (short)f2bf(v.y);
    r.z = (short)f2bf(v.z); r.w = (short)f2bf(v.w);
    return r;
}

// ---------------- K0: convert + transpose weights to bf16 in ws ---------------
__global__ __launch_bounds__(256) void k_prep(
    const float* __restrict__ naWK, const float* __restrict__ naWV,
    const float* __restrict__ eaWK, const float* __restrict__ eaWV,
    const float* __restrict__ eaWO, const float* __restrict__ d2Win,
    const float* __restrict__ d2Wout, const float* __restrict__ opW2,
    const float* __restrict__ d1Win, const float* __restrict__ d1Wout,
    const float* __restrict__ opW1, const float* __restrict__ naWQ,
    const float* __restrict__ naWO, u16* __restrict__ wb)
{
    int i = blockIdx.x * 256 + threadIdx.x;
    const float* src; int R, C, off;
    if (i < 32768)       { src = naWK;   R = 256; C = 128; off = OFF_NAWKT; }
    else if (i < 65536)  { src = naWV;   R = 256; C = 128; off = OFF_NAWVT; }
    else if (i < 81920)  { src = eaWK;   R = 128; C = 128; off = OFF_EAWKT; }
    else if (i < 98304)  { src = eaWV;   R = 128; C = 128; off = OFF_EAWVT; }
    else if (i < 114688) { src = eaWO;   R = 128; C = 128; off = OFF_EAWOT; }
    else if (i < 180224) { src = d2Win;  R = 128; C = 512; off = OFF_D2WINT; }
    else if (i < 245760) { src = d2Wout; R = 512; C = 128; off = OFF_D2WOUTT; }
    else if (i < 262144) { src = opW2;   R = 128; C = 128; off = OFF_OPW2T; }
    else if (i < 327680) { src = d1Win;  R = 128; C = 512; off = OFF_D1WINT; }
    else if (i < 393216) { src = d1Wout; R = 512; C = 128; off = OFF_D1WOUTT; }
    else if (i < 409600) { src = opW1;   R = 128; C = 128; off = OFF_OPW1T; }
    else if (i < 425984) { src = naWQ;   R = 128; C = 128; off = OFF_NAWQT; }
    else                 { src = naWO;   R = 128; C = 128; off = OFF_NAWOT; }
    int j = i - off;
    int c = j / R, r = j - c * R;       // dest W^T[C][R]
    wb[i] = f2bf(src[r * C + c]);
}

// ---------------- K1a: batched Qall = hV @ WQ (bf16) --------------------------
__global__ __launch_bounds__(256) void k_qproj(
    const float* __restrict__ hV, const u16* __restrict__ wb,
    u16* __restrict__ Qall)
{
    __shared__ __align__(16) short A1[32 * 136];
    const int bn = blockIdx.x, t = threadIdx.x;
    const int w = t >> 6, l = t & 63, l15 = l & 15, lq = l >> 4;
    const float* xp = hV + (size_t)bn * 4096;
    for (int i4 = t * 4; i4 < 4096; i4 += 1024)
        *(s16x4*)&A1[(i4 >> 7) * 136 + (i4 & 127)] = packbf4(*(const f32x4*)&xp[i4]);
    __syncthreads();
    #pragma unroll
    for (int i = 0; i < 4; ++i) {
        int id = w + 4 * i;
        int m0 = (id >> 3) << 4, n0 = (id & 7) << 4;
        f32x4 acc = {0.f, 0.f, 0.f, 0.f};
        #pragma unroll
        for (int kt = 0; kt < 4; ++kt) {
            bf16x8 a = *(const bf16x8*)&A1[(m0 + l15) * 136 + kt * 32 + lq * 8];
            bf16x8 bv = *(const bf16x8*)(wb + OFF_NAWQT + (size_t)(n0 + l15) * 128 + kt * 32 + lq * 8);
            acc = __builtin_amdgcn_mfma_f32_16x16x32_bf16(a, bv, acc, 0, 0, 0);
        }
        int col = n0 + l15;
        #pragma unroll
        for (int r = 0; r < 4; ++r)
            Qall[(size_t)(bn * 32 + m0 + lq * 4 + r) * 128 + col] = f2bf(acc[r]);
    }
}

// ---------------- K1b: per-token attention core -> outr (bf16) ----------------
__global__ __launch_bounds__(256, 4) void k_node_core(
    const float* __restrict__ hEV, const float* __restrict__ maskA,
    const u16* __restrict__ Qall, const u16* __restrict__ wb,
    u16* __restrict__ outr)
{
    __shared__ __align__(16) short EVb[32 * 264];   // 16.9 KB
    __shared__ __align__(16) short KtT[128 * 34];   // K^T [h][k], 8.7 KB
    __shared__ __align__(16) short VtT[128 * 34];   // V^T [h][k], 8.7 KB
    __shared__ float Qs[128];
    __shared__ float att[NH_][Kk];

    const int bn = blockIdx.x, t = threadIdx.x;
    const int w = t >> 6, l = t & 63, l15 = l & 15, lq = l >> 4;
    const float* evp = hEV + (size_t)bn * 8192;
    for (int i8 = t * 8; i8 < 8192; i8 += 2048) {
        f32x4 v0 = *(const f32x4*)&evp[i8];
        f32x4 v1 = *(const f32x4*)&evp[i8 + 4];
        int r = i8 >> 8, c = i8 & 255;
        *(s16x4*)&EVb[r * 264 + c] = packbf4(v0);
        *(s16x4*)&EVb[r * 264 + c + 4] = packbf4(v1);
    }
    if (t < 128) Qs[t] = bf2f(Qall[(size_t)bn * 128 + t]);
    __syncthreads();

    // K = EV @ WK, V = EV @ WV via MFMA; store transposed bf16
    #pragma unroll
    for (int i = 0; i < 8; ++i) {
        int id = w + 4 * i;
        int mat = id >> 4, rem = id & 15;
        int m0 = (rem >> 3) << 4, n0 = (rem & 7) << 4;
        const u16* Bp = wb + (mat ? OFF_NAWVT : OFF_NAWKT);
        f32x4 acc = {0.f, 0.f, 0.f, 0.f};
        #pragma unroll
        for (int kt = 0; kt < 8; ++kt) {
            bf16x8 a = *(const bf16x8*)&EVb[(m0 + l15) * 264 + kt * 32 + lq * 8];
            bf16x8 b = *(const bf16x8*)(Bp + (size_t)(n0 + l15) * 256 + kt * 32 + lq * 8);
            acc = __builtin_amdgcn_mfma_f32_16x16x32_bf16(a, b, acc, 0, 0, 0);
        }
        int col = n0 + l15;
        short* dst = mat ? VtT : KtT;
        #pragma unroll
        for (int r = 0; r < 4; ++r)
            dst[col * 34 + m0 + lq * 4 + r] = (short)f2bf(acc[r]);
    }
    __syncthreads();

    // logits + wave-parallel masked softmax (nh = t>>5, k = t&31)
    if (t < 128) {
        int nh = t >> 5, k = t & 31;
        float a = 0.f;
        #pragma unroll
        for (int d = 0; d < 32; ++d)
            a += Qs[nh * 32 + d] * bf2f(KtT[(nh * 32 + d) * 34 + k]);
        float mk = maskA[(size_t)bn * 32 + k];
        float lg = (mk > 0.f) ? a * 0.17677669529663687f : NEGF;
        float mx = lg;
        #pragma unroll
        for (int s = 16; s; s >>= 1) mx = fmaxf(mx, __shfl_xor(mx, s, 32));
        float e = __expf(lg - mx);
        float sum = e;
        #pragma unroll
        for (int s = 16; s; s >>= 1) sum += __shfl_xor(sum, s, 32);
        att[nh][k] = mk * e / sum;
    }
    __syncthreads();
    // PV (nh = t>>5, d = t&31)
    if (t < 128) {
        int nh = t >> 5, d = t & 31;
        float a = 0.f;
        #pragma unroll
        for (int k = 0; k < 32; ++k)
            a += att[nh][k] * bf2f(VtT[(nh * 32 + d) * 34 + k]);
        outr[(size_t)bn * 128 + t] = f2bf(a);
    }
}

// ---------------- K1c: batched LN(hV + gelu(outr @ WO)) -> outV ---------------
__global__ __launch_bounds__(256) void k_node_out(
    const u16* __restrict__ outr, const float* __restrict__ hV,
    const u16* __restrict__ wb,
    const float* __restrict__ n1g, const float* __restrict__ n1b,
    float* __restrict__ outV)
{
    __shared__ __align__(16) float Xf[32][132];
    __shared__ __align__(16) short A1[32 * 136];
    __shared__ float mu_[32], isd_[32];
    const int bn = blockIdx.x, t = threadIdx.x;
    const int w = t >> 6, l = t & 63, l15 = l & 15, lq = l >> 4;
    const float* xp = hV + (size_t)bn * 4096;
    const u16* op = outr + (size_t)bn * 4096;
    for (int i4 = t * 4; i4 < 4096; i4 += 1024) {
        int r = i4 >> 7, c = i4 & 127;
        *(f32x4*)&Xf[r][c] = *(const f32x4*)&xp[i4];
        *(s16x4*)&A1[r * 136 + c] = *(const s16x4*)&op[i4];
    }
    __syncthreads();
    #pragma unroll
    for (int i = 0; i < 4; ++i) {
        int id = w + 4 * i;
        int m0 = (id >> 3) << 4, n0 = (id & 7) << 4;
        f32x4 acc = {0.f, 0.f, 0.f, 0.f};
        #pragma unroll
        for (int kt = 0; kt < 4; ++kt) {
            bf16x8 a = *(const bf16x8*)&A1[(m0 + l15) * 136 + kt * 32 + lq * 8];
            bf16x8 bv = *(const bf16x8*)(wb + OFF_NAWOT + (size_t)(n0 + l15) * 128 + kt * 32 + lq * 8);
            acc = __builtin_amdgcn_mfma_f32_16x16x32_bf16(a, bv, acc, 0, 0, 0);
        }
        int col = n0 + l15;
        #pragma unroll
        for (int r = 0; r < 4; ++r) {
            int row = m0 + lq * 4 + r;
            Xf[row][col] += gelu_f(acc[r]);
        }
    }
    __syncthreads();
    {
        int r = t >> 3, sub = t & 7;
        float s = 0.f, ss = 0.f;
        #pragma unroll
        for (int j = 0; j < 16; ++j) {
            float v = Xf[r][sub * 16 + j]; s += v; ss += v * v;
        }
        #pragma unroll
        for (int m = 1; m < 8; m <<= 1) { s += __shfl_xor(s, m, 8); ss += __shfl_xor(ss, m, 8); }
        if (sub == 0) {
            float mu = s * (1.f / 128.f);
            mu_[r] = mu;
            isd_[r] = 1.f / sqrtf(ss * (1.f / 128.f) - mu * mu + 1e-5f);
        }
    }
    __syncthreads();
    float* ov = outV + (size_t)bn * 4096;
    for (int i4 = t * 4; i4 < 4096; i4 += 1024) {
        int r = i4 >> 7, c = i4 & 127;
        f32x4 xv = *(const f32x4*)&Xf[r][c];
        f32x4 o;
        #pragma unroll
        for (int j = 0; j < 4; ++j)
            o[j] = n1g[c + j] * (xv[j] - mu_[r]) * isd_[r] + n1b[c + j];
        *(f32x4*)&ov[i4] = o;
    }
}

// ---------------- K2: batched node FFN (M=32 tokens), MFMA, in-place on hv ----
__global__ __launch_bounds__(256, 3) void k_node_ffn(
    float* __restrict__ hv, const float* __restrict__ maskV,
    const u16* __restrict__ wb, const float* __restrict__ bin,
    const float* __restrict__ bout,
    const float* __restrict__ n1g, const float* __restrict__ n1b)
{
    __shared__ __align__(16) float Xf[32][132];
    __shared__ __align__(16) short A1[32 * 136];
    __shared__ __align__(16) short Hd[32 * 264];
    __shared__ float mu_[32], isd_[32];
    const int bn = blockIdx.x, t = threadIdx.x;
    const int w = t >> 6, l = t & 63, l15 = l & 15, lq = l >> 4;
    float* ep = hv + (size_t)bn * 4096;
    for (int i4 = t * 4; i4 < 4096; i4 += 1024) {
        f32x4 v = *(const f32x4*)&ep[i4];
        int r = i4 >> 7, c = i4 & 127;
        *(f32x4*)&Xf[r][c] = v;
        *(s16x4*)&A1[r * 136 + c] = packbf4(v);
    }
    __syncthreads();

    bf16x8 aA[2][4];
    #pragma unroll
    for (int m = 0; m < 2; ++m)
        #pragma unroll
        for (int kt = 0; kt < 4; ++kt)
            aA[m][kt] = *(const bf16x8*)&A1[(m * 16 + l15) * 136 + kt * 32 + lq * 8];

    const int col0 = w * 16 + l15, col1 = (w + 4) * 16 + l15;
    f32x4 acc2[2][2];
    #pragma unroll
    for (int i = 0; i < 2; ++i)
        #pragma unroll
        for (int m = 0; m < 2; ++m) acc2[i][m] = (f32x4){0.f, 0.f, 0.f, 0.f};

    for (int ch = 0; ch < 2; ++ch) {
        #pragma unroll
        for (int nt = 0; nt < 4; ++nt) {
            int lc0 = (w * 4 + nt) * 16;
            int g = ch * 256 + lc0 + l15;
            bf16x8 bB[4];
            #pragma unroll
            for (int kt = 0; kt < 4; ++kt)
                bB[kt] = *(const bf16x8*)(wb + OFF_D1WINT + (size_t)g * 128 + kt * 32 + lq * 8);
            float bi = bin[g];
            #pragma unroll
            for (int m = 0; m < 2; ++m) {
                f32x4 acc = {0.f, 0.f, 0.f, 0.f};
                #pragma unroll
                for (int kt = 0; kt < 4; ++kt)
                    acc = __builtin_amdgcn_mfma_f32_16x16x32_bf16(aA[m][kt], bB[kt], acc, 0, 0, 0);
                #pragma unroll
                for (int r = 0; r < 4; ++r)
                    Hd[(m * 16 + lq * 4 + r) * 264 + lc0 + l15] = (short)f2bf(gelu_f(acc[r] + bi));
            }
        }
        __syncthreads();
        #pragma unroll
        for (int kt = 0; kt < 8; ++kt) {
            bf16x8 a0 = *(const bf16x8*)&Hd[l15 * 264 + kt * 32 + lq * 8];
            bf16x8 a1 = *(const bf16x8*)&Hd[(16 + l15) * 264 + kt * 32 + lq * 8];
            bf16x8 b0 = *(const bf16x8*)(wb + OFF_D1WOUTT + (size_t)col0 * 512 + ch * 256 + kt * 32 + lq * 8);
            bf16x8 b1 = *(const bf16x8*)(wb + OFF_D1WOUTT + (size_t)col1 * 512 + ch * 256 + kt * 32 + lq * 8);
            acc2[0][0] = __builtin_amdgcn_mfma_f32_16x16x32_bf16(a0, b0, acc2[0][0], 0, 0, 0);
            acc2[0][1] = __builtin_amdgcn_mfma_f32_16x16x32_bf16(a1, b0, acc2[0][1], 0, 0, 0);
            acc2[1][0] = __builtin_amdgcn_mfma_f32_16x16x32_bf16(a0, b1, acc2[1][0], 0, 0, 0);
            acc2[1][1] = __builtin_amdgcn_mfma_f32_16x16x32_bf16(a1, b1, acc2[1][1], 0, 0, 0);
        }
        __syncthreads();
    }
    #pragma unroll
    for (int ni = 0; ni < 2; ++ni) {
        int col = ni ? col1 : col0;
        float bo = bout[col];
        #pragma unroll
        for (int m = 0; m < 2; ++m)
            #pragma unroll
            for (int r = 0; r < 4; ++r) {
                int row = m * 16 + lq * 4 + r;
                Xf[row][col] += gelu_f(acc2[ni][m][r] + bo);
            }
    }
    __syncthreads();
    {
        int r = t >> 3, sub = t & 7;
        float s = 0.f, ss = 0.f;
        #pragma unroll
        for (int j = 0; j < 16; ++j) {
            float v = Xf[r][sub * 16 + j]; s += v; ss += v * v;
        }
        #pragma unroll
        for (int m = 1; m < 8; m <<= 1) { s += __shfl_xor(s, m, 8); ss += __shfl_xor(ss, m, 8); }
        if (sub == 0) {
            float mu = s * (1.f / 128.f);
            mu_[r] = mu;
            isd_[r] = 1.f / sqrtf(ss * (1.f / 128.f) - mu * mu + 1e-5f);
        }
    }
    __syncthreads();
    for (int i4 = t * 4; i4 < 4096; i4 += 1024) {
        int r = i4 >> 7, c = i4 & 127;
        float mv = maskV[bn * 32 + r];
        f32x4 xv = *(const f32x4*)&Xf[r][c];
        f32x4 o;
        #pragma unroll
        for (int j = 0; j < 4; ++j)
            o[j] = mv * (n1g[c + j] * (xv[j] - mu_[r]) * isd_[r] + n1b[c + j]);
        *(f32x4*)&ep[i4] = o;
    }
}

// ---------------- K3: batched xop = LN(hv2, op_g, op_beta) @ W1 + b1 (bf16) ---
__global__ __launch_bounds__(256) void k_xop(
    const float* __restrict__ hv2, const u16* __restrict__ wb,
    const float* __restrict__ b1, const float* __restrict__ opg,
    const float* __restrict__ opb, u16* __restrict__ xop)
{
    __shared__ __align__(16) float Xf[32][132];
    __shared__ __align__(16) short A1[32 * 136];
    __shared__ float mu_[32], isd_[32];
    const int bn = blockIdx.x, t = threadIdx.x;
    const int w = t >> 6, l = t & 63, l15 = l & 15, lq = l >> 4;
    const float* ep = hv2 + (size_t)bn * 4096;
    for (int i4 = t * 4; i4 < 4096; i4 += 1024) {
        f32x4 v = *(const f32x4*)&ep[i4];
        *(f32x4*)&Xf[i4 >> 7][i4 & 127] = v;
    }
    __syncthreads();
    {
        int r = t >> 3, sub = t & 7;
        float s = 0.f, ss = 0.f;
        #pragma unroll
        for (int j = 0; j < 16; ++j) {
            float v = Xf[r][sub * 16 + j]; s += v; ss += v * v;
        }
        #pragma unroll
        for (int m = 1; m < 8; m <<= 1) { s += __shfl_xor(s, m, 8); ss += __shfl_xor(ss, m, 8); }
        if (sub == 0) {
            float mu = s * (1.f / 128.f);
            mu_[r] = mu;
            isd_[r] = 1.f / sqrtf(ss * (1.f / 128.f) - mu * mu + 1e-5f);
        }
    }
    __syncthreads();
    for (int i4 = t * 4; i4 < 4096; i4 += 1024) {
        int r = i4 >> 7, c = i4 & 127;
        f32x4 xv = *(const f32x4*)&Xf[r][c];
        f32x4 y;
        #pragma unroll
        for (int j = 0; j < 4; ++j)
            y[j] = opg[c + j] * (xv[j] - mu_[r]) * isd_[r] + opb[c + j];
        *(s16x4*)&A1[r * 136 + c] = packbf4(y);
    }
    __syncthreads();
    #pragma unroll
    for (int i = 0; i < 4; ++i) {
        int id = w + 4 * i;
        int m0 = (id >> 3) << 4, n0 = (id & 7) << 4;
        f32x4 acc = {0.f, 0.f, 0.f, 0.f};
        #pragma unroll
        for (int kt = 0; kt < 4; ++kt) {
            bf16x8 a = *(const bf16x8*)&A1[(m0 + l15) * 136 + kt * 32 + lq * 8];
            bf16x8 bv = *(const bf16x8*)(wb + OFF_OPW1T + (size_t)(n0 + l15) * 128 + kt * 32 + lq * 8);
            acc = __builtin_amdgcn_mfma_f32_16x16x32_bf16(a, bv, acc, 0, 0, 0);
        }
        int col = n0 + l15;
        float bb = b1[col];
        #pragma unroll
        for (int r = 0; r < 4; ++r)
            xop[(size_t)(bn * 32 + m0 + lq * 4 + r) * 128 + col] = f2bf(acc[r] + bb);
    }
}

// ---------------- K4: h_E1 = h_E + (x ⊙ x[nbr]) @ W2 + b2 -> outE (MFMA) ------
__global__ __launch_bounds__(256) void k_outer(
    const u16* __restrict__ xop, const float* __restrict__ hE,
    const int* __restrict__ Eidx, const u16* __restrict__ wb,
    const float* __restrict__ b2, float* __restrict__ outE)
{
    __shared__ __align__(16) short A1[32 * 136];
    __shared__ float xcf[128];
    __shared__ int idxs[32];
    const int bn = blockIdx.x, t = threadIdx.x;
    const int b = bn >> 11;
    const int w = t >> 6, l = t & 63, l15 = l & 15, lq = l >> 4;
    if (t < 128) xcf[t] = bf2f(xop[(size_t)bn * 128 + t]);
    if (t < 32) idxs[t] = Eidx[(size_t)bn * 32 + t];
    __syncthreads();
    for (int i4 = t * 4; i4 < 4096; i4 += 1024) {
        int k = i4 >> 7, h = i4 & 127;
        s16x4 nb = *(const s16x4*)&xop[((size_t)b * Nn + idxs[k]) * 128 + h];
        f32x4 prod;
        prod.x = xcf[h] * bf2f(nb.x);
        prod.y = xcf[h + 1] * bf2f(nb.y);
        prod.z = xcf[h + 2] * bf2f(nb.z);
        prod.w = xcf[h + 3] * bf2f(nb.w);
        *(s16x4*)&A1[k * 136 + h] = packbf4(prod);
    }
    __syncthreads();
    const u16* Bp = wb + OFF_OPW2T;
    #pragma unroll
    for (int i = 0; i < 4; ++i) {
        int id = w + 4 * i, m0 = (id >> 3) << 4, n0 = (id & 7) << 4;
        f32x4 acc = {0.f, 0.f, 0.f, 0.f};
        #pragma unroll
        for (int kt = 0; kt < 4; ++kt) {
            bf16x8 a = *(const bf16x8*)&A1[(m0 + l15) * 136 + kt * 32 + lq * 8];
            bf16x8 bv = *(const bf16x8*)(Bp + (size_t)(n0 + l15) * 128 + kt * 32 + lq * 8);
            acc = __builtin_amdgcn_mfma_f32_16x16x32_bf16(a, bv, acc, 0, 0, 0);
        }
        int col = n0 + l15;
        float bb = b2[col];
        #pragma unroll
        for (int r = 0; r < 4; ++r) {
            int row = m0 + lq * 4 + r;
            size_t o = (size_t)bn * 4096 + row * 128 + col;
            outE[o] = hE[o] + acc[r] + bb;
        }
    }
}

// ---------------- K5: edge self-attention + gelu + residual + LN(n3), in place
__global__ __launch_bounds__(256) void k_edge_attn(
    const float* __restrict__ maskA, const u16* __restrict__ wb,
    const float* __restrict__ n3g, const float* __restrict__ n3b,
    float* __restrict__ outE)
{
    __shared__ __align__(16) float Xf[32][132];
    __shared__ __align__(16) short A1[32 * 136];     // X bf16; later O2
    __shared__ __align__(16) short QeP[5120];        // Qe [32][136-ish]; later Pe [4][32][40]
    __shared__ __align__(16) short Ke[32 * 136];
    __shared__ __align__(16) short Vp[4 * 32 * 40];  // V''[a][dd][c]
    __shared__ __align__(16) float Le[NH_][Kk][Kk + 1];
    __shared__ float ms[32];
    __shared__ float mu_[32], isd_[32];

    const int bn = blockIdx.x, t = threadIdx.x;
    const int w = t >> 6, l = t & 63, l15 = l & 15, lq = l >> 4;
    float* ep = outE + (size_t)bn * 4096;

    for (int i4 = t * 4; i4 < 4096; i4 += 1024) {
        f32x4 v = *(const f32x4*)&ep[i4];
        int r = i4 >> 7, c = i4 & 127;
        *(f32x4*)&Xf[r][c] = v;
        *(s16x4*)&A1[r * 136 + c] = packbf4(v);
    }
    if (t < 32) ms[t] = maskA[(size_t)bn * 32 + t];
    __syncthreads();

    // Projections: Q = X@WO (faithful), K = X@WK, V = X@WV
    #pragma unroll
    for (int i = 0; i < 12; ++i) {
        int id = w + 4 * i;
        int mat = id >> 4, rem = id & 15;
        int m0 = (rem >> 3) << 4, n0 = (rem & 7) << 4;
        const u16* Bp = wb + ((mat == 0) ? OFF_EAWOT : (mat == 1) ? OFF_EAWKT : OFF_EAWVT);
        f32x4 acc = {0.f, 0.f, 0.f, 0.f};
        #pragma unroll
        for (int kt = 0; kt < 4; ++kt) {
            bf16x8 a = *(const bf16x8*)&A1[(m0 + l15) * 136 + kt * 32 + lq * 8];
            bf16x8 bv = *(const bf16x8*)(Bp + (size_t)(n0 + l15) * 128 + kt * 32 + lq * 8);
            acc = __builtin_amdgcn_mfma_f32_16x16x32_bf16(a, bv, acc, 0, 0, 0);
        }
        int col = n0 + l15;
        #pragma unroll
        for (int r = 0; r < 4; ++r) {
            int row = m0 + lq * 4 + r;
            u16 hv = f2bf(acc[r]);
            if (mat == 0) QeP[row * 136 + col] = (short)hv;
            else if (mat == 1) Ke[row * 136 + col] = (short)hv;
            else Vp[((row >> 3) * 32 + (col & 31)) * 40 + (((row & 7) << 2) | (col >> 5))] = (short)hv;
        }
    }
    __syncthreads();

    // logits via MFMA over d=32: Le[h][q][k]
    #pragma unroll
    for (int i = 0; i < 4; ++i) {
        int id = w + 4 * i;
        int h = id >> 2, rem = id & 3;
        int q0 = (rem >> 1) << 4, k0 = (rem & 1) << 4;
        int q = q0 + l15, k = k0 + l15;
        bf16x8 a = *(const bf16x8*)&QeP[(((h << 3) | (q >> 2)) * 136) + (((q & 3) << 5) + lq * 8)];
        bf16x8 bv = *(const bf16x8*)&Ke[(((h << 3) | (k >> 2)) * 136) + (((k & 3) << 5) + lq * 8)];
        f32x4 acc = {0.f, 0.f, 0.f, 0.f};
        acc = __builtin_amdgcn_mfma_f32_16x16x32_bf16(a, bv, acc, 0, 0, 0);
        #pragma unroll
        for (int r = 0; r < 4; ++r)
            Le[h][q0 + lq * 4 + r][k0 + l15] = acc[r];
    }
    __syncthreads();

    // masked softmax (reshape+swap semantics), write Pe bf16 into QeP region
    if (t < 128) {
        int a = t >> 5, q2 = t & 31;
        float mq = ms[q2];
        float lv[Kk];
        float mx = NEGF;
        #pragma unroll
        for (int c = 0; c < Kk; ++c) {
            float lg = Le[c >> 3][((c & 7) << 2) | (q2 >> 3)][((q2 & 7) << 2) | a]
                       * 0.17677669529663687f;
            lv[c] = (mq * ms[c] > 0.f) ? lg : NEGF;
            mx = fmaxf(mx, lv[c]);
        }
        float s = 0.f;
        #pragma unroll
        for (int c = 0; c < Kk; ++c) { lv[c] = __expf(lv[c] - mx); s += lv[c]; }
        float inv = 1.f / s;
        #pragma unroll
        for (int c = 0; c < Kk; ++c)
            QeP[((a * 32 + q2) * 40) + c] = (short)f2bf(lv[c] * inv);
    }
    __syncthreads();

    // PV via MFMA over c=32: O2[q2][(a<<5)+dd] into A1 region
    #pragma unroll
    for (int i = 0; i < 4; ++i) {
        int id = w + 4 * i;
        int a = id >> 2, rem = id & 3;
        int q0 = (rem >> 1) << 4, d0 = (rem & 1) << 4;
        bf16x8 pa = *(const bf16x8*)&QeP[((a * 32 + q0 + l15) * 40) + lq * 8];
        bf16x8 vb = *(const bf16x8*)&Vp[((a * 32 + d0 + l15) * 40) + lq * 8];
        f32x4 acc = {0.f, 0.f, 0.f, 0.f};
        acc = __builtin_amdgcn_mfma_f32_16x16x32_bf16(pa, vb, acc, 0, 0, 0);
        #pragma unroll
        for (int r = 0; r < 4; ++r)
            A1[(q0 + lq * 4 + r) * 136 + (a << 5) + d0 + l15] = (short)f2bf(acc[r]);
    }
    __syncthreads();

    // final: dh = gelu(O2 @ WO); Xf += dh
    const u16* Bo = wb + OFF_EAWOT;
    #pragma unroll
    for (int i = 0; i < 4; ++i) {
        int id = w + 4 * i;
        int m0 = (id >> 3) << 4, n0 = (id & 7) << 4;
        f32x4 acc = {0.f, 0.f, 0.f, 0.f};
        #pragma unroll
        for (int kt = 0; kt < 4; ++kt) {
            bf16x8 a = *(const bf16x8*)&A1[(m0 + l15) * 136 + kt * 32 + lq * 8];
            bf16x8 bv = *(const bf16x8*)(Bo + (size_t)(n0 + l15) * 128 + kt * 32 + lq * 8);
            acc = __builtin_amdgcn_mfma_f32_16x16x32_bf16(a, bv, acc, 0, 0, 0);
        }
        int col = n0 + l15;
        #pragma unroll
        for (int r = 0; r < 4; ++r) {
            int row = m0 + lq * 4 + r;
            Xf[row][col] += gelu_f(acc[r]);
        }
    }
    __syncthreads();
    {
        int r = t >> 3, sub = t & 7;
        float s = 0.f, ss = 0.f;
        #pragma unroll
        for (int j = 0; j < 16; ++j) {
            float v = Xf[r][sub * 16 + j]; s += v; ss += v * v;
        }
        #pragma unroll
        for (int m = 1; m < 8; m <<= 1) { s += __shfl_xor(s, m, 8); ss += __shfl_xor(ss, m, 8); }
        if (sub == 0) {
            float mu = s * (1.f / 128.f);
            mu_[r] = mu;
            isd_[r] = 1.f / sqrtf(ss * (1.f / 128.f) - mu * mu + 1e-5f);
        }
    }
    __syncthreads();
    for (int i4 = t * 4; i4 < 4096; i4 += 1024) {
        int r = i4 >> 7, c = i4 & 127;
        f32x4 xv = *(const f32x4*)&Xf[r][c];
        f32x4 o;
        #pragma unroll
        for (int j = 0; j < 4; ++j)
            o[j] = n3g[c + j] * (xv[j] - mu_[r]) * isd_[r] + n3b[c + j];
        *(f32x4*)&ep[i4] = o;
    }
}

// ---------------- K6: edge FFN + gelu + residual + LN(n4), in place (MFMA) ----
__global__ __launch_bounds__(256, 3) void k_edge_ffn(
    const u16* __restrict__ wb, const float* __restrict__ bin,
    const float* __restrict__ bout,
    const float* __restrict__ n4g, const float* __restrict__ n4b,
    float* __restrict__ outE)
{
    __shared__ __align__(16) float Xf[32][132];
    __shared__ __align__(16) short A1[32 * 136];
    __shared__ __align__(16) short Hd[32 * 264];
    __shared__ float mu_[32], isd_[32];
    const int bn = blockIdx.x, t = threadIdx.x;
    const int w = t >> 6, l = t & 63, l15 = l & 15, lq = l >> 4;
    float* ep = outE + (size_t)bn * 4096;
    for (int i4 = t * 4; i4 < 4096; i4 += 1024) {
        f32x4 v = *(const f32x4*)&ep[i4];
        int r = i4 >> 7, c = i4 & 127;
        *(f32x4*)&Xf[r][c] = v;
        *(s16x4*)&A1[r * 136 + c] = packbf4(v);
    }
    __syncthreads();

    bf16x8 aA[2][4];
    #pragma unroll
    for (int m = 0; m < 2; ++m)
        #pragma unroll
        for (int kt = 0; kt < 4; ++kt)
            aA[m][kt] = *(const bf16x8*)&A1[(m * 16 + l15) * 136 + kt * 32 + lq * 8];

    const int col0 = w * 16 + l15, col1 = (w + 4) * 16 + l15;
    f32x4 acc2[2][2];
    #pragma unroll
    for (int i = 0; i < 2; ++i)
        #pragma unroll
        for (int m = 0; m < 2; ++m) acc2[i][m] = (f32x4){0.f, 0.f, 0.f, 0.f};

    for (int ch = 0; ch < 2; ++ch) {
        #pragma unroll
        for (int nt = 0; nt < 4; ++nt) {
            int lc0 = (w * 4 + nt) * 16;
            int g = ch * 256 + lc0 + l15;
            bf16x8 bB[4];
            #pragma unroll
            for (int kt = 0; kt < 4; ++kt)
                bB[kt] = *(const bf16x8*)(wb + OFF_D2WINT + (size_t)g * 128 + kt * 32 + lq * 8);
            float bi = bin[g];
            #pragma unroll
            for (int m = 0; m < 2; ++m) {
                f32x4 acc = {0.f, 0.f, 0.f, 0.f};
                #pragma unroll
                for (int kt = 0; kt < 4; ++kt)
                    acc = __builtin_amdgcn_mfma_f32_16x16x32_bf16(aA[m][kt], bB[kt], acc, 0, 0, 0);
                #pragma unroll
                for (int r = 0; r < 4; ++r)
                    Hd[(m * 16 + lq * 4 + r) * 264 + lc0 + l15] = (short)f2bf(gelu_f(acc[r] + bi));
            }
        }
        __syncthreads();
        #pragma unroll
        for (int kt = 0; kt < 8; ++kt) {
            bf16x8 a0 = *(const bf16x8*)&Hd[l15 * 264 + kt * 32 + lq * 8];
            bf16x8 a1 = *(const bf16x8*)&Hd[(16 + l15) * 264 + kt * 32 + lq * 8];
            bf16x8 b0 = *(const bf16x8*)(wb + OFF_D2WOUTT + (size_t)col0 * 512 + ch * 256 + kt * 32 + lq * 8);
            bf16x8 b1 = *(const bf16x8*)(wb + OFF_D2WOUTT + (size_t)col1 * 512 + ch * 256 + kt * 32 + lq * 8);
            acc2[0][0] = __builtin_amdgcn_mfma_f32_16x16x32_bf16(a0, b0, acc2[0][0], 0, 0, 0);
            acc2[0][1] = __builtin_amdgcn_mfma_f32_16x16x32_bf16(a1, b0, acc2[0][1], 0, 0, 0);
            acc2[1][0] = __builtin_amdgcn_mfma_f32_16x16x32_bf16(a0, b1, acc2[1][0], 0, 0, 0);
            acc2[1][1] = __builtin_amdgcn_mfma_f32_16x16x32_bf16(a1, b1, acc2[1][1], 0, 0, 0);
        }
        __syncthreads();
    }
    #pragma unroll
    for (int ni = 0; ni < 2; ++ni) {
        int col = ni ? col1 : col0;
        float bo = bout[col];
        #pragma unroll
        for (int m = 0; m < 2; ++m)
            #pragma unroll
            for (int r = 0; r < 4; ++r) {
                int row = m * 16 + lq * 4 + r;
                Xf[row][col] += gelu_f(acc2[ni][m][r] + bo);
            }
    }
    __syncthreads();
    {
        int r = t >> 3, sub = t & 7;
        float s = 0.f, ss = 0.f;
        #pragma unroll
        for (int j = 0; j < 16; ++j) {
            float v = Xf[r][sub * 16 + j]; s += v; ss += v * v;
        }
        #pragma unroll
        for (int m = 1; m < 8; m <<= 1) { s += __shfl_xor(s, m, 8); ss += __shfl_xor(ss, m, 8); }
        if (sub == 0) {
            float mu = s * (1.f / 128.f);
            mu_[r] = mu;
            isd_[r] = 1.f / sqrtf(ss * (1.f / 128.f) - mu * mu + 1e-5f);
        }
    }
    __syncthreads();
    for (int i4 = t * 4; i4 < 4096; i4 += 1024) {
        int r = i4 >> 7, c = i4 & 127;
        f32x4 xv = *(const f32x4*)&Xf[r][c];
        f32x4 o;
        #pragma unroll
        for (int j = 0; j < 4; ++j)
            o[j] = n4g[c + j] * (xv[j] - mu_[r]) * isd_[r] + n4b[c + j];
        *(f32x4*)&ep[i4] = o;
    }
}

extern "C" void kernel_launch(void* const* d_in, const int* in_sizes, int n_in,
                              void* d_out, int out_size, void* d_ws, size_t ws_size,
                              hipStream_t stream) {
    const float* hV     = (const float*)d_in[0];
    const float* hE     = (const float*)d_in[1];
    const float* hEV    = (const float*)d_in[2];
    const float* maskV  = (const float*)d_in[3];
    const float* maskA  = (const float*)d_in[4];
    const float* naWQ   = (const float*)d_in[5];
    const float* naWK   = (const float*)d_in[6];
    const float* naWV   = (const float*)d_in[7];
    const float* naWO   = (const float*)d_in[8];
    const float* eaWK   = (const float*)d_in[9];
    const float* eaWV   = (const float*)d_in[10];
    const float* eaWO   = (const float*)d_in[11];
    const float* d1Win  = (const float*)d_in[12];
    const float* d1bin  = (const float*)d_in[13];
    const float* d1Wout = (const float*)d_in[14];
    const float* d1bout = (const float*)d_in[15];
    const float* d2Win  = (const float*)d_in[16];
    const float* d2bin  = (const float*)d_in[17];
    const float* d2Wout = (const float*)d_in[18];
    const float* d2bout = (const float*)d_in[19];
    const float* opW1   = (const float*)d_in[20];
    const float* opb1   = (const float*)d_in[21];
    const float* opW2   = (const float*)d_in[22];
    const float* opb2   = (const float*)d_in[23];
    const float* opg    = (const float*)d_in[24];
    const float* opbeta = (const float*)d_in[25];
    const float* n1g    = (const float*)d_in[26];
    const float* n1b    = (const float*)d_in[27];
    const float* n3g    = (const float*)d_in[28];
    const float* n3b    = (const float*)d_in[29];
    const float* n4g    = (const float*)d_in[30];
    const float* n4b    = (const float*)d_in[31];
    const int*   Eidx   = (const int*)d_in[32];

    float* outV = (float*)d_out;
    float* outE = outV + (size_t)Bb * Nn * Hh;
    u16* xop = (u16*)d_ws;                        // [B*N*H] bf16 (2 MB)
    u16* wb  = (u16*)d_ws + (size_t)Bb * Nn * Hh; // bf16 weights (~880 KB)
    // scratch inside outE region (consumed before k_outer writes it):
    u16* Qall = (u16*)(outE + (size_t)30 * 1048576);  // 2 MB @ +120MB
    u16* outr = (u16*)(outE + (size_t)31 * 1048576);  // 2 MB @ +124MB

    dim3 blk(256);
    k_prep<<<dim3(WB_TOTAL / 256), blk, 0, stream>>>(naWK, naWV, eaWK, eaWV, eaWO,
                                                     d2Win, d2Wout, opW2,
                                                     d1Win, d1Wout, opW1,
                                                     naWQ, naWO, wb);
    dim3 gridTok(Bb * Nn / 32);
    dim3 grid(Bb * Nn);
    k_qproj<<<gridTok, blk, 0, stream>>>(hV, wb, Qall);
    k_node_core<<<grid, blk, 0, stream>>>(hEV, maskA, Qall, wb, outr);
    k_node_out<<<gridTok, blk, 0, stream>>>(outr, hV, wb, n1g, n1b, outV);
    k_node_ffn<<<gridTok, blk, 0, stream>>>(outV, maskV, wb, d1bin,
                                            d1bout, n1g, n1b);
    k_xop<<<gridTok, blk, 0, stream>>>(outV, wb, opb1, opg, opbeta, xop);
    k_outer<<<grid, blk, 0, stream>>>(xop, hE, Eidx, wb, opb2, outE);
    k_edge_attn<<<grid, blk, 0, stream>>>(maskA, wb, n3g, n3b, outE);
    k_edge_ffn<<<grid, blk, 0, stream>>>(wb, d2bin, d2bout, n4g, n4b, outE);
}

// Round 5
// 854.446 us; speedup vs baseline: 6.7827x; 1.1603x over previous
//
#include <hip/hip_runtime.h>
#include <hip/hip_bf16.h>
#include <math.h>

#define Bb 4
#define Nn 2048
#define Kk 32
#define Hh 128
#define NIi 256
#define NH_ 4
#define Dd 32
#define DFFh 512

#define NEGF -3.402823466e38f

typedef unsigned short u16;
typedef __attribute__((ext_vector_type(8))) short bf16x8;
typedef __attribute__((ext_vector_type(4))) short s16x4;
typedef __attribute__((ext_vector_type(4))) float f32x4;

// bf16 weight buffer offsets (elements); base = d_ws + 2MB
#define OFF_NAWKT   0        // [128][256]
#define OFF_NAWVT   32768    // [128][256]
#define OFF_EAWKT   65536    // [128][128]
#define OFF_EAWVT   81920
#define OFF_EAWOT   98304
#define OFF_D2WINT  114688   // [512][128]
#define OFF_D2WOUTT 180224   // [128][512]
#define OFF_OPW2T   245760   // [128][128]
#define OFF_D1WINT  262144   // [512][128]
#define OFF_D1WOUTT 327680   // [128][512]
#define OFF_OPW1T   393216   // [128][128]
#define OFF_NAWQT   409600   // [128][128]
#define OFF_NAWOT   425984   // [128][128]
#define WB_TOTAL    442368

// Fast exact-gelu: A&S 7.1.26 erf (|eps|<=1.5e-7), branchless.
__device__ __forceinline__ float gelu_f(float x) {
    float z = x * 0.7071067811865476f;
    float a = fabsf(z);
    float d = fmaf(0.3275911f, a, 1.0f);
    float t = __fdividef(1.0f, d);
    float p = fmaf(fmaf(fmaf(fmaf(1.061405429f, t, -1.453152027f), t,
                             1.421413741f), t, -0.284496736f), t, 0.254829592f);
    float e = __expf(-a * a);
    float erfa = fmaf(-p * t, e, 1.0f);
    float er = copysignf(erfa, z);
    return 0.5f * x * (1.0f + er);
}

__device__ __forceinline__ u16 f2bf(float f) {
    union { __hip_bfloat16 h; u16 u; } v;
    v.h = __float2bfloat16(f);
    return v.u;
}

__device__ __forceinline__ float bf2f(u16 u) {
    union { unsigned int u; float f; } v; v.u = ((unsigned int)u) << 16;
    return v.f;
}

__device__ __forceinline__ s16x4 packbf4(f32x4 v) {
    s16x4 r;
    r.x = (short)f2bf(v.x); r.y = (short)f2bf(v.y);
    r.z = (short)f2bf(v.z); r.w = (short)f2bf(v.w);
    return r;
}

// ---------------- K0: convert + transpose weights to bf16 in ws ---------------
__global__ __launch_bounds__(256) void k_prep(
    const float* __restrict__ naWK, const float* __restrict__ naWV,
    const float* __restrict__ eaWK, const float* __restrict__ eaWV,
    const float* __restrict__ eaWO, const float* __restrict__ d2Win,
    const float* __restrict__ d2Wout, const float* __restrict__ opW2,
    const float* __restrict__ d1Win, const float* __restrict__ d1Wout,
    const float* __restrict__ opW1, const float* __restrict__ naWQ,
    const float* __restrict__ naWO, u16* __restrict__ wb)
{
    int i = blockIdx.x * 256 + threadIdx.x;
    const float* src; int R, C, off;
    if (i < 32768)       { src = naWK;   R = 256; C = 128; off = OFF_NAWKT; }
    else if (i < 65536)  { src = naWV;   R = 256; C = 128; off = OFF_NAWVT; }
    else if (i < 81920)  { src = eaWK;   R = 128; C = 128; off = OFF_EAWKT; }
    else if (i < 98304)  { src = eaWV;   R = 128; C = 128; off = OFF_EAWVT; }
    else if (i < 114688) { src = eaWO;   R = 128; C = 128; off = OFF_EAWOT; }
    else if (i < 180224) { src = d2Win;  R = 128; C = 512; off = OFF_D2WINT; }
    else if (i < 245760) { src = d2Wout; R = 512; C = 128; off = OFF_D2WOUTT; }
    else if (i < 262144) { src = opW2;   R = 128; C = 128; off = OFF_OPW2T; }
    else if (i < 327680) { src = d1Win;  R = 128; C = 512; off = OFF_D1WINT; }
    else if (i < 393216) { src = d1Wout; R = 512; C = 128; off = OFF_D1WOUTT; }
    else if (i < 409600) { src = opW1;   R = 128; C = 128; off = OFF_OPW1T; }
    else if (i < 425984) { src = naWQ;   R = 128; C = 128; off = OFF_NAWQT; }
    else                 { src = naWO;   R = 128; C = 128; off = OFF_NAWOT; }
    int j = i - off;
    int c = j / R, r = j - c * R;       // dest W^T[C][R]
    wb[i] = f2bf(src[r * C + c]);
}

// ---------------- K1a: batched Qall = hV @ WQ (bf16) --------------------------
__global__ __launch_bounds__(256) void k_qproj(
    const float* __restrict__ hV, const u16* __restrict__ wb,
    u16* __restrict__ Qall)
{
    __shared__ __align__(16) short A1[32 * 136];
    const int bn = blockIdx.x, t = threadIdx.x;
    const int w = t >> 6, l = t & 63, l15 = l & 15, lq = l >> 4;
    const float* xp = hV + (size_t)bn * 4096;
    for (int i4 = t * 4; i4 < 4096; i4 += 1024)
        *(s16x4*)&A1[(i4 >> 7) * 136 + (i4 & 127)] = packbf4(*(const f32x4*)&xp[i4]);
    __syncthreads();
    #pragma unroll
    for (int i = 0; i < 4; ++i) {
        int id = w + 4 * i;
        int m0 = (id >> 3) << 4, n0 = (id & 7) << 4;
        f32x4 acc = {0.f, 0.f, 0.f, 0.f};
        #pragma unroll
        for (int kt = 0; kt < 4; ++kt) {
            bf16x8 a = *(const bf16x8*)&A1[(m0 + l15) * 136 + kt * 32 + lq * 8];
            bf16x8 bv = *(const bf16x8*)(wb + OFF_NAWQT + (size_t)(n0 + l15) * 128 + kt * 32 + lq * 8);
            acc = __builtin_amdgcn_mfma_f32_16x16x32_bf16(a, bv, acc, 0, 0, 0);
        }
        int col = n0 + l15;
        #pragma unroll
        for (int r = 0; r < 4; ++r)
            Qall[(size_t)(bn * 32 + m0 + lq * 4 + r) * 128 + col] = f2bf(acc[r]);
    }
}

// ---------------- K1b: per-token attention core -> outr (bf16) ----------------
__global__ __launch_bounds__(256, 4) void k_node_core(
    const float* __restrict__ hEV, const float* __restrict__ maskA,
    const u16* __restrict__ Qall, const u16* __restrict__ wb,
    u16* __restrict__ outr)
{
    __shared__ __align__(16) short EVb[32 * 264];   // 16.9 KB
    __shared__ __align__(16) short KtT[128 * 34];   // K^T [h][k], 8.7 KB
    __shared__ __align__(16) short VtT[128 * 34];   // V^T [h][k], 8.7 KB
    __shared__ float Qs[128];
    __shared__ float att[NH_][Kk];

    const int bn = blockIdx.x, t = threadIdx.x;
    const int w = t >> 6, l = t & 63, l15 = l & 15, lq = l >> 4;
    const float* evp = hEV + (size_t)bn * 8192;
    for (int i8 = t * 8; i8 < 8192; i8 += 2048) {
        f32x4 v0 = *(const f32x4*)&evp[i8];
        f32x4 v1 = *(const f32x4*)&evp[i8 + 4];
        int r = i8 >> 8, c = i8 & 255;
        *(s16x4*)&EVb[r * 264 + c] = packbf4(v0);
        *(s16x4*)&EVb[r * 264 + c + 4] = packbf4(v1);
    }
    if (t < 128) Qs[t] = bf2f(Qall[(size_t)bn * 128 + t]);
    __syncthreads();

    // K = EV @ WK, V = EV @ WV via MFMA; store transposed bf16
    #pragma unroll
    for (int i = 0; i < 8; ++i) {
        int id = w + 4 * i;
        int mat = id >> 4, rem = id & 15;
        int m0 = (rem >> 3) << 4, n0 = (rem & 7) << 4;
        const u16* Bp = wb + (mat ? OFF_NAWVT : OFF_NAWKT);
        f32x4 acc = {0.f, 0.f, 0.f, 0.f};
        #pragma unroll
        for (int kt = 0; kt < 8; ++kt) {
            bf16x8 a = *(const bf16x8*)&EVb[(m0 + l15) * 264 + kt * 32 + lq * 8];
            bf16x8 b = *(const bf16x8*)(Bp + (size_t)(n0 + l15) * 256 + kt * 32 + lq * 8);
            acc = __builtin_amdgcn_mfma_f32_16x16x32_bf16(a, b, acc, 0, 0, 0);
        }
        int col = n0 + l15;
        short* dst = mat ? VtT : KtT;
        #pragma unroll
        for (int r = 0; r < 4; ++r)
            dst[col * 34 + m0 + lq * 4 + r] = (short)f2bf(acc[r]);
    }
    __syncthreads();

    // logits + wave-parallel masked softmax (nh = t>>5, k = t&31)
    if (t < 128) {
        int nh = t >> 5, k = t & 31;
        float a = 0.f;
        #pragma unroll
        for (int d = 0; d < 32; ++d)
            a += Qs[nh * 32 + d] * bf2f(KtT[(nh * 32 + d) * 34 + k]);
        float mk = maskA[(size_t)bn * 32 + k];
        float lg = (mk > 0.f) ? a * 0.17677669529663687f : NEGF;
        float mx = lg;
        #pragma unroll
        for (int s = 16; s; s >>= 1) mx = fmaxf(mx, __shfl_xor(mx, s, 32));
        float e = __expf(lg - mx);
        float sum = e;
        #pragma unroll
        for (int s = 16; s; s >>= 1) sum += __shfl_xor(sum, s, 32);
        att[nh][k] = mk * e / sum;
    }
    __syncthreads();
    // PV (nh = t>>5, d = t&31)
    if (t < 128) {
        int nh = t >> 5, d = t & 31;
        float a = 0.f;
        #pragma unroll
        for (int k = 0; k < 32; ++k)
            a += att[nh][k] * bf2f(VtT[(nh * 32 + d) * 34 + k]);
        outr[(size_t)bn * 128 + t] = f2bf(a);
    }
}

// ---------------- K1c: batched LN(hV + gelu(outr @ WO)) -> outV ---------------
__global__ __launch_bounds__(256) void k_node_out(
    const u16* __restrict__ outr, const float* __restrict__ hV,
    const u16* __restrict__ wb,
    const float* __restrict__ n1g, const float* __restrict__ n1b,
    float* __restrict__ outV)
{
    __shared__ __align__(16) float Xf[32][132];
    __shared__ __align__(16) short A1[32 * 136];
    __shared__ float mu_[32], isd_[32];
    const int bn = blockIdx.x, t = threadIdx.x;
    const int w = t >> 6, l = t & 63, l15 = l & 15, lq = l >> 4;
    const float* xp = hV + (size_t)bn * 4096;
    const u16* op = outr + (size_t)bn * 4096;
    for (int i4 = t * 4; i4 < 4096; i4 += 1024) {
        int r = i4 >> 7, c = i4 & 127;
        *(f32x4*)&Xf[r][c] = *(const f32x4*)&xp[i4];
        *(s16x4*)&A1[r * 136 + c] = *(const s16x4*)&op[i4];
    }
    __syncthreads();
    #pragma unroll
    for (int i = 0; i < 4; ++i) {
        int id = w + 4 * i;
        int m0 = (id >> 3) << 4, n0 = (id & 7) << 4;
        f32x4 acc = {0.f, 0.f, 0.f, 0.f};
        #pragma unroll
        for (int kt = 0; kt < 4; ++kt) {
            bf16x8 a = *(const bf16x8*)&A1[(m0 + l15) * 136 + kt * 32 + lq * 8];
            bf16x8 bv = *(const bf16x8*)(wb + OFF_NAWOT + (size_t)(n0 + l15) * 128 + kt * 32 + lq * 8);
            acc = __builtin_amdgcn_mfma_f32_16x16x32_bf16(a, bv, acc, 0, 0, 0);
        }
        int col = n0 + l15;
        #pragma unroll
        for (int r = 0; r < 4; ++r) {
            int row = m0 + lq * 4 + r;
            Xf[row][col] += gelu_f(acc[r]);
        }
    }
    __syncthreads();
    {
        int r = t >> 3, sub = t & 7;
        float s = 0.f, ss = 0.f;
        #pragma unroll
        for (int j = 0; j < 16; ++j) {
            float v = Xf[r][sub * 16 + j]; s += v; ss += v * v;
        }
        #pragma unroll
        for (int m = 1; m < 8; m <<= 1) { s += __shfl_xor(s, m, 8); ss += __shfl_xor(ss, m, 8); }
        if (sub == 0) {
            float mu = s * (1.f / 128.f);
            mu_[r] = mu;
            isd_[r] = 1.f / sqrtf(ss * (1.f / 128.f) - mu * mu + 1e-5f);
        }
    }
    __syncthreads();
    float* ov = outV + (size_t)bn * 4096;
    for (int i4 = t * 4; i4 < 4096; i4 += 1024) {
        int r = i4 >> 7, c = i4 & 127;
        f32x4 xv = *(const f32x4*)&Xf[r][c];
        f32x4 o;
        #pragma unroll
        for (int j = 0; j < 4; ++j)
            o[j] = n1g[c + j] * (xv[j] - mu_[r]) * isd_[r] + n1b[c + j];
        *(f32x4*)&ov[i4] = o;
    }
}

// ---------------- K2: batched node FFN (M=32 tokens), MFMA, in-place on hv ----
__global__ __launch_bounds__(256, 3) void k_node_ffn(
    float* __restrict__ hv, const float* __restrict__ maskV,
    const u16* __restrict__ wb, const float* __restrict__ bin,
    const float* __restrict__ bout,
    const float* __restrict__ n1g, const float* __restrict__ n1b)
{
    __shared__ __align__(16) float Xf[32][132];
    __shared__ __align__(16) short A1[32 * 136];
    __shared__ __align__(16) short Hd[32 * 264];
    __shared__ float mu_[32], isd_[32];
    const int bn = blockIdx.x, t = threadIdx.x;
    const int w = t >> 6, l = t & 63, l15 = l & 15, lq = l >> 4;
    float* ep = hv + (size_t)bn * 4096;
    for (int i4 = t * 4; i4 < 4096; i4 += 1024) {
        f32x4 v = *(const f32x4*)&ep[i4];
        int r = i4 >> 7, c = i4 & 127;
        *(f32x4*)&Xf[r][c] = v;
        *(s16x4*)&A1[r * 136 + c] = packbf4(v);
    }
    __syncthreads();

    bf16x8 aA[2][4];
    #pragma unroll
    for (int m = 0; m < 2; ++m)
        #pragma unroll
        for (int kt = 0; kt < 4; ++kt)
            aA[m][kt] = *(const bf16x8*)&A1[(m * 16 + l15) * 136 + kt * 32 + lq * 8];

    const int col0 = w * 16 + l15, col1 = (w + 4) * 16 + l15;
    f32x4 acc2[2][2];
    #pragma unroll
    for (int i = 0; i < 2; ++i)
        #pragma unroll
        for (int m = 0; m < 2; ++m) acc2[i][m] = (f32x4){0.f, 0.f, 0.f, 0.f};

    for (int ch = 0; ch < 2; ++ch) {
        #pragma unroll
        for (int nt = 0; nt < 4; ++nt) {
            int lc0 = (w * 4 + nt) * 16;
            int g = ch * 256 + lc0 + l15;
            bf16x8 bB[4];
            #pragma unroll
            for (int kt = 0; kt < 4; ++kt)
                bB[kt] = *(const bf16x8*)(wb + OFF_D1WINT + (size_t)g * 128 + kt * 32 + lq * 8);
            float bi = bin[g];
            #pragma unroll
            for (int m = 0; m < 2; ++m) {
                f32x4 acc = {0.f, 0.f, 0.f, 0.f};
                #pragma unroll
                for (int kt = 0; kt < 4; ++kt)
                    acc = __builtin_amdgcn_mfma_f32_16x16x32_bf16(aA[m][kt], bB[kt], acc, 0, 0, 0);
                #pragma unroll
                for (int r = 0; r < 4; ++r)
                    Hd[(m * 16 + lq * 4 + r) * 264 + lc0 + l15] = (short)f2bf(gelu_f(acc[r] + bi));
            }
        }
        __syncthreads();
        #pragma unroll
        for (int kt = 0; kt < 8; ++kt) {
            bf16x8 a0 = *(const bf16x8*)&Hd[l15 * 264 + kt * 32 + lq * 8];
            bf16x8 a1 = *(const bf16x8*)&Hd[(16 + l15) * 264 + kt * 32 + lq * 8];
            bf16x8 b0 = *(const bf16x8*)(wb + OFF_D1WOUTT + (size_t)col0 * 512 + ch * 256 + kt * 32 + lq * 8);
            bf16x8 b1 = *(const bf16x8*)(wb + OFF_D1WOUTT + (size_t)col1 * 512 + ch * 256 + kt * 32 + lq * 8);
            acc2[0][0] = __builtin_amdgcn_mfma_f32_16x16x32_bf16(a0, b0, acc2[0][0], 0, 0, 0);
            acc2[0][1] = __builtin_amdgcn_mfma_f32_16x16x32_bf16(a1, b0, acc2[0][1], 0, 0, 0);
            acc2[1][0] = __builtin_amdgcn_mfma_f32_16x16x32_bf16(a0, b1, acc2[1][0], 0, 0, 0);
            acc2[1][1] = __builtin_amdgcn_mfma_f32_16x16x32_bf16(a1, b1, acc2[1][1], 0, 0, 0);
        }
        __syncthreads();
    }
    #pragma unroll
    for (int ni = 0; ni < 2; ++ni) {
        int col = ni ? col1 : col0;
        float bo = bout[col];
        #pragma unroll
        for (int m = 0; m < 2; ++m)
            #pragma unroll
            for (int r = 0; r < 4; ++r) {
                int row = m * 16 + lq * 4 + r;
                Xf[row][col] += gelu_f(acc2[ni][m][r] + bo);
            }
    }
    __syncthreads();
    {
        int r = t >> 3, sub = t & 7;
        float s = 0.f, ss = 0.f;
        #pragma unroll
        for (int j = 0; j < 16; ++j) {
            float v = Xf[r][sub * 16 + j]; s += v; ss += v * v;
        }
        #pragma unroll
        for (int m = 1; m < 8; m <<= 1) { s += __shfl_xor(s, m, 8); ss += __shfl_xor(ss, m, 8); }
        if (sub == 0) {
            float mu = s * (1.f / 128.f);
            mu_[r] = mu;
            isd_[r] = 1.f / sqrtf(ss * (1.f / 128.f) - mu * mu + 1e-5f);
        }
    }
    __syncthreads();
    for (int i4 = t * 4; i4 < 4096; i4 += 1024) {
        int r = i4 >> 7, c = i4 & 127;
        float mv = maskV[bn * 32 + r];
        f32x4 xv = *(const f32x4*)&Xf[r][c];
        f32x4 o;
        #pragma unroll
        for (int j = 0; j < 4; ++j)
            o[j] = mv * (n1g[c + j] * (xv[j] - mu_[r]) * isd_[r] + n1b[c + j]);
        *(f32x4*)&ep[i4] = o;
    }
}

// ---------------- K3: batched xop = LN(hv2, op_g, op_beta) @ W1 + b1 (bf16) ---
__global__ __launch_bounds__(256) void k_xop(
    const float* __restrict__ hv2, const u16* __restrict__ wb,
    const float* __restrict__ b1, const float* __restrict__ opg,
    const float* __restrict__ opb, u16* __restrict__ xop)
{
    __shared__ __align__(16) float Xf[32][132];
    __shared__ __align__(16) short A1[32 * 136];
    __shared__ float mu_[32], isd_[32];
    const int bn = blockIdx.x, t = threadIdx.x;
    const int w = t >> 6, l = t & 63, l15 = l & 15, lq = l >> 4;
    const float* ep = hv2 + (size_t)bn * 4096;
    for (int i4 = t * 4; i4 < 4096; i4 += 1024) {
        f32x4 v = *(const f32x4*)&ep[i4];
        *(f32x4*)&Xf[i4 >> 7][i4 & 127] = v;
    }
    __syncthreads();
    {
        int r = t >> 3, sub = t & 7;
        float s = 0.f, ss = 0.f;
        #pragma unroll
        for (int j = 0; j < 16; ++j) {
            float v = Xf[r][sub * 16 + j]; s += v; ss += v * v;
        }
        #pragma unroll
        for (int m = 1; m < 8; m <<= 1) { s += __shfl_xor(s, m, 8); ss += __shfl_xor(ss, m, 8); }
        if (sub == 0) {
            float mu = s * (1.f / 128.f);
            mu_[r] = mu;
            isd_[r] = 1.f / sqrtf(ss * (1.f / 128.f) - mu * mu + 1e-5f);
        }
    }
    __syncthreads();
    for (int i4 = t * 4; i4 < 4096; i4 += 1024) {
        int r = i4 >> 7, c = i4 & 127;
        f32x4 xv = *(const f32x4*)&Xf[r][c];
        f32x4 y;
        #pragma unroll
        for (int j = 0; j < 4; ++j)
            y[j] = opg[c + j] * (xv[j] - mu_[r]) * isd_[r] + opb[c + j];
        *(s16x4*)&A1[r * 136 + c] = packbf4(y);
    }
    __syncthreads();
    #pragma unroll
    for (int i = 0; i < 4; ++i) {
        int id = w + 4 * i;
        int m0 = (id >> 3) << 4, n0 = (id & 7) << 4;
        f32x4 acc = {0.f, 0.f, 0.f, 0.f};
        #pragma unroll
        for (int kt = 0; kt < 4; ++kt) {
            bf16x8 a = *(const bf16x8*)&A1[(m0 + l15) * 136 + kt * 32 + lq * 8];
            bf16x8 bv = *(const bf16x8*)(wb + OFF_OPW1T + (size_t)(n0 + l15) * 128 + kt * 32 + lq * 8);
            acc = __builtin_amdgcn_mfma_f32_16x16x32_bf16(a, bv, acc, 0, 0, 0);
        }
        int col = n0 + l15;
        float bb = b1[col];
        #pragma unroll
        for (int r = 0; r < 4; ++r)
            xop[(size_t)(bn * 32 + m0 + lq * 4 + r) * 128 + col] = f2bf(acc[r] + bb);
    }
}

// ---------------- K4: fused edge pipeline ------------------------------------
// outer+residual -> (Q,K,V) proj -> logits -> softmax -> PV -> WO gemm -> LN3
// -> FFN -> LN4 -> store. Residuals live in registers (MFMA fragment layout).
__global__ __launch_bounds__(256, 3) void k_edge_fused(
    const u16* __restrict__ xop, const float* __restrict__ hE,
    const int* __restrict__ Eidx, const float* __restrict__ maskA,
    const u16* __restrict__ wb, const float* __restrict__ b2,
    const float* __restrict__ n3g, const float* __restrict__ n3b,
    const float* __restrict__ bin, const float* __restrict__ bout,
    const float* __restrict__ n4g, const float* __restrict__ n4b,
    float* __restrict__ outE)
{
    __shared__ __align__(16) char smem[48640];
    short* A1  = (short*)smem;                 // [32*136] X/O2/X2 bf16
    short* Qe  = (short*)(smem + 8704);        // [32*136]
    short* Ke  = (short*)(smem + 17408);       // [32*136]
    short* Hd  = Qe;                           // [32*264] overlays Qe+Ke
    short* Vp  = (short*)(smem + 26112);       // [4*32*40]
    short* Ls  = (short*)(smem + 36352);       // [4*32*40] logits->Pe
    float* ms  = (float*)(smem + 46592);       // [32]
    float* mu_ = (float*)(smem + 46720);       // [32]
    float* isd_= (float*)(smem + 46848);       // [32]
    float* pps = (float*)(smem + 46976);       // [4*32]
    float* ppss= (float*)(smem + 47488);       // [4*32]
    float* xcf = (float*)(smem + 48000);       // [128]
    int*   idxs= (int*)(smem + 48512);         // [32]

    const int bn = blockIdx.x, t = threadIdx.x;
    const int b = bn >> 11;
    const int w = t >> 6, l = t & 63, l15 = l & 15, lq = l >> 4;
    const int c0 = w * 16 + l15, c1 = c0 + 64;

    // phase 0: gather bases + masks + per-thread channel constants
    if (t < 128) xcf[t] = bf2f(xop[(size_t)bn * 128 + t]);
    if (t < 32) { idxs[t] = Eidx[(size_t)bn * 32 + t]; ms[t] = maskA[(size_t)bn * 32 + t]; }
    const float bb_0 = b2[c0], bb_1 = b2[c1];
    const float g3_0 = n3g[c0], g3_1 = n3g[c1], b3_0 = n3b[c0], b3_1 = n3b[c1];
    const float g4_0 = n4g[c0], g4_1 = n4g[c1], b4_0 = n4b[c0], b4_1 = n4b[c1];
    const float bo_0 = bout[c0], bo_1 = bout[c1];
    __syncthreads();

    // phase 1: A1 = bf16(x ⊙ x[nbr])
    for (int i4 = t * 4; i4 < 4096; i4 += 1024) {
        int k = i4 >> 7, h = i4 & 127;
        s16x4 nb = *(const s16x4*)&xop[((size_t)b * Nn + idxs[k]) * 128 + h];
        f32x4 prod;
        prod.x = xcf[h] * bf2f(nb.x);
        prod.y = xcf[h + 1] * bf2f(nb.y);
        prod.z = xcf[h + 2] * bf2f(nb.z);
        prod.w = xcf[h + 3] * bf2f(nb.w);
        *(s16x4*)&A1[k * 136 + h] = packbf4(prod);
    }
    __syncthreads();

    // phase 2a: xv = hE + outer@W2 + b2  (MFMA-fragment layout, regs)
    float xv[4][4];
    #pragma unroll
    for (int i = 0; i < 4; ++i) {
        int id = w + 4 * i;
        int m0 = (id >> 3) << 4, n0 = (id & 7) << 4;
        f32x4 acc = {0.f, 0.f, 0.f, 0.f};
        #pragma unroll
        for (int kt = 0; kt < 4; ++kt) {
            bf16x8 a = *(const bf16x8*)&A1[(m0 + l15) * 136 + kt * 32 + lq * 8];
            bf16x8 bv = *(const bf16x8*)(wb + OFF_OPW2T + (size_t)(n0 + l15) * 128 + kt * 32 + lq * 8);
            acc = __builtin_amdgcn_mfma_f32_16x16x32_bf16(a, bv, acc, 0, 0, 0);
        }
        int col = n0 + l15;
        float bb = (i & 1) ? bb_1 : bb_0;
        #pragma unroll
        for (int r = 0; r < 4; ++r) {
            int row = m0 + lq * 4 + r;
            xv[i][r] = acc[r] + bb + hE[(size_t)bn * 4096 + row * 128 + col];
        }
    }
    __syncthreads();
    // phase 2b: A1 = bf16(xv)
    #pragma unroll
    for (int i = 0; i < 4; ++i) {
        int m0 = (i >> 1) << 4, col = (i & 1) ? c1 : c0;
        #pragma unroll
        for (int r = 0; r < 4; ++r)
            A1[(m0 + lq * 4 + r) * 136 + col] = (short)f2bf(xv[i][r]);
    }
    __syncthreads();

    // phase 3: projections Q = X@WO (faithful), K = X@WK, V = X@WV
    #pragma unroll
    for (int i = 0; i < 12; ++i) {
        int id = w + 4 * i;
        int mat = id >> 4, rem = id & 15;
        int m0 = (rem >> 3) << 4, n0 = (rem & 7) << 4;
        const u16* Bp = wb + ((mat == 0) ? OFF_EAWOT : (mat == 1) ? OFF_EAWKT : OFF_EAWVT);
        f32x4 acc = {0.f, 0.f, 0.f, 0.f};
        #pragma unroll
        for (int kt = 0; kt < 4; ++kt) {
            bf16x8 a = *(const bf16x8*)&A1[(m0 + l15) * 136 + kt * 32 + lq * 8];
            bf16x8 bv = *(const bf16x8*)(Bp + (size_t)(n0 + l15) * 128 + kt * 32 + lq * 8);
            acc = __builtin_amdgcn_mfma_f32_16x16x32_bf16(a, bv, acc, 0, 0, 0);
        }
        int col = n0 + l15;
        #pragma unroll
        for (int r = 0; r < 4; ++r) {
            int row = m0 + lq * 4 + r;
            u16 hv = f2bf(acc[r]);
            if (mat == 0) Qe[row * 136 + col] = (short)hv;
            else if (mat == 1) Ke[row * 136 + col] = (short)hv;
            else Vp[((row >> 3) * 32 + (col & 31)) * 40 + (((row & 7) << 2) | (col >> 5))] = (short)hv;
        }
    }
    __syncthreads();

    // phase 4: logits via MFMA, written DIRECTLY in swapped order (bf16, scaled)
    #pragma unroll
    for (int i = 0; i < 4; ++i) {
        int id = w + 4 * i;                 // 0..15
        int h = id >> 2, rem = id & 3;
        int q0 = (rem >> 1) << 4, k0 = (rem & 1) << 4;
        int q = q0 + l15, k = k0 + l15;
        bf16x8 a = *(const bf16x8*)&Qe[(((h << 3) | (q >> 2)) * 136) + (((q & 3) << 5) + lq * 8)];
        bf16x8 bv = *(const bf16x8*)&Ke[(((h << 3) | (k >> 2)) * 136) + (((k & 3) << 5) + lq * 8)];
        f32x4 acc = {0.f, 0.f, 0.f, 0.f};
        acc = __builtin_amdgcn_mfma_f32_16x16x32_bf16(a, bv, acc, 0, 0, 0);
        int aa = l15 & 3;
        int kq = (k0 >> 2) + (l15 >> 2);
        int cc = (h << 3) + (q0 >> 2) + lq;
        #pragma unroll
        for (int r = 0; r < 4; ++r) {
            int q2 = (r << 3) | kq;
            Ls[(aa * 32 + q2) * 40 + cc] = (short)f2bf(acc[r] * 0.17677669529663687f);
        }
    }
    __syncthreads();

    // phase 5: masked softmax over c, in place (rows are linear now)
    if (t < 128) {
        int a = t >> 5, q2 = t & 31;
        float mq = ms[q2];
        float lv[Kk];
        int base = (a * 32 + q2) * 40;
        #pragma unroll
        for (int j = 0; j < 8; ++j) {
            s16x4 v = *(const s16x4*)&Ls[base + j * 4];
            lv[j * 4] = bf2f(v.x); lv[j * 4 + 1] = bf2f(v.y);
            lv[j * 4 + 2] = bf2f(v.z); lv[j * 4 + 3] = bf2f(v.w);
        }
        float mx = NEGF;
        #pragma unroll
        for (int c = 0; c < Kk; ++c) {
            lv[c] = (mq * ms[c] > 0.f) ? lv[c] : NEGF;
            mx = fmaxf(mx, lv[c]);
        }
        float s = 0.f;
        #pragma unroll
        for (int c = 0; c < Kk; ++c) { lv[c] = __expf(lv[c] - mx); s += lv[c]; }
        float inv = 1.f / s;
        #pragma unroll
        for (int j = 0; j < 8; ++j) {
            f32x4 pv;
            pv.x = lv[j * 4] * inv; pv.y = lv[j * 4 + 1] * inv;
            pv.z = lv[j * 4 + 2] * inv; pv.w = lv[j * 4 + 3] * inv;
            *(s16x4*)&Ls[base + j * 4] = packbf4(pv);
        }
    }
    __syncthreads();

    // phase 6: PV via MFMA -> O2 bf16 into A1
    #pragma unroll
    for (int i = 0; i < 4; ++i) {
        int id = w + 4 * i;
        int a = id >> 2, rem = id & 3;
        int q0 = (rem >> 1) << 4, d0 = (rem & 1) << 4;
        bf16x8 pa = *(const bf16x8*)&Ls[((a * 32 + q0 + l15) * 40) + lq * 8];
        bf16x8 vb = *(const bf16x8*)&Vp[((a * 32 + d0 + l15) * 40) + lq * 8];
        f32x4 acc = {0.f, 0.f, 0.f, 0.f};
        acc = __builtin_amdgcn_mfma_f32_16x16x32_bf16(pa, vb, acc, 0, 0, 0);
        #pragma unroll
        for (int r = 0; r < 4; ++r)
            A1[(q0 + lq * 4 + r) * 136 + (a << 5) + d0 + l15] = (short)f2bf(acc[r]);
    }
    __syncthreads();

    // phase 7: xv += gelu(O2 @ WO)   (same fragment layout as phase 2)
    #pragma unroll
    for (int i = 0; i < 4; ++i) {
        int id = w + 4 * i;
        int m0 = (id >> 3) << 4, n0 = (id & 7) << 4;
        f32x4 acc = {0.f, 0.f, 0.f, 0.f};
        #pragma unroll
        for (int kt = 0; kt < 4; ++kt) {
            bf16x8 a = *(const bf16x8*)&A1[(m0 + l15) * 136 + kt * 32 + lq * 8];
            bf16x8 bv = *(const bf16x8*)(wb + OFF_EAWOT + (size_t)(n0 + l15) * 128 + kt * 32 + lq * 8);
            acc = __builtin_amdgcn_mfma_f32_16x16x32_bf16(a, bv, acc, 0, 0, 0);
        }
        #pragma unroll
        for (int r = 0; r < 4; ++r)
            xv[i][r] += gelu_f(acc[r]);
    }
    __syncthreads();

    // phase 8: LN3 stats from regs (shuffle over l15 group + cross-wave LDS)
    {
        float s8[8], ss8[8];
        #pragma unroll
        for (int j = 0; j < 8; ++j) { s8[j] = 0.f; ss8[j] = 0.f; }
        #pragma unroll
        for (int i = 0; i < 4; ++i)
            #pragma unroll
            for (int r = 0; r < 4; ++r) {
                int j = (i >> 1) * 4 + r;
                float v = xv[i][r];
                s8[j] += v; ss8[j] += v * v;
            }
        #pragma unroll
        for (int m = 1; m < 16; m <<= 1)
            #pragma unroll
            for (int j = 0; j < 8; ++j) {
                s8[j] += __shfl_xor(s8[j], m);
                ss8[j] += __shfl_xor(ss8[j], m);
            }
        if (l15 == 0) {
            #pragma unroll
            for (int j = 0; j < 8; ++j) {
                int row = (j >> 2) * 16 + lq * 4 + (j & 3);
                pps[w * 32 + row] = s8[j];
                ppss[w * 32 + row] = ss8[j];
            }
        }
    }
    __syncthreads();
    if (t < 32) {
        float s = pps[t] + pps[32 + t] + pps[64 + t] + pps[96 + t];
        float ss = ppss[t] + ppss[32 + t] + ppss[64 + t] + ppss[96 + t];
        float mu = s * (1.f / 128.f);
        mu_[t] = mu;
        isd_[t] = 1.f / sqrtf(ss * (1.f / 128.f) - mu * mu + 1e-5f);
    }
    __syncthreads();

    // phase 9: x2 = LN3(xv) -> regs (residual) + A1 bf16 (FFN input)
    #pragma unroll
    for (int i = 0; i < 4; ++i) {
        int m0 = (i >> 1) << 4, col = (i & 1) ? c1 : c0;
        float g = (i & 1) ? g3_1 : g3_0, bB = (i & 1) ? b3_1 : b3_0;
        #pragma unroll
        for (int r = 0; r < 4; ++r) {
            int row = m0 + lq * 4 + r;
            float v = g * (xv[i][r] - mu_[row]) * isd_[row] + bB;
            xv[i][r] = v;
            A1[row * 136 + col] = (short)f2bf(v);
        }
    }
    __syncthreads();

    // phase 10: FFN (Hd overlays Qe/Ke)
    bf16x8 aA[2][4];
    #pragma unroll
    for (int m = 0; m < 2; ++m)
        #pragma unroll
        for (int kt = 0; kt < 4; ++kt)
            aA[m][kt] = *(const bf16x8*)&A1[(m * 16 + l15) * 136 + kt * 32 + lq * 8];

    f32x4 acc2[2][2];
    #pragma unroll
    for (int i = 0; i < 2; ++i)
        #pragma unroll
        for (int m = 0; m < 2; ++m) acc2[i][m] = (f32x4){0.f, 0.f, 0.f, 0.f};

    for (int ch = 0; ch < 2; ++ch) {
        #pragma unroll
        for (int nt = 0; nt < 4; ++nt) {
            int lc0 = (w * 4 + nt) * 16;
            int g = ch * 256 + lc0 + l15;
            bf16x8 bB[4];
            #pragma unroll
            for (int kt = 0; kt < 4; ++kt)
                bB[kt] = *(const bf16x8*)(wb + OFF_D2WINT + (size_t)g * 128 + kt * 32 + lq * 8);
            float bi = bin[g];
            #pragma unroll
            for (int m = 0; m < 2; ++m) {
                f32x4 acc = {0.f, 0.f, 0.f, 0.f};
                #pragma unroll
                for (int kt = 0; kt < 4; ++kt)
                    acc = __builtin_amdgcn_mfma_f32_16x16x32_bf16(aA[m][kt], bB[kt], acc, 0, 0, 0);
                #pragma unroll
                for (int r = 0; r < 4; ++r)
                    Hd[(m * 16 + lq * 4 + r) * 264 + lc0 + l15] = (short)f2bf(gelu_f(acc[r] + bi));
            }
        }
        __syncthreads();
        #pragma unroll
        for (int kt = 0; kt < 8; ++kt) {
            bf16x8 a0 = *(const bf16x8*)&Hd[l15 * 264 + kt * 32 + lq * 8];
            bf16x8 a1 = *(const bf16x8*)&Hd[(16 + l15) * 264 + kt * 32 + lq * 8];
            bf16x8 b0 = *(const bf16x8*)(wb + OFF_D2WOUTT + (size_t)c0 * 512 + ch * 256 + kt * 32 + lq * 8);
            bf16x8 b1 = *(const bf16x8*)(wb + OFF_D2WOUTT + (size_t)c1 * 512 + ch * 256 + kt * 32 + lq * 8);
            acc2[0][0] = __builtin_amdgcn_mfma_f32_16x16x32_bf16(a0, b0, acc2[0][0], 0, 0, 0);
            acc2[0][1] = __builtin_amdgcn_mfma_f32_16x16x32_bf16(a1, b0, acc2[0][1], 0, 0, 0);
            acc2[1][0] = __builtin_amdgcn_mfma_f32_16x16x32_bf16(a0, b1, acc2[1][0], 0, 0, 0);
            acc2[1][1] = __builtin_amdgcn_mfma_f32_16x16x32_bf16(a1, b1, acc2[1][1], 0, 0, 0);
        }
        __syncthreads();
    }
    // phase 11: xv += gelu(acc2 + bout)  (i = m*2 + ni)
    #pragma unroll
    for (int ni = 0; ni < 2; ++ni) {
        float bo = ni ? bo_1 : bo_0;
        #pragma unroll
        for (int m = 0; m < 2; ++m) {
            int i = m * 2 + ni;
            #pragma unroll
            for (int r = 0; r < 4; ++r)
                xv[i][r] += gelu_f(acc2[ni][m][r] + bo);
        }
    }

    // phase 12: LN4 stats + store
    {
        float s8[8], ss8[8];
        #pragma unroll
        for (int j = 0; j < 8; ++j) { s8[j] = 0.f; ss8[j] = 0.f; }
        #pragma unroll
        for (int i = 0; i < 4; ++i)
            #pragma unroll
            for (int r = 0; r < 4; ++r) {
                int j = (i >> 1) * 4 + r;
                float v = xv[i][r];
                s8[j] += v; ss8[j] += v * v;
            }
        #pragma unroll
        for (int m = 1; m < 16; m <<= 1)
            #pragma unroll
            for (int j = 0; j < 8; ++j) {
                s8[j] += __shfl_xor(s8[j], m);
                ss8[j] += __shfl_xor(ss8[j], m);
            }
        if (l15 == 0) {
            #pragma unroll
            for (int j = 0; j < 8; ++j) {
                int row = (j >> 2) * 16 + lq * 4 + (j & 3);
                pps[w * 32 + row] = s8[j];
                ppss[w * 32 + row] = ss8[j];
            }
        }
    }
    __syncthreads();
    if (t < 32) {
        float s = pps[t] + pps[32 + t] + pps[64 + t] + pps[96 + t];
        float ss = ppss[t] + ppss[32 + t] + ppss[64 + t] + ppss[96 + t];
        float mu = s * (1.f / 128.f);
        mu_[t] = mu;
        isd_[t] = 1.f / sqrtf(ss * (1.f / 128.f) - mu * mu + 1e-5f);
    }
    __syncthreads();
    #pragma unroll
    for (int i = 0; i < 4; ++i) {
        int m0 = (i >> 1) << 4, col = (i & 1) ? c1 : c0;
        float g = (i & 1) ? g4_1 : g4_0, bB = (i & 1) ? b4_1 : b4_0;
        #pragma unroll
        for (int r = 0; r < 4; ++r) {
            int row = m0 + lq * 4 + r;
            outE[(size_t)bn * 4096 + row * 128 + col] =
                g * (xv[i][r] - mu_[row]) * isd_[row] + bB;
        }
    }
}

extern "C" void kernel_launch(void* const* d_in, const int* in_sizes, int n_in,
                              void* d_out, int out_size, void* d_ws, size_t ws_size,
                              hipStream_t stream) {
    const float* hV     = (const float*)d_in[0];
    const float* hE     = (const float*)d_in[1];
    const float* hEV    = (const float*)d_in[2];
    const float* maskV  = (const float*)d_in[3];
    const float* maskA  = (const float*)d_in[4];
    const float* naWQ   = (const float*)d_in[5];
    const float* naWK   = (const float*)d_in[6];
    const float* naWV   = (const float*)d_in[7];
    const float* naWO   = (const float*)d_in[8];
    const float* eaWK   = (const float*)d_in[9];
    const float* eaWV   = (const float*)d_in[10];
    const float* eaWO   = (const float*)d_in[11];
    const float* d1Win  = (const float*)d_in[12];
    const float* d1bin  = (const float*)d_in[13];
    const float* d1Wout = (const float*)d_in[14];
    const float* d1bout = (const float*)d_in[15];
    const float* d2Win  = (const float*)d_in[16];
    const float* d2bin  = (const float*)d_in[17];
    const float* d2Wout = (const float*)d_in[18];
    const float* d2bout = (const float*)d_in[19];
    const float* opW1   = (const float*)d_in[20];
    const float* opb1   = (const float*)d_in[21];
    const float* opW2   = (const float*)d_in[22];
    const float* opb2   = (const float*)d_in[23];
    const float* opg    = (const float*)d_in[24];
    const float* opbeta = (const float*)d_in[25];
    const float* n1g    = (const float*)d_in[26];
    const float* n1b    = (const float*)d_in[27];
    const float* n3g    = (const float*)d_in[28];
    const float* n3b    = (const float*)d_in[29];
    const float* n4g    = (const float*)d_in[30];
    const float* n4b    = (const float*)d_in[31];
    const int*   Eidx   = (const int*)d_in[32];

    float* outV = (float*)d_out;
    float* outE = outV + (size_t)Bb * Nn * Hh;
    u16* xop = (u16*)d_ws;                        // [B*N*H] bf16 (2 MB)
    u16* wb  = (u16*)d_ws + (size_t)Bb * Nn * Hh; // bf16 weights (~880 KB)
    // scratch inside outE region (consumed before k_edge_fused writes it):
    u16* Qall = (u16*)(outE + (size_t)30 * 1048576);  // 2 MB @ +120MB
    u16* outr = (u16*)(outE + (size_t)31 * 1048576);  // 2 MB @ +124MB

    dim3 blk(256);
    k_prep<<<dim3(WB_TOTAL / 256), blk, 0, stream>>>(naWK, naWV, eaWK, eaWV, eaWO,
                                                     d2Win, d2Wout, opW2,
                                                     d1Win, d1Wout, opW1,
                                                     naWQ, naWO, wb);
    dim3 gridTok(Bb * Nn / 32);
    dim3 grid(Bb * Nn);
    k_qproj<<<gridTok, blk, 0, stream>>>(hV, wb, Qall);
    k_node_core<<<grid, blk, 0, stream>>>(hEV, maskA, Qall, wb, outr);
    k_node_out<<<gridTok, blk, 0, stream>>>(outr, hV, wb, n1g, n1b, outV);
    k_node_ffn<<<gridTok, blk, 0, stream>>>(outV, maskV, wb, d1bin,
                                            d1bout, n1g, n1b);
    k_xop<<<gridTok, blk, 0, stream>>>(outV, wb, opb1, opg, opbeta, xop);
    k_edge_fused<<<grid, blk, 0, stream>>>(xop, hE, Eidx, maskA, wb, opb2,
                                           n3g, n3b, d2bin, d2bout, n4g, n4b,
                                           outE);
}

// Round 6
// 854.138 us; speedup vs baseline: 6.7851x; 1.0004x over previous
//
#include <hip/hip_runtime.h>
#include <hip/hip_bf16.h>
#include <math.h>

#define Bb 4
#define Nn 2048
#define Kk 32
#define Hh 128
#define NIi 256
#define NH_ 4
#define Dd 32
#define DFFh 512

#define NEGF -3.402823466e38f

typedef unsigned short u16;
typedef __attribute__((ext_vector_type(8))) short bf16x8;
typedef __attribute__((ext_vector_type(4))) short s16x4;
typedef __attribute__((ext_vector_type(4))) float f32x4;

// bf16 weight buffer offsets (elements); base = d_ws + 2MB
#define OFF_NAWKT   0        // [128][256]
#define OFF_NAWVT   32768    // [128][256]
#define OFF_EAWKT   65536    // [128][128]
#define OFF_EAWVT   81920
#define OFF_EAWOT   98304
#define OFF_D2WINT  114688   // [512][128]
#define OFF_D2WOUTT 180224   // [128][512]
#define OFF_OPW2T   245760   // [128][128]
#define OFF_D1WINT  262144   // [512][128]
#define OFF_D1WOUTT 327680   // [128][512]
#define OFF_OPW1T   393216   // [128][128]
#define OFF_NAWQT   409600   // [128][128]
#define OFF_NAWOT   425984   // [128][128]
#define WB_TOTAL    442368

// Fast exact-gelu: A&S 7.1.26 erf (|eps|<=1.5e-7), branchless.
__device__ __forceinline__ float gelu_f(float x) {
    float z = x * 0.7071067811865476f;
    float a = fabsf(z);
    float d = fmaf(0.3275911f, a, 1.0f);
    float t = __fdividef(1.0f, d);
    float p = fmaf(fmaf(fmaf(fmaf(1.061405429f, t, -1.453152027f), t,
                             1.421413741f), t, -0.284496736f), t, 0.254829592f);
    float e = __expf(-a * a);
    float erfa = fmaf(-p * t, e, 1.0f);
    float er = copysignf(erfa, z);
    return 0.5f * x * (1.0f + er);
}

__device__ __forceinline__ u16 f2bf(float f) {
    union { __hip_bfloat16 h; u16 u; } v;
    v.h = __float2bfloat16(f);
    return v.u;
}

__device__ __forceinline__ float bf2f(u16 u) {
    union { unsigned int u; float f; } v; v.u = ((unsigned int)u) << 16;
    return v.f;
}

__device__ __forceinline__ s16x4 packbf4(f32x4 v) {
    s16x4 r;
    r.x = (short)f2bf(v.x); r.y = (short)f2bf(v.y);
    r.z = (short)f2bf(v.z); r.w = (short)f2bf(v.w);
    return r;
}

// ---------------- K0: convert + transpose weights to bf16 in ws ---------------
__global__ __launch_bounds__(256) void k_prep(
    const float* __restrict__ naWK, const float* __restrict__ naWV,
    const float* __restrict__ eaWK, const float* __restrict__ eaWV,
    const float* __restrict__ eaWO, const float* __restrict__ d2Win,
    const float* __restrict__ d2Wout, const float* __restrict__ opW2,
    const float* __restrict__ d1Win, const float* __restrict__ d1Wout,
    const float* __restrict__ opW1, const float* __restrict__ naWQ,
    const float* __restrict__ naWO, u16* __restrict__ wb)
{
    int i = blockIdx.x * 256 + threadIdx.x;
    const float* src; int R, C, off;
    if (i < 32768)       { src = naWK;   R = 256; C = 128; off = OFF_NAWKT; }
    else if (i < 65536)  { src = naWV;   R = 256; C = 128; off = OFF_NAWVT; }
    else if (i < 81920)  { src = eaWK;   R = 128; C = 128; off = OFF_EAWKT; }
    else if (i < 98304)  { src = eaWV;   R = 128; C = 128; off = OFF_EAWVT; }
    else if (i < 114688) { src = eaWO;   R = 128; C = 128; off = OFF_EAWOT; }
    else if (i < 180224) { src = d2Win;  R = 128; C = 512; off = OFF_D2WINT; }
    else if (i < 245760) { src = d2Wout; R = 512; C = 128; off = OFF_D2WOUTT; }
    else if (i < 262144) { src = opW2;   R = 128; C = 128; off = OFF_OPW2T; }
    else if (i < 327680) { src = d1Win;  R = 128; C = 512; off = OFF_D1WINT; }
    else if (i < 393216) { src = d1Wout; R = 512; C = 128; off = OFF_D1WOUTT; }
    else if (i < 409600) { src = opW1;   R = 128; C = 128; off = OFF_OPW1T; }
    else if (i < 425984) { src = naWQ;   R = 128; C = 128; off = OFF_NAWQT; }
    else                 { src = naWO;   R = 128; C = 128; off = OFF_NAWOT; }
    int j = i - off;
    int c = j / R, r = j - c * R;       // dest W^T[C][R]
    wb[i] = f2bf(src[r * C + c]);
}

// ---------------- K1a: batched Qall = hV @ WQ (bf16) --------------------------
__global__ __launch_bounds__(256) void k_qproj(
    const float* __restrict__ hV, const u16* __restrict__ wb,
    u16* __restrict__ Qall)
{
    __shared__ __align__(16) short A1[32 * 136];
    const int bn = blockIdx.x, t = threadIdx.x;
    const int w = t >> 6, l = t & 63, l15 = l & 15, lq = l >> 4;
    const float* xp = hV + (size_t)bn * 4096;
    for (int i4 = t * 4; i4 < 4096; i4 += 1024)
        *(s16x4*)&A1[(i4 >> 7) * 136 + (i4 & 127)] = packbf4(*(const f32x4*)&xp[i4]);
    __syncthreads();
    #pragma unroll
    for (int i = 0; i < 4; ++i) {
        int id = w + 4 * i;
        int m0 = (id >> 3) << 4, n0 = (id & 7) << 4;
        f32x4 acc = {0.f, 0.f, 0.f, 0.f};
        #pragma unroll
        for (int kt = 0; kt < 4; ++kt) {
            bf16x8 a = *(const bf16x8*)&A1[(m0 + l15) * 136 + kt * 32 + lq * 8];
            bf16x8 bv = *(const bf16x8*)(wb + OFF_NAWQT + (size_t)(n0 + l15) * 128 + kt * 32 + lq * 8);
            acc = __builtin_amdgcn_mfma_f32_16x16x32_bf16(a, bv, acc, 0, 0, 0);
        }
        int col = n0 + l15;
        #pragma unroll
        for (int r = 0; r < 4; ++r)
            Qall[(size_t)(bn * 32 + m0 + lq * 4 + r) * 128 + col] = f2bf(acc[r]);
    }
}

// ---------------- K1b: per-token attention core -> outr (bf16) ----------------
__global__ __launch_bounds__(256, 4) void k_node_core(
    const float* __restrict__ hEV, const float* __restrict__ maskA,
    const u16* __restrict__ Qall, const u16* __restrict__ wb,
    u16* __restrict__ outr)
{
    __shared__ __align__(16) short EVb[32 * 264];   // 16.9 KB
    __shared__ __align__(16) short KtT[128 * 34];   // K^T [h][k], 8.7 KB
    __shared__ __align__(16) short VtT[128 * 34];   // V^T [h][k], 8.7 KB
    __shared__ float Qs[128];
    __shared__ float att[NH_][Kk];

    const int bn = blockIdx.x, t = threadIdx.x;
    const int w = t >> 6, l = t & 63, l15 = l & 15, lq = l >> 4;
    const float* evp = hEV + (size_t)bn * 8192;
    for (int i8 = t * 8; i8 < 8192; i8 += 2048) {
        f32x4 v0 = *(const f32x4*)&evp[i8];
        f32x4 v1 = *(const f32x4*)&evp[i8 + 4];
        int r = i8 >> 8, c = i8 & 255;
        *(s16x4*)&EVb[r * 264 + c] = packbf4(v0);
        *(s16x4*)&EVb[r * 264 + c + 4] = packbf4(v1);
    }
    if (t < 128) Qs[t] = bf2f(Qall[(size_t)bn * 128 + t]);
    __syncthreads();

    // K = EV @ WK, V = EV @ WV via MFMA; store transposed bf16
    #pragma unroll
    for (int i = 0; i < 8; ++i) {
        int id = w + 4 * i;
        int mat = id >> 4, rem = id & 15;
        int m0 = (rem >> 3) << 4, n0 = (rem & 7) << 4;
        const u16* Bp = wb + (mat ? OFF_NAWVT : OFF_NAWKT);
        f32x4 acc = {0.f, 0.f, 0.f, 0.f};
        #pragma unroll
        for (int kt = 0; kt < 8; ++kt) {
            bf16x8 a = *(const bf16x8*)&EVb[(m0 + l15) * 264 + kt * 32 + lq * 8];
            bf16x8 b = *(const bf16x8*)(Bp + (size_t)(n0 + l15) * 256 + kt * 32 + lq * 8);
            acc = __builtin_amdgcn_mfma_f32_16x16x32_bf16(a, b, acc, 0, 0, 0);
        }
        int col = n0 + l15;
        short* dst = mat ? VtT : KtT;
        #pragma unroll
        for (int r = 0; r < 4; ++r)
            dst[col * 34 + m0 + lq * 4 + r] = (short)f2bf(acc[r]);
    }
    __syncthreads();

    // logits + wave-parallel masked softmax (nh = t>>5, k = t&31)
    if (t < 128) {
        int nh = t >> 5, k = t & 31;
        float a = 0.f;
        #pragma unroll
        for (int d = 0; d < 32; ++d)
            a += Qs[nh * 32 + d] * bf2f(KtT[(nh * 32 + d) * 34 + k]);
        float mk = maskA[(size_t)bn * 32 + k];
        float lg = (mk > 0.f) ? a * 0.17677669529663687f : NEGF;
        float mx = lg;
        #pragma unroll
        for (int s = 16; s; s >>= 1) mx = fmaxf(mx, __shfl_xor(mx, s, 32));
        float e = __expf(lg - mx);
        float sum = e;
        #pragma unroll
        for (int s = 16; s; s >>= 1) sum += __shfl_xor(sum, s, 32);
        att[nh][k] = mk * e / sum;
    }
    __syncthreads();
    // PV (nh = t>>5, d = t&31)
    if (t < 128) {
        int nh = t >> 5, d = t & 31;
        float a = 0.f;
        #pragma unroll
        for (int k = 0; k < 32; ++k)
            a += att[nh][k] * bf2f(VtT[(nh * 32 + d) * 34 + k]);
        outr[(size_t)bn * 128 + t] = f2bf(a);
    }
}

// ---------------- K1c: batched LN(hV + gelu(outr @ WO)) -> outV ---------------
__global__ __launch_bounds__(256) void k_node_out(
    const u16* __restrict__ outr, const float* __restrict__ hV,
    const u16* __restrict__ wb,
    const float* __restrict__ n1g, const float* __restrict__ n1b,
    float* __restrict__ outV)
{
    __shared__ __align__(16) float Xf[32][132];
    __shared__ __align__(16) short A1[32 * 136];
    __shared__ float mu_[32], isd_[32];
    const int bn = blockIdx.x, t = threadIdx.x;
    const int w = t >> 6, l = t & 63, l15 = l & 15, lq = l >> 4;
    const float* xp = hV + (size_t)bn * 4096;
    const u16* op = outr + (size_t)bn * 4096;
    for (int i4 = t * 4; i4 < 4096; i4 += 1024) {
        int r = i4 >> 7, c = i4 & 127;
        *(f32x4*)&Xf[r][c] = *(const f32x4*)&xp[i4];
        *(s16x4*)&A1[r * 136 + c] = *(const s16x4*)&op[i4];
    }
    __syncthreads();
    #pragma unroll
    for (int i = 0; i < 4; ++i) {
        int id = w + 4 * i;
        int m0 = (id >> 3) << 4, n0 = (id & 7) << 4;
        f32x4 acc = {0.f, 0.f, 0.f, 0.f};
        #pragma unroll
        for (int kt = 0; kt < 4; ++kt) {
            bf16x8 a = *(const bf16x8*)&A1[(m0 + l15) * 136 + kt * 32 + lq * 8];
            bf16x8 bv = *(const bf16x8*)(wb + OFF_NAWOT + (size_t)(n0 + l15) * 128 + kt * 32 + lq * 8);
            acc = __builtin_amdgcn_mfma_f32_16x16x32_bf16(a, bv, acc, 0, 0, 0);
        }
        int col = n0 + l15;
        #pragma unroll
        for (int r = 0; r < 4; ++r) {
            int row = m0 + lq * 4 + r;
            Xf[row][col] += gelu_f(acc[r]);
        }
    }
    __syncthreads();
    {
        int r = t >> 3, sub = t & 7;
        float s = 0.f, ss = 0.f;
        #pragma unroll
        for (int j = 0; j < 16; ++j) {
            float v = Xf[r][sub * 16 + j]; s += v; ss += v * v;
        }
        #pragma unroll
        for (int m = 1; m < 8; m <<= 1) { s += __shfl_xor(s, m, 8); ss += __shfl_xor(ss, m, 8); }
        if (sub == 0) {
            float mu = s * (1.f / 128.f);
            mu_[r] = mu;
            isd_[r] = 1.f / sqrtf(ss * (1.f / 128.f) - mu * mu + 1e-5f);
        }
    }
    __syncthreads();
    float* ov = outV + (size_t)bn * 4096;
    for (int i4 = t * 4; i4 < 4096; i4 += 1024) {
        int r = i4 >> 7, c = i4 & 127;
        f32x4 xv = *(const f32x4*)&Xf[r][c];
        f32x4 o;
        #pragma unroll
        for (int j = 0; j < 4; ++j)
            o[j] = n1g[c + j] * (xv[j] - mu_[r]) * isd_[r] + n1b[c + j];
        *(f32x4*)&ov[i4] = o;
    }
}

// ---------------- K2: batched node FFN (M=32 tokens), MFMA, in-place on hv ----
__global__ __launch_bounds__(256, 3) void k_node_ffn(
    float* __restrict__ hv, const float* __restrict__ maskV,
    const u16* __restrict__ wb, const float* __restrict__ bin,
    const float* __restrict__ bout,
    const float* __restrict__ n1g, const float* __restrict__ n1b)
{
    __shared__ __align__(16) float Xf[32][132];
    __shared__ __align__(16) short A1[32 * 136];
    __shared__ __align__(16) short Hd[32 * 264];
    __shared__ float mu_[32], isd_[32];
    const int bn = blockIdx.x, t = threadIdx.x;
    const int w = t >> 6, l = t & 63, l15 = l & 15, lq = l >> 4;
    float* ep = hv + (size_t)bn * 4096;
    for (int i4 = t * 4; i4 < 4096; i4 += 1024) {
        f32x4 v = *(const f32x4*)&ep[i4];
        int r = i4 >> 7, c = i4 & 127;
        *(f32x4*)&Xf[r][c] = v;
        *(s16x4*)&A1[r * 136 + c] = packbf4(v);
    }
    __syncthreads();

    bf16x8 aA[2][4];
    #pragma unroll
    for (int m = 0; m < 2; ++m)
        #pragma unroll
        for (int kt = 0; kt < 4; ++kt)
            aA[m][kt] = *(const bf16x8*)&A1[(m * 16 + l15) * 136 + kt * 32 + lq * 8];

    const int col0 = w * 16 + l15, col1 = (w + 4) * 16 + l15;
    f32x4 acc2[2][2];
    #pragma unroll
    for (int i = 0; i < 2; ++i)
        #pragma unroll
        for (int m = 0; m < 2; ++m) acc2[i][m] = (f32x4){0.f, 0.f, 0.f, 0.f};

    for (int ch = 0; ch < 2; ++ch) {
        #pragma unroll
        for (int nt = 0; nt < 4; ++nt) {
            int lc0 = (w * 4 + nt) * 16;
            int g = ch * 256 + lc0 + l15;
            bf16x8 bB[4];
            #pragma unroll
            for (int kt = 0; kt < 4; ++kt)
                bB[kt] = *(const bf16x8*)(wb + OFF_D1WINT + (size_t)g * 128 + kt * 32 + lq * 8);
            float bi = bin[g];
            #pragma unroll
            for (int m = 0; m < 2; ++m) {
                f32x4 acc = {0.f, 0.f, 0.f, 0.f};
                #pragma unroll
                for (int kt = 0; kt < 4; ++kt)
                    acc = __builtin_amdgcn_mfma_f32_16x16x32_bf16(aA[m][kt], bB[kt], acc, 0, 0, 0);
                #pragma unroll
                for (int r = 0; r < 4; ++r)
                    Hd[(m * 16 + lq * 4 + r) * 264 + lc0 + l15] = (short)f2bf(gelu_f(acc[r] + bi));
            }
        }
        __syncthreads();
        #pragma unroll
        for (int kt = 0; kt < 8; ++kt) {
            bf16x8 a0 = *(const bf16x8*)&Hd[l15 * 264 + kt * 32 + lq * 8];
            bf16x8 a1 = *(const bf16x8*)&Hd[(16 + l15) * 264 + kt * 32 + lq * 8];
            bf16x8 b0 = *(const bf16x8*)(wb + OFF_D1WOUTT + (size_t)col0 * 512 + ch * 256 + kt * 32 + lq * 8);
            bf16x8 b1 = *(const bf16x8*)(wb + OFF_D1WOUTT + (size_t)col1 * 512 + ch * 256 + kt * 32 + lq * 8);
            acc2[0][0] = __builtin_amdgcn_mfma_f32_16x16x32_bf16(a0, b0, acc2[0][0], 0, 0, 0);
            acc2[0][1] = __builtin_amdgcn_mfma_f32_16x16x32_bf16(a1, b0, acc2[0][1], 0, 0, 0);
            acc2[1][0] = __builtin_amdgcn_mfma_f32_16x16x32_bf16(a0, b1, acc2[1][0], 0, 0, 0);
            acc2[1][1] = __builtin_amdgcn_mfma_f32_16x16x32_bf16(a1, b1, acc2[1][1], 0, 0, 0);
        }
        __syncthreads();
    }
    #pragma unroll
    for (int ni = 0; ni < 2; ++ni) {
        int col = ni ? col1 : col0;
        float bo = bout[col];
        #pragma unroll
        for (int m = 0; m < 2; ++m)
            #pragma unroll
            for (int r = 0; r < 4; ++r) {
                int row = m * 16 + lq * 4 + r;
                Xf[row][col] += gelu_f(acc2[ni][m][r] + bo);
            }
    }
    __syncthreads();
    {
        int r = t >> 3, sub = t & 7;
        float s = 0.f, ss = 0.f;
        #pragma unroll
        for (int j = 0; j < 16; ++j) {
            float v = Xf[r][sub * 16 + j]; s += v; ss += v * v;
        }
        #pragma unroll
        for (int m = 1; m < 8; m <<= 1) { s += __shfl_xor(s, m, 8); ss += __shfl_xor(ss, m, 8); }
        if (sub == 0) {
            float mu = s * (1.f / 128.f);
            mu_[r] = mu;
            isd_[r] = 1.f / sqrtf(ss * (1.f / 128.f) - mu * mu + 1e-5f);
        }
    }
    __syncthreads();
    for (int i4 = t * 4; i4 < 4096; i4 += 1024) {
        int r = i4 >> 7, c = i4 & 127;
        float mv = maskV[bn * 32 + r];
        f32x4 xv = *(const f32x4*)&Xf[r][c];
        f32x4 o;
        #pragma unroll
        for (int j = 0; j < 4; ++j)
            o[j] = mv * (n1g[c + j] * (xv[j] - mu_[r]) * isd_[r] + n1b[c + j]);
        *(f32x4*)&ep[i4] = o;
    }
}

// ---------------- K3: batched xop = LN(hv2, op_g, op_beta) @ W1 + b1 (bf16) ---
__global__ __launch_bounds__(256) void k_xop(
    const float* __restrict__ hv2, const u16* __restrict__ wb,
    const float* __restrict__ b1, const float* __restrict__ opg,
    const float* __restrict__ opb, u16* __restrict__ xop)
{
    __shared__ __align__(16) float Xf[32][132];
    __shared__ __align__(16) short A1[32 * 136];
    __shared__ float mu_[32], isd_[32];
    const int bn = blockIdx.x, t = threadIdx.x;
    const int w = t >> 6, l = t & 63, l15 = l & 15, lq = l >> 4;
    const float* ep = hv2 + (size_t)bn * 4096;
    for (int i4 = t * 4; i4 < 4096; i4 += 1024) {
        f32x4 v = *(const f32x4*)&ep[i4];
        *(f32x4*)&Xf[i4 >> 7][i4 & 127] = v;
    }
    __syncthreads();
    {
        int r = t >> 3, sub = t & 7;
        float s = 0.f, ss = 0.f;
        #pragma unroll
        for (int j = 0; j < 16; ++j) {
            float v = Xf[r][sub * 16 + j]; s += v; ss += v * v;
        }
        #pragma unroll
        for (int m = 1; m < 8; m <<= 1) { s += __shfl_xor(s, m, 8); ss += __shfl_xor(ss, m, 8); }
        if (sub == 0) {
            float mu = s * (1.f / 128.f);
            mu_[r] = mu;
            isd_[r] = 1.f / sqrtf(ss * (1.f / 128.f) - mu * mu + 1e-5f);
        }
    }
    __syncthreads();
    for (int i4 = t * 4; i4 < 4096; i4 += 1024) {
        int r = i4 >> 7, c = i4 & 127;
        f32x4 xv = *(const f32x4*)&Xf[r][c];
        f32x4 y;
        #pragma unroll
        for (int j = 0; j < 4; ++j)
            y[j] = opg[c + j] * (xv[j] - mu_[r]) * isd_[r] + opb[c + j];
        *(s16x4*)&A1[r * 136 + c] = packbf4(y);
    }
    __syncthreads();
    #pragma unroll
    for (int i = 0; i < 4; ++i) {
        int id = w + 4 * i;
        int m0 = (id >> 3) << 4, n0 = (id & 7) << 4;
        f32x4 acc = {0.f, 0.f, 0.f, 0.f};
        #pragma unroll
        for (int kt = 0; kt < 4; ++kt) {
            bf16x8 a = *(const bf16x8*)&A1[(m0 + l15) * 136 + kt * 32 + lq * 8];
            bf16x8 bv = *(const bf16x8*)(wb + OFF_OPW1T + (size_t)(n0 + l15) * 128 + kt * 32 + lq * 8);
            acc = __builtin_amdgcn_mfma_f32_16x16x32_bf16(a, bv, acc, 0, 0, 0);
        }
        int col = n0 + l15;
        float bb = b1[col];
        #pragma unroll
        for (int r = 0; r < 4; ++r)
            xop[(size_t)(bn * 32 + m0 + lq * 4 + r) * 128 + col] = f2bf(acc[r] + bb);
    }
}

// ---------------- K4: fused edge pipeline (LDS-overlaid, 4 blocks/CU) --------
// Regions: A = X / logits+Pe / FFN-in. B = Q / O2 / Hd-lo. C = K / Hd-hi.
// D = V. Residual h_E lives in registers throughout.
#define LS_A 0
#define LS_B 9216
#define LS_C 17920
#define LS_D 26112
#define LS_SM 35328
__global__ __launch_bounds__(256, 4) void k_edge_fused(
    const u16* __restrict__ xop, const float* __restrict__ hE,
    const int* __restrict__ Eidx, const float* __restrict__ maskA,
    const u16* __restrict__ wb, const float* __restrict__ b2,
    const float* __restrict__ n3g, const float* __restrict__ n3b,
    const float* __restrict__ bin, const float* __restrict__ bout,
    const float* __restrict__ n4g, const float* __restrict__ n4b,
    float* __restrict__ outE)
{
    __shared__ __align__(16) char smem[37504];
    short* A1  = (short*)(smem + LS_A);        // [32][136] X; [128][36] Ls/Pe; FFN-in
    short* Qe  = (short*)(smem + LS_B);        // [32][136] Q; O2; Hd lo
    short* Ke  = (short*)(smem + LS_C);        // [32][136] K; Hd hi
    short* Hd  = Qe;                           // [32][264] overlays B+C
    short* Vp  = (short*)(smem + LS_D);        // [128][36] V''
    short* Ls  = A1;                           // [128][36] logits/Pe
    float* ms  = (float*)(smem + LS_SM);       // [32]
    float* mu_ = (float*)(smem + LS_SM + 128);
    float* isd_= (float*)(smem + LS_SM + 256);
    float* pps = (float*)(smem + LS_SM + 384); // [128]
    float* ppss= (float*)(smem + LS_SM + 896); // [128]
    float* xcf = (float*)(smem + LS_SM + 1408);// [128]
    int*   idxs= (int*)(smem + LS_SM + 1920);  // [32]

    const int bn = blockIdx.x, t = threadIdx.x;
    const int b = bn >> 11;
    const int w = t >> 6, l = t & 63, l15 = l & 15, lq = l >> 4;
    const int c0 = w * 16 + l15, c1 = c0 + 64;

    // phase 0: prefetch hE residual fragments into regs (overlaps phase 1)
    float her[4][4];
    #pragma unroll
    for (int i = 0; i < 4; ++i) {
        int id = w + 4 * i;
        int m0 = (id >> 3) << 4, n0 = (id & 7) << 4;
        int col = n0 + l15;
        #pragma unroll
        for (int r = 0; r < 4; ++r)
            her[i][r] = hE[(size_t)bn * 4096 + (m0 + lq * 4 + r) * 128 + col];
    }
    if (t < 128) xcf[t] = bf2f(xop[(size_t)bn * 128 + t]);
    if (t < 32) { idxs[t] = Eidx[(size_t)bn * 32 + t]; ms[t] = maskA[(size_t)bn * 32 + t]; }
    const float bb_0 = b2[c0], bb_1 = b2[c1];
    const float g3_0 = n3g[c0], g3_1 = n3g[c1], b3_0 = n3b[c0], b3_1 = n3b[c1];
    const float g4_0 = n4g[c0], g4_1 = n4g[c1], b4_0 = n4b[c0], b4_1 = n4b[c1];
    const float bo_0 = bout[c0], bo_1 = bout[c1];
    __syncthreads();

    // phase 1: A = bf16(x ⊙ x[nbr])
    for (int i4 = t * 4; i4 < 4096; i4 += 1024) {
        int k = i4 >> 7, h = i4 & 127;
        s16x4 nb = *(const s16x4*)&xop[((size_t)b * Nn + idxs[k]) * 128 + h];
        f32x4 prod;
        prod.x = xcf[h] * bf2f(nb.x);
        prod.y = xcf[h + 1] * bf2f(nb.y);
        prod.z = xcf[h + 2] * bf2f(nb.z);
        prod.w = xcf[h + 3] * bf2f(nb.w);
        *(s16x4*)&A1[k * 136 + h] = packbf4(prod);
    }
    __syncthreads();

    // phase 2a: xv = hE + outer@W2 + b2  (MFMA-fragment layout, regs)
    float xv[4][4];
    #pragma unroll
    for (int i = 0; i < 4; ++i) {
        int id = w + 4 * i;
        int m0 = (id >> 3) << 4, n0 = (id & 7) << 4;
        f32x4 acc = {0.f, 0.f, 0.f, 0.f};
        #pragma unroll
        for (int kt = 0; kt < 4; ++kt) {
            bf16x8 a = *(const bf16x8*)&A1[(m0 + l15) * 136 + kt * 32 + lq * 8];
            bf16x8 bv = *(const bf16x8*)(wb + OFF_OPW2T + (size_t)(n0 + l15) * 128 + kt * 32 + lq * 8);
            acc = __builtin_amdgcn_mfma_f32_16x16x32_bf16(a, bv, acc, 0, 0, 0);
        }
        float bb = (i & 1) ? bb_1 : bb_0;
        #pragma unroll
        for (int r = 0; r < 4; ++r)
            xv[i][r] = acc[r] + bb + her[i][r];
    }
    __syncthreads();
    // phase 2b: A = bf16(xv)
    #pragma unroll
    for (int i = 0; i < 4; ++i) {
        int m0 = (i >> 1) << 4, col = (i & 1) ? c1 : c0;
        #pragma unroll
        for (int r = 0; r < 4; ++r)
            A1[(m0 + lq * 4 + r) * 136 + col] = (short)f2bf(xv[i][r]);
    }
    __syncthreads();

    // phase 3: projections Q = X@WO (faithful), K = X@WK, V = X@WV
    #pragma unroll
    for (int i = 0; i < 12; ++i) {
        int id = w + 4 * i;
        int mat = id >> 4, rem = id & 15;
        int m0 = (rem >> 3) << 4, n0 = (rem & 7) << 4;
        const u16* Bp = wb + ((mat == 0) ? OFF_EAWOT : (mat == 1) ? OFF_EAWKT : OFF_EAWVT);
        f32x4 acc = {0.f, 0.f, 0.f, 0.f};
        #pragma unroll
        for (int kt = 0; kt < 4; ++kt) {
            bf16x8 a = *(const bf16x8*)&A1[(m0 + l15) * 136 + kt * 32 + lq * 8];
            bf16x8 bv = *(const bf16x8*)(Bp + (size_t)(n0 + l15) * 128 + kt * 32 + lq * 8);
            acc = __builtin_amdgcn_mfma_f32_16x16x32_bf16(a, bv, acc, 0, 0, 0);
        }
        int col = n0 + l15;
        #pragma unroll
        for (int r = 0; r < 4; ++r) {
            int row = m0 + lq * 4 + r;
            u16 hv = f2bf(acc[r]);
            if (mat == 0) Qe[row * 136 + col] = (short)hv;
            else if (mat == 1) Ke[row * 136 + col] = (short)hv;
            else Vp[((row >> 3) * 32 + (col & 31)) * 36 + (((row & 7) << 2) | (col >> 5))] = (short)hv;
        }
    }
    __syncthreads();

    // phase 4: logits via MFMA, written in swapped order into Ls (=A region)
    #pragma unroll
    for (int i = 0; i < 4; ++i) {
        int id = w + 4 * i;                 // 0..15
        int h = id >> 2, rem = id & 3;
        int q0 = (rem >> 1) << 4, k0 = (rem & 1) << 4;
        int q = q0 + l15, k = k0 + l15;
        bf16x8 a = *(const bf16x8*)&Qe[(((h << 3) | (q >> 2)) * 136) + (((q & 3) << 5) + lq * 8)];
        bf16x8 bv = *(const bf16x8*)&Ke[(((h << 3) | (k >> 2)) * 136) + (((k & 3) << 5) + lq * 8)];
        f32x4 acc = {0.f, 0.f, 0.f, 0.f};
        acc = __builtin_amdgcn_mfma_f32_16x16x32_bf16(a, bv, acc, 0, 0, 0);
        int aa = l15 & 3;
        int kq = (k0 >> 2) + (l15 >> 2);
        int cc = (h << 3) + (q0 >> 2) + lq;
        #pragma unroll
        for (int r = 0; r < 4; ++r) {
            int q2 = (r << 3) | kq;
            Ls[(aa * 32 + q2) * 36 + cc] = (short)f2bf(acc[r] * 0.17677669529663687f);
        }
    }
    __syncthreads();

    // phase 5: masked softmax over c, all 256 threads (pair splits the row)
    {
        int rr = t >> 1, hf = t & 1;       // row 0..127, half 0/1
        int q2 = rr & 31;
        float mq = ms[q2];
        float lv[16];
        int base = rr * 36 + hf * 16;
        #pragma unroll
        for (int j = 0; j < 4; ++j) {
            s16x4 v = *(const s16x4*)&Ls[base + j * 4];
            lv[j * 4] = bf2f(v.x); lv[j * 4 + 1] = bf2f(v.y);
            lv[j * 4 + 2] = bf2f(v.z); lv[j * 4 + 3] = bf2f(v.w);
        }
        float mx = NEGF;
        #pragma unroll
        for (int c = 0; c < 16; ++c) {
            lv[c] = (mq * ms[hf * 16 + c] > 0.f) ? lv[c] : NEGF;
            mx = fmaxf(mx, lv[c]);
        }
        mx = fmaxf(mx, __shfl_xor(mx, 1));
        float s = 0.f;
        #pragma unroll
        for (int c = 0; c < 16; ++c) { lv[c] = __expf(lv[c] - mx); s += lv[c]; }
        s += __shfl_xor(s, 1);
        float inv = 1.f / s;
        #pragma unroll
        for (int j = 0; j < 4; ++j) {
            f32x4 pv;
            pv.x = lv[j * 4] * inv; pv.y = lv[j * 4 + 1] * inv;
            pv.z = lv[j * 4 + 2] * inv; pv.w = lv[j * 4 + 3] * inv;
            *(s16x4*)&Ls[base + j * 4] = packbf4(pv);
        }
    }
    __syncthreads();

    // phase 6: PV via MFMA -> O2 bf16 into B region (Q dead)
    #pragma unroll
    for (int i = 0; i < 4; ++i) {
        int id = w + 4 * i;
        int a = id >> 2, rem = id & 3;
        int q0 = (rem >> 1) << 4, d0 = (rem & 1) << 4;
        bf16x8 pa = *(const bf16x8*)&Ls[((a * 32 + q0 + l15) * 36) + lq * 8];
        bf16x8 vb = *(const bf16x8*)&Vp[((a * 32 + d0 + l15) * 36) + lq * 8];
        f32x4 acc = {0.f, 0.f, 0.f, 0.f};
        acc = __builtin_amdgcn_mfma_f32_16x16x32_bf16(pa, vb, acc, 0, 0, 0);
        #pragma unroll
        for (int r = 0; r < 4; ++r)
            Qe[(q0 + lq * 4 + r) * 136 + (a << 5) + d0 + l15] = (short)f2bf(acc[r]);
    }
    __syncthreads();

    // phase 7: xv += gelu(O2 @ WO)
    #pragma unroll
    for (int i = 0; i < 4; ++i) {
        int id = w + 4 * i;
        int m0 = (id >> 3) << 4, n0 = (id & 7) << 4;
        f32x4 acc = {0.f, 0.f, 0.f, 0.f};
        #pragma unroll
        for (int kt = 0; kt < 4; ++kt) {
            bf16x8 a = *(const bf16x8*)&Qe[(m0 + l15) * 136 + kt * 32 + lq * 8];
            bf16x8 bv = *(const bf16x8*)(wb + OFF_EAWOT + (size_t)(n0 + l15) * 128 + kt * 32 + lq * 8);
            acc = __builtin_amdgcn_mfma_f32_16x16x32_bf16(a, bv, acc, 0, 0, 0);
        }
        #pragma unroll
        for (int r = 0; r < 4; ++r)
            xv[i][r] += gelu_f(acc[r]);
    }
    __syncthreads();

    // phase 8: LN3 stats (shuffle over l15 group + cross-wave LDS)
    {
        float s8[8], ss8[8];
        #pragma unroll
        for (int j = 0; j < 8; ++j) { s8[j] = 0.f; ss8[j] = 0.f; }
        #pragma unroll
        for (int i = 0; i < 4; ++i)
            #pragma unroll
            for (int r = 0; r < 4; ++r) {
                int j = (i >> 1) * 4 + r;
                float v = xv[i][r];
                s8[j] += v; ss8[j] += v * v;
            }
        #pragma unroll
        for (int m = 1; m < 16; m <<= 1)
            #pragma unroll
            for (int j = 0; j < 8; ++j) {
                s8[j] += __shfl_xor(s8[j], m);
                ss8[j] += __shfl_xor(ss8[j], m);
            }
        if (l15 == 0) {
            #pragma unroll
            for (int j = 0; j < 8; ++j) {
                int row = (j >> 2) * 16 + lq * 4 + (j & 3);
                pps[w * 32 + row] = s8[j];
                ppss[w * 32 + row] = ss8[j];
            }
        }
    }
    __syncthreads();
    if (t < 32) {
        float s = pps[t] + pps[32 + t] + pps[64 + t] + pps[96 + t];
        float ss = ppss[t] + ppss[32 + t] + ppss[64 + t] + ppss[96 + t];
        float mu = s * (1.f / 128.f);
        mu_[t] = mu;
        isd_[t] = 1.f / sqrtf(ss * (1.f / 128.f) - mu * mu + 1e-5f);
    }
    __syncthreads();

    // phase 9: x2 = LN3(xv) -> regs + A region bf16 (FFN input; Pe dead)
    #pragma unroll
    for (int i = 0; i < 4; ++i) {
        int m0 = (i >> 1) << 4, col = (i & 1) ? c1 : c0;
        float g = (i & 1) ? g3_1 : g3_0, bB = (i & 1) ? b3_1 : b3_0;
        #pragma unroll
        for (int r = 0; r < 4; ++r) {
            int row = m0 + lq * 4 + r;
            float v = g * (xv[i][r] - mu_[row]) * isd_[row] + bB;
            xv[i][r] = v;
            A1[row * 136 + col] = (short)f2bf(v);
        }
    }
    __syncthreads();

    // phase 10: FFN (Hd overlays B+C; O2 and K dead)
    bf16x8 aA[2][4];
    #pragma unroll
    for (int m = 0; m < 2; ++m)
        #pragma unroll
        for (int kt = 0; kt < 4; ++kt)
            aA[m][kt] = *(const bf16x8*)&A1[(m * 16 + l15) * 136 + kt * 32 + lq * 8];

    f32x4 acc2[2][2];
    #pragma unroll
    for (int i = 0; i < 2; ++i)
        #pragma unroll
        for (int m = 0; m < 2; ++m) acc2[i][m] = (f32x4){0.f, 0.f, 0.f, 0.f};

    for (int ch = 0; ch < 2; ++ch) {
        #pragma unroll
        for (int nt = 0; nt < 4; ++nt) {
            int lc0 = (w * 4 + nt) * 16;
            int g = ch * 256 + lc0 + l15;
            bf16x8 bB[4];
            #pragma unroll
            for (int kt = 0; kt < 4; ++kt)
                bB[kt] = *(const bf16x8*)(wb + OFF_D2WINT + (size_t)g * 128 + kt * 32 + lq * 8);
            float bi = bin[g];
            #pragma unroll
            for (int m = 0; m < 2; ++m) {
                f32x4 acc = {0.f, 0.f, 0.f, 0.f};
                #pragma unroll
                for (int kt = 0; kt < 4; ++kt)
                    acc = __builtin_amdgcn_mfma_f32_16x16x32_bf16(aA[m][kt], bB[kt], acc, 0, 0, 0);
                #pragma unroll
                for (int r = 0; r < 4; ++r)
                    Hd[(m * 16 + lq * 4 + r) * 264 + lc0 + l15] = (short)f2bf(gelu_f(acc[r] + bi));
            }
        }
        __syncthreads();
        #pragma unroll
        for (int kt = 0; kt < 8; ++kt) {
            bf16x8 a0 = *(const bf16x8*)&Hd[l15 * 264 + kt * 32 + lq * 8];
            bf16x8 a1 = *(const bf16x8*)&Hd[(16 + l15) * 264 + kt * 32 + lq * 8];
            bf16x8 b0 = *(const bf16x8*)(wb + OFF_D2WOUTT + (size_t)c0 * 512 + ch * 256 + kt * 32 + lq * 8);
            bf16x8 b1 = *(const bf16x8*)(wb + OFF_D2WOUTT + (size_t)c1 * 512 + ch * 256 + kt * 32 + lq * 8);
            acc2[0][0] = __builtin_amdgcn_mfma_f32_16x16x32_bf16(a0, b0, acc2[0][0], 0, 0, 0);
            acc2[0][1] = __builtin_amdgcn_mfma_f32_16x16x32_bf16(a1, b0, acc2[0][1], 0, 0, 0);
            acc2[1][0] = __builtin_amdgcn_mfma_f32_16x16x32_bf16(a0, b1, acc2[1][0], 0, 0, 0);
            acc2[1][1] = __builtin_amdgcn_mfma_f32_16x16x32_bf16(a1, b1, acc2[1][1], 0, 0, 0);
        }
        __syncthreads();
    }
    // phase 11: xv += gelu(acc2 + bout)  (i = m*2 + ni)
    #pragma unroll
    for (int ni = 0; ni < 2; ++ni) {
        float bo = ni ? bo_1 : bo_0;
        #pragma unroll
        for (int m = 0; m < 2; ++m) {
            int i = m * 2 + ni;
            #pragma unroll
            for (int r = 0; r < 4; ++r)
                xv[i][r] += gelu_f(acc2[ni][m][r] + bo);
        }
    }

    // phase 12: LN4 stats + store
    {
        float s8[8], ss8[8];
        #pragma unroll
        for (int j = 0; j < 8; ++j) { s8[j] = 0.f; ss8[j] = 0.f; }
        #pragma unroll
        for (int i = 0; i < 4; ++i)
            #pragma unroll
            for (int r = 0; r < 4; ++r) {
                int j = (i >> 1) * 4 + r;
                float v = xv[i][r];
                s8[j] += v; ss8[j] += v * v;
            }
        #pragma unroll
        for (int m = 1; m < 16; m <<= 1)
            #pragma unroll
            for (int j = 0; j < 8; ++j) {
                s8[j] += __shfl_xor(s8[j], m);
                ss8[j] += __shfl_xor(ss8[j], m);
            }
        if (l15 == 0) {
            #pragma unroll
            for (int j = 0; j < 8; ++j) {
                int row = (j >> 2) * 16 + lq * 4 + (j & 3);
                pps[w * 32 + row] = s8[j];
                ppss[w * 32 + row] = ss8[j];
            }
        }
    }
    __syncthreads();
    if (t < 32) {
        float s = pps[t] + pps[32 + t] + pps[64 + t] + pps[96 + t];
        float ss = ppss[t] + ppss[32 + t] + ppss[64 + t] + ppss[96 + t];
        float mu = s * (1.f / 128.f);
        mu_[t] = mu;
        isd_[t] = 1.f / sqrtf(ss * (1.f / 128.f) - mu * mu + 1e-5f);
    }
    __syncthreads();
    #pragma unroll
    for (int i = 0; i < 4; ++i) {
        int m0 = (i >> 1) << 4, col = (i & 1) ? c1 : c0;
        float g = (i & 1) ? g4_1 : g4_0, bB = (i & 1) ? b4_1 : b4_0;
        #pragma unroll
        for (int r = 0; r < 4; ++r) {
            int row = m0 + lq * 4 + r;
            outE[(size_t)bn * 4096 + row * 128 + col] =
                g * (xv[i][r] - mu_[row]) * isd_[row] + bB;
        }
    }
}

extern "C" void kernel_launch(void* const* d_in, const int* in_sizes, int n_in,
                              void* d_out, int out_size, void* d_ws, size_t ws_size,
                              hipStream_t stream) {
    const float* hV     = (const float*)d_in[0];
    const float* hE     = (const float*)d_in[1];
    const float* hEV    = (const float*)d_in[2];
    const float* maskV  = (const float*)d_in[3];
    const float* maskA  = (const float*)d_in[4];
    const float* naWQ   = (const float*)d_in[5];
    const float* naWK   = (const float*)d_in[6];
    const float* naWV   = (const float*)d_in[7];
    const float* naWO   = (const float*)d_in[8];
    const float* eaWK   = (const float*)d_in[9];
    const float* eaWV   = (const float*)d_in[10];
    const float* eaWO   = (const float*)d_in[11];
    const float* d1Win  = (const float*)d_in[12];
    const float* d1bin  = (const float*)d_in[13];
    const float* d1Wout = (const float*)d_in[14];
    const float* d1bout = (const float*)d_in[15];
    const float* d2Win  = (const float*)d_in[16];
    const float* d2bin  = (const float*)d_in[17];
    const float* d2Wout = (const float*)d_in[18];
    const float* d2bout = (const float*)d_in[19];
    const float* opW1   = (const float*)d_in[20];
    const float* opb1   = (const float*)d_in[21];
    const float* opW2   = (const float*)d_in[22];
    const float* opb2   = (const float*)d_in[23];
    const float* opg    = (const float*)d_in[24];
    const float* opbeta = (const float*)d_in[25];
    const float* n1g    = (const float*)d_in[26];
    const float* n1b    = (const float*)d_in[27];
    const float* n3g    = (const float*)d_in[28];
    const float* n3b    = (const float*)d_in[29];
    const float* n4g    = (const float*)d_in[30];
    const float* n4b    = (const float*)d_in[31];
    const int*   Eidx   = (const int*)d_in[32];

    float* outV = (float*)d_out;
    float* outE = outV + (size_t)Bb * Nn * Hh;
    u16* xop = (u16*)d_ws;                        // [B*N*H] bf16 (2 MB)
    u16* wb  = (u16*)d_ws + (size_t)Bb * Nn * Hh; // bf16 weights (~880 KB)
    // scratch inside outE region (consumed before k_edge_fused writes it):
    u16* Qall = (u16*)(outE + (size_t)30 * 1048576);  // 2 MB @ +120MB
    u16* outr = (u16*)(outE + (size_t)31 * 1048576);  // 2 MB @ +124MB

    dim3 blk(256);
    k_prep<<<dim3(WB_TOTAL / 256), blk, 0, stream>>>(naWK, naWV, eaWK, eaWV, eaWO,
                                                     d2Win, d2Wout, opW2,
                                                     d1Win, d1Wout, opW1,
                                                     naWQ, naWO, wb);
    dim3 gridTok(Bb * Nn / 32);
    dim3 grid(Bb * Nn);
    k_qproj<<<gridTok, blk, 0, stream>>>(hV, wb, Qall);
    k_node_core<<<grid, blk, 0, stream>>>(hEV, maskA, Qall, wb, outr);
    k_node_out<<<gridTok, blk, 0, stream>>>(outr, hV, wb, n1g, n1b, outV);
    k_node_ffn<<<gridTok, blk, 0, stream>>>(outV, maskV, wb, d1bin,
                                            d1bout, n1g, n1b);
    k_xop<<<gridTok, blk, 0, stream>>>(outV, wb, opb1, opg, opbeta, xop);
    k_edge_fused<<<grid, blk, 0, stream>>>(xop, hE, Eidx, maskA, wb, opb2,
                                           n3g, n3b, d2bin, d2bout, n4g, n4b,
                                           outE);
}